// Round 2
// baseline (3924.764 us; speedup 1.0000x reference)
//
#include <hip/hip_runtime.h>
#include <cfloat>
#include <cmath>

// ---------------------------------------------------------------------------
// GAT 2-layer forward, fp32 baseline.
// Layer1: h1 = x@W1 [N,256]; attention (8 heads x 32ch); agg -> +b1, relu
// Layer2: h2 = h1out@W2 [N,64]; attention (1 head); agg -> +b2, log_softmax
// ---------------------------------------------------------------------------

#define HEADS1 8
#define CH1 32
#define F1 256   // HEADS1*CH1
#define F2 64
#define NEG_SLOPE 0.2f

// ----------------------------- GEMM (fp32, LDS-tiled) ----------------------
// C[M,N] = A[M,K] @ B[K,N].  BM=64 BN=64 BK=32, 256 thr, 4x4 per thread.
#define BM 64
#define BN 64
#define BK 32
#define TM 4
#define TN 4

__global__ __launch_bounds__(256) void gemm_f32(
    const float* __restrict__ A, const float* __restrict__ B,
    float* __restrict__ C, int M, int N, int K) {
  __shared__ float As[BK][BM];
  __shared__ float Bs[BK][BN];
  const int tid = threadIdx.x;
  const int row0 = blockIdx.y * BM;
  const int col0 = blockIdx.x * BN;
  const int tx = tid & 15;   // 16 thread cols
  const int ty = tid >> 4;   // 16 thread rows
  float acc[TM][TN] = {};
  for (int k0 = 0; k0 < K; k0 += BK) {
    // A tile: BM*BK = 2048 elems. idx -> m = idx/32, k = idx%32
    #pragma unroll
    for (int i = 0; i < (BM * BK) / 256; ++i) {
      int idx = tid + i * 256;
      int m = idx >> 5, k = idx & 31;
      int gr = row0 + m;
      As[k][m] = (gr < M) ? A[(size_t)gr * K + k0 + k] : 0.f;
    }
    // B tile: BK*BN = 2048 elems. idx -> k = idx/64, n = idx%64
    #pragma unroll
    for (int i = 0; i < (BK * BN) / 256; ++i) {
      int idx = tid + i * 256;
      int k = idx >> 6, n = idx & 63;
      Bs[k][n] = B[(size_t)(k0 + k) * N + col0 + n];
    }
    __syncthreads();
    #pragma unroll
    for (int k = 0; k < BK; ++k) {
      float ra[TM], rb[TN];
      #pragma unroll
      for (int i = 0; i < TM; ++i) ra[i] = As[k][ty * TM + i];
      #pragma unroll
      for (int j = 0; j < TN; ++j) rb[j] = Bs[k][tx * TN + j];
      #pragma unroll
      for (int i = 0; i < TM; ++i)
        #pragma unroll
        for (int j = 0; j < TN; ++j) acc[i][j] += ra[i] * rb[j];
    }
    __syncthreads();
  }
  #pragma unroll
  for (int i = 0; i < TM; ++i) {
    int gr = row0 + ty * TM + i;
    if (gr >= M) continue;
    #pragma unroll
    for (int j = 0; j < TN; ++j)
      C[(size_t)gr * N + col0 + tx * TN + j] = acc[i][j];
  }
}

// ------------------------- attention scalar products ------------------------
// a_src[n,h] = sum_c h1[n,h*32+c]*att_src[h*32+c]; block=256 per node
__global__ __launch_bounds__(256) void att1_kernel(
    const float* __restrict__ h1, const float* __restrict__ att_src,
    const float* __restrict__ att_dst, float* __restrict__ a_src,
    float* __restrict__ a_dst) {
  const int node = blockIdx.x;
  const int tid = threadIdx.x;
  float v = h1[(size_t)node * F1 + tid];
  float ps = v * att_src[tid];
  float pd = v * att_dst[tid];
  #pragma unroll
  for (int off = 16; off > 0; off >>= 1) {
    ps += __shfl_down(ps, off, 32);
    pd += __shfl_down(pd, off, 32);
  }
  if ((tid & 31) == 0) {
    a_src[node * HEADS1 + (tid >> 5)] = ps;
    a_dst[node * HEADS1 + (tid >> 5)] = pd;
  }
}

// block=64 per node (1 head, 64 channels)
__global__ __launch_bounds__(64) void att2_kernel(
    const float* __restrict__ h2, const float* __restrict__ att_src,
    const float* __restrict__ att_dst, float* __restrict__ a_src,
    float* __restrict__ a_dst) {
  const int node = blockIdx.x;
  const int lane = threadIdx.x;
  float v = h2[(size_t)node * F2 + lane];
  float ps = v * att_src[lane];
  float pd = v * att_dst[lane];
  #pragma unroll
  for (int off = 32; off > 0; off >>= 1) {
    ps += __shfl_down(ps, off, 64);
    pd += __shfl_down(pd, off, 64);
  }
  if (lane == 0) {
    a_src[node] = ps;
    a_dst[node] = pd;
  }
}

// ------------------------------ edge helpers --------------------------------
__device__ __forceinline__ void edge_sd(const int* __restrict__ ei, int e,
                                        int E0, int& s, int& d) {
  if (e < E0) {
    s = ei[e];
    d = ei[E0 + e];
  } else {
    s = d = e - E0;
  }
}

__device__ __forceinline__ float lrelu(float x) {
  return x >= 0.f ? x : NEG_SLOPE * x;
}

// monotone float<->uint order encoding for atomicMax
__device__ __forceinline__ unsigned fkey(float x) {
  unsigned u = __float_as_uint(x);
  return (u & 0x80000000u) ? ~u : (u | 0x80000000u);
}
__device__ __forceinline__ float fkey_dec(unsigned key) {
  return __uint_as_float((key & 0x80000000u) ? (key & 0x7FFFFFFFu) : ~key);
}

// ------------------------------- layer1 edges -------------------------------
__global__ __launch_bounds__(256) void edge1_max(
    const int* __restrict__ ei, int E0, int Etot,
    const float* __restrict__ a_src, const float* __restrict__ a_dst,
    unsigned* __restrict__ emax) {
  int e = blockIdx.x * 256 + threadIdx.x;
  if (e >= Etot) return;
  int s, d;
  edge_sd(ei, e, E0, s, d);
  #pragma unroll
  for (int h = 0; h < HEADS1; ++h) {
    float x = lrelu(a_src[s * HEADS1 + h] + a_dst[d * HEADS1 + h]);
    atomicMax(&emax[d * HEADS1 + h], fkey(x));
  }
}

__global__ __launch_bounds__(256) void edge1_sum(
    const int* __restrict__ ei, int E0, int Etot,
    const float* __restrict__ a_src, const float* __restrict__ a_dst,
    const unsigned* __restrict__ emax, float* __restrict__ denom) {
  int e = blockIdx.x * 256 + threadIdx.x;
  if (e >= Etot) return;
  int s, d;
  edge_sd(ei, e, E0, s, d);
  #pragma unroll
  for (int h = 0; h < HEADS1; ++h) {
    float x = lrelu(a_src[s * HEADS1 + h] + a_dst[d * HEADS1 + h]);
    float m = fkey_dec(emax[d * HEADS1 + h]);
    atomicAdd(&denom[d * HEADS1 + h], expf(x - m));
  }
}

// one 64-lane wave per edge; lane handles 4 channels
__global__ __launch_bounds__(256) void edge1_scatter(
    const int* __restrict__ ei, int E0, int Etot,
    const float* __restrict__ a_src, const float* __restrict__ a_dst,
    const unsigned* __restrict__ emax, const float* __restrict__ denom,
    const float* __restrict__ h1, float* __restrict__ agg) {
  int e = (blockIdx.x * 256 + threadIdx.x) >> 6;
  if (e >= Etot) return;
  int lane = threadIdx.x & 63;
  int s, d;
  edge_sd(ei, e, E0, s, d);
  int ch = lane * 4;
  int h = ch >> 5;
  float x = lrelu(a_src[s * HEADS1 + h] + a_dst[d * HEADS1 + h]);
  float m = fkey_dec(emax[d * HEADS1 + h]);
  float coef = expf(x - m) / denom[d * HEADS1 + h];
  const float4 hv = *(const float4*)&h1[(size_t)s * F1 + ch];
  float* dst = &agg[(size_t)d * F1 + ch];
  atomicAdd(dst + 0, hv.x * coef);
  atomicAdd(dst + 1, hv.y * coef);
  atomicAdd(dst + 2, hv.z * coef);
  atomicAdd(dst + 3, hv.w * coef);
}

// ------------------------------- layer2 edges -------------------------------
__global__ __launch_bounds__(256) void edge2_max(
    const int* __restrict__ ei, int E0, int Etot,
    const float* __restrict__ a_src, const float* __restrict__ a_dst,
    unsigned* __restrict__ emax) {
  int e = blockIdx.x * 256 + threadIdx.x;
  if (e >= Etot) return;
  int s, d;
  edge_sd(ei, e, E0, s, d);
  float x = lrelu(a_src[s] + a_dst[d]);
  atomicMax(&emax[d], fkey(x));
}

__global__ __launch_bounds__(256) void edge2_sum(
    const int* __restrict__ ei, int E0, int Etot,
    const float* __restrict__ a_src, const float* __restrict__ a_dst,
    const unsigned* __restrict__ emax, float* __restrict__ denom) {
  int e = blockIdx.x * 256 + threadIdx.x;
  if (e >= Etot) return;
  int s, d;
  edge_sd(ei, e, E0, s, d);
  float x = lrelu(a_src[s] + a_dst[d]);
  float m = fkey_dec(emax[d]);
  atomicAdd(&denom[d], expf(x - m));
}

// one 64-lane wave per edge; lane = channel
__global__ __launch_bounds__(256) void edge2_scatter(
    const int* __restrict__ ei, int E0, int Etot,
    const float* __restrict__ a_src, const float* __restrict__ a_dst,
    const unsigned* __restrict__ emax, const float* __restrict__ denom,
    const float* __restrict__ h2, float* __restrict__ agg) {
  int e = (blockIdx.x * 256 + threadIdx.x) >> 6;
  if (e >= Etot) return;
  int lane = threadIdx.x & 63;
  int s, d;
  edge_sd(ei, e, E0, s, d);
  float x = lrelu(a_src[s] + a_dst[d]);
  float m = fkey_dec(emax[d]);
  float coef = expf(x - m) / denom[d];
  float v = h2[(size_t)s * F2 + lane];
  atomicAdd(&agg[(size_t)d * F2 + lane], v * coef);
}

// ------------------------------ epilogues -----------------------------------
__global__ __launch_bounds__(256) void bias_relu1(float* __restrict__ agg,
                                                  const float* __restrict__ b,
                                                  int total) {
  int i = blockIdx.x * 256 + threadIdx.x;
  if (i >= total) return;
  agg[i] = fmaxf(agg[i] + b[i & (F1 - 1)], 0.f);
}

__global__ __launch_bounds__(64) void final_logsoftmax(
    const float* __restrict__ agg, const float* __restrict__ b,
    float* __restrict__ out) {
  const int node = blockIdx.x;
  const int lane = threadIdx.x;
  float v = agg[(size_t)node * F2 + lane] + b[lane];
  float m = v;
  #pragma unroll
  for (int off = 32; off > 0; off >>= 1) m = fmaxf(m, __shfl_xor(m, off, 64));
  float ex = expf(v - m);
  float ssum = ex;
  #pragma unroll
  for (int off = 32; off > 0; off >>= 1) ssum += __shfl_xor(ssum, off, 64);
  out[(size_t)node * F2 + lane] = v - m - logf(ssum);
}

// ------------------------------- launch -------------------------------------
extern "C" void kernel_launch(void* const* d_in, const int* in_sizes, int n_in,
                              void* d_out, int out_size, void* d_ws,
                              size_t ws_size, hipStream_t stream) {
  const float* x        = (const float*)d_in[0];
  const int*   ei       = (const int*)d_in[1];
  const float* W1       = (const float*)d_in[2];
  const float* att_src1 = (const float*)d_in[3];
  const float* att_dst1 = (const float*)d_in[4];
  const float* b1       = (const float*)d_in[5];
  const float* W2       = (const float*)d_in[6];
  const float* att_src2 = (const float*)d_in[7];
  const float* att_dst2 = (const float*)d_in[8];
  const float* b2       = (const float*)d_in[9];

  const int N = in_sizes[0] / 128;   // 50000
  const int E0 = in_sizes[1] / 2;    // 800000
  const int Etot = E0 + N;           // with self loops

  char* w = (char*)d_ws;
  // region A: h1 [N*256 f32]; after layer1 done, reused for h2 + agg2
  float* h1   = (float*)w;
  float* h2   = (float*)w;
  float* agg2 = (float*)(w + (size_t)N * F2 * 4);   // NOTE: aliases h1 rows!
  // region B: agg1 [N*256 f32] (becomes h1out in place)
  float* agg1 = (float*)(w + (size_t)N * F1 * 4);
  // small arrays
  char* sm = w + 2 * (size_t)N * F1 * 4;
  float*    a_src1 = (float*)(sm);
  float*    a_dst1 = (float*)(sm + (size_t)N * HEADS1 * 4);
  unsigned* emax1  = (unsigned*)(sm + 2 * (size_t)N * HEADS1 * 4);
  float*    denom1 = (float*)(sm + 3 * (size_t)N * HEADS1 * 4);
  float*    a_src2 = (float*)(sm + 4 * (size_t)N * HEADS1 * 4);
  float*    a_dst2 = (float*)(sm + 4 * (size_t)N * HEADS1 * 4 + (size_t)N * 4);
  unsigned* emax2  = (unsigned*)(sm + 4 * (size_t)N * HEADS1 * 4 + 2 * (size_t)N * 4);
  float*    denom2 = (float*)(sm + 4 * (size_t)N * HEADS1 * 4 + 3 * (size_t)N * 4);

  // zero-init for layer 1 (agg2 is zeroed LATER: it aliases h1's region)
  hipMemsetAsync(agg1, 0, (size_t)N * F1 * 4, stream);
  hipMemsetAsync(emax1, 0, 2 * (size_t)N * HEADS1 * 4, stream);
  hipMemsetAsync(emax2, 0, 2 * (size_t)N * 4, stream);

  const int gy = (N + BM - 1) / BM;  // 782
  dim3 blk(256);

  // layer 1
  gemm_f32<<<dim3(F1 / BN, gy), blk, 0, stream>>>(x, W1, h1, N, F1, 128);
  att1_kernel<<<N, 256, 0, stream>>>(h1, att_src1, att_dst1, a_src1, a_dst1);
  int eb = (Etot + 255) / 256;
  edge1_max<<<eb, blk, 0, stream>>>(ei, E0, Etot, a_src1, a_dst1, emax1);
  edge1_sum<<<eb, blk, 0, stream>>>(ei, E0, Etot, a_src1, a_dst1, emax1, denom1);
  int ebw = (Etot + 3) / 4;  // 4 waves (edges) per 256-thread block
  edge1_scatter<<<ebw, blk, 0, stream>>>(ei, E0, Etot, a_src1, a_dst1, emax1,
                                         denom1, h1, agg1);
  bias_relu1<<<((size_t)N * F1 + 255) / 256, blk, 0, stream>>>(agg1, b1, N * F1);

  // h1 is dead now -> safe to zero agg2 (which lives inside h1's region)
  hipMemsetAsync(agg2, 0, (size_t)N * F2 * 4, stream);

  // layer 2
  gemm_f32<<<dim3(F2 / BN, gy), blk, 0, stream>>>(agg1, W2, h2, N, F2, F1);
  att2_kernel<<<N, 64, 0, stream>>>(h2, att_src2, att_dst2, a_src2, a_dst2);
  edge2_max<<<eb, blk, 0, stream>>>(ei, E0, Etot, a_src2, a_dst2, emax2);
  edge2_sum<<<eb, blk, 0, stream>>>(ei, E0, Etot, a_src2, a_dst2, emax2, denom2);
  edge2_scatter<<<ebw, blk, 0, stream>>>(ei, E0, Etot, a_src2, a_dst2, emax2,
                                         denom2, h2, agg2);
  final_logsoftmax<<<N, 64, 0, stream>>>(agg2, b2, (float*)d_out);
}

// Round 4
// 656.466 us; speedup vs baseline: 5.9786x; 5.9786x over previous
//
#include <hip/hip_runtime.h>
#include <hip/hip_bf16.h>
#include <cmath>

// ---------------------------------------------------------------------------
// GAT 2-layer forward. R4: CSR gather pipeline, zero-aliasing workspace
// (~97MB), cursor-based CSR fill, h1out stored bf16 (layer-2 GEMM input).
// ---------------------------------------------------------------------------

#define HEADS1 8
#define F1 256   // HEADS1*32
#define F2 64
#define NEG_SLOPE 0.2f

#define BM 64
#define BN 64
#define BK 32
#define TM 4
#define TN 4

// ----------------------------- GEMM fp32 ------------------------------------
__global__ __launch_bounds__(256) void gemm_f32(
    const float* __restrict__ A, const float* __restrict__ B,
    float* __restrict__ C, int M, int N, int K) {
  __shared__ float As[BK][BM];
  __shared__ float Bs[BK][BN];
  const int tid = threadIdx.x;
  const int row0 = blockIdx.y * BM;
  const int col0 = blockIdx.x * BN;
  const int tx = tid & 15;
  const int ty = tid >> 4;
  float acc[TM][TN] = {};
  for (int k0 = 0; k0 < K; k0 += BK) {
    #pragma unroll
    for (int i = 0; i < (BM * BK) / 256; ++i) {
      int idx = tid + i * 256;
      int m = idx >> 5, k = idx & 31;
      int gr = row0 + m;
      As[k][m] = (gr < M) ? A[(size_t)gr * K + k0 + k] : 0.f;
    }
    #pragma unroll
    for (int i = 0; i < (BK * BN) / 256; ++i) {
      int idx = tid + i * 256;
      int k = idx >> 6, n = idx & 63;
      Bs[k][n] = B[(size_t)(k0 + k) * N + col0 + n];
    }
    __syncthreads();
    #pragma unroll
    for (int k = 0; k < BK; ++k) {
      float ra[TM], rb[TN];
      #pragma unroll
      for (int i = 0; i < TM; ++i) ra[i] = As[k][ty * TM + i];
      #pragma unroll
      for (int j = 0; j < TN; ++j) rb[j] = Bs[k][tx * TN + j];
      #pragma unroll
      for (int i = 0; i < TM; ++i)
        #pragma unroll
        for (int j = 0; j < TN; ++j) acc[i][j] += ra[i] * rb[j];
    }
    __syncthreads();
  }
  #pragma unroll
  for (int i = 0; i < TM; ++i) {
    int gr = row0 + ty * TM + i;
    if (gr >= M) continue;
    #pragma unroll
    for (int j = 0; j < TN; ++j)
      C[(size_t)gr * N + col0 + tx * TN + j] = acc[i][j];
  }
}

// ----------------------------- GEMM, A in bf16 -------------------------------
__global__ __launch_bounds__(256) void gemm_abf16(
    const __hip_bfloat16* __restrict__ A, const float* __restrict__ B,
    float* __restrict__ C, int M, int N, int K) {
  __shared__ float As[BK][BM];
  __shared__ float Bs[BK][BN];
  const int tid = threadIdx.x;
  const int row0 = blockIdx.y * BM;
  const int col0 = blockIdx.x * BN;
  const int tx = tid & 15;
  const int ty = tid >> 4;
  float acc[TM][TN] = {};
  for (int k0 = 0; k0 < K; k0 += BK) {
    #pragma unroll
    for (int i = 0; i < (BM * BK) / 256; ++i) {
      int idx = tid + i * 256;
      int m = idx >> 5, k = idx & 31;
      int gr = row0 + m;
      As[k][m] = (gr < M) ? __bfloat162float(A[(size_t)gr * K + k0 + k]) : 0.f;
    }
    #pragma unroll
    for (int i = 0; i < (BK * BN) / 256; ++i) {
      int idx = tid + i * 256;
      int k = idx >> 6, n = idx & 63;
      Bs[k][n] = B[(size_t)(k0 + k) * N + col0 + n];
    }
    __syncthreads();
    #pragma unroll
    for (int k = 0; k < BK; ++k) {
      float ra[TM], rb[TN];
      #pragma unroll
      for (int i = 0; i < TM; ++i) ra[i] = As[k][ty * TM + i];
      #pragma unroll
      for (int j = 0; j < TN; ++j) rb[j] = Bs[k][tx * TN + j];
      #pragma unroll
      for (int i = 0; i < TM; ++i)
        #pragma unroll
        for (int j = 0; j < TN; ++j) acc[i][j] += ra[i] * rb[j];
    }
    __syncthreads();
  }
  #pragma unroll
  for (int i = 0; i < TM; ++i) {
    int gr = row0 + ty * TM + i;
    if (gr >= M) continue;
    #pragma unroll
    for (int j = 0; j < TN; ++j)
      C[(size_t)gr * N + col0 + tx * TN + j] = acc[i][j];
  }
}

// ------------------------- attention scalar products ------------------------
__global__ __launch_bounds__(256) void att1_kernel(
    const float* __restrict__ h1, const float* __restrict__ att_src,
    const float* __restrict__ att_dst, float* __restrict__ a_src,
    float* __restrict__ a_dst) {
  const int node = blockIdx.x;
  const int tid = threadIdx.x;
  float v = h1[(size_t)node * F1 + tid];
  float ps = v * att_src[tid];
  float pd = v * att_dst[tid];
  #pragma unroll
  for (int off = 16; off > 0; off >>= 1) {
    ps += __shfl_down(ps, off, 32);
    pd += __shfl_down(pd, off, 32);
  }
  if ((tid & 31) == 0) {
    a_src[node * HEADS1 + (tid >> 5)] = ps;
    a_dst[node * HEADS1 + (tid >> 5)] = pd;
  }
}

__global__ __launch_bounds__(64) void att2_kernel(
    const float* __restrict__ h2, const float* __restrict__ att_src,
    const float* __restrict__ att_dst, float* __restrict__ a_src,
    float* __restrict__ a_dst) {
  const int node = blockIdx.x;
  const int lane = threadIdx.x;
  float v = h2[(size_t)node * F2 + lane];
  float ps = v * att_src[lane];
  float pd = v * att_dst[lane];
  #pragma unroll
  for (int off = 32; off > 0; off >>= 1) {
    ps += __shfl_down(ps, off, 64);
    pd += __shfl_down(pd, off, 64);
  }
  if (lane == 0) {
    a_src[node] = ps;
    a_dst[node] = pd;
  }
}

// ------------------------------- CSR build ----------------------------------
__global__ __launch_bounds__(256) void deg_count(
    const int* __restrict__ ei, int E0, int Etot, int* __restrict__ counts) {
  int e = blockIdx.x * 256 + threadIdx.x;
  if (e >= Etot) return;
  int d = (e < E0) ? ei[E0 + e] : (e - E0);
  atomicAdd(&counts[d], 1);
}

// single-block exclusive scan
__global__ __launch_bounds__(1024) void scan_kernel(
    const int* __restrict__ counts, int* __restrict__ row_start, int n) {
  __shared__ int lds[1024];
  const int tid = threadIdx.x;
  int carry = 0;
  for (int base = 0; base < n; base += 1024) {
    int i = base + tid;
    int v = (i < n) ? counts[i] : 0;
    lds[tid] = v;
    __syncthreads();
    #pragma unroll
    for (int off = 1; off < 1024; off <<= 1) {
      int t = (tid >= off) ? lds[tid - off] : 0;
      __syncthreads();
      lds[tid] += t;
      __syncthreads();
    }
    if (i < n) row_start[i + 1] = carry + lds[tid];
    carry += lds[1023];
    __syncthreads();
  }
  if (tid == 0) row_start[0] = 0;
}

// cursor-based fill: slot = row_start[d] + atomicAdd(cursor[d],1)
__global__ __launch_bounds__(256) void fill_csr(
    const int* __restrict__ ei, int E0, int Etot,
    const int* __restrict__ row_start, int* __restrict__ cursor,
    int* __restrict__ csr_src) {
  int e = blockIdx.x * 256 + threadIdx.x;
  if (e >= Etot) return;
  int s, d;
  if (e < E0) { s = ei[e]; d = ei[E0 + e]; } else { s = d = e - E0; }
  int slot = row_start[d] + atomicAdd(&cursor[d], 1);
  csr_src[slot] = s;
}

// ------------------------- gather aggregation (layer 1) ---------------------
// one 256-thread block per dst node; softmax without max-subtraction
// (logits bounded ~|8|, exp safe in fp32; shift cancels in normalization).
__global__ __launch_bounds__(256) void gather1(
    const int* __restrict__ csr_src, const int* __restrict__ row_start,
    const float* __restrict__ a_src, const float* __restrict__ a_dst,
    const float* __restrict__ h1, const float* __restrict__ b,
    __hip_bfloat16* __restrict__ out) {
  const int d = blockIdx.x;
  const int tid = threadIdx.x;
  const int rs = row_start[d];
  const int deg = row_start[d + 1] - rs;
  __shared__ float red[256];

  // pass 1: denominators. thread = (slot, head): h = tid&7, slot = tid>>3
  {
    int h = tid & 7, slot = tid >> 3;
    float adv = a_dst[d * HEADS1 + h];
    float lsum = 0.f;
    for (int i = slot; i < deg; i += 32) {
      int s = csr_src[rs + i];
      float x = a_src[s * HEADS1 + h] + adv;
      x = (x >= 0.f) ? x : NEG_SLOPE * x;
      lsum += __expf(x);
    }
    red[tid] = lsum;
  }
  __syncthreads();
  #pragma unroll
  for (int off = 128; off >= 8; off >>= 1) {
    if (tid < off) red[tid] += red[tid + off];
    __syncthreads();
  }
  // red[h] = denom for head h

  // pass 2: thread = channel
  const int ch = tid;
  const int hh = ch >> 5;
  const float advh = a_dst[d * HEADS1 + hh];
  const float den = red[hh];
  float acc = 0.f;
  for (int i = 0; i < deg; ++i) {
    int s = csr_src[rs + i];
    float x = a_src[s * HEADS1 + hh] + advh;
    x = (x >= 0.f) ? x : NEG_SLOPE * x;
    float coef = __expf(x) / den;
    acc += coef * h1[(size_t)s * F1 + ch];
  }
  out[(size_t)d * F1 + ch] = __float2bfloat16(fmaxf(acc + b[ch], 0.f));
}

// ------------------- gather aggregation (layer 2) + log_softmax -------------
__global__ __launch_bounds__(256) void gather2(
    const int* __restrict__ csr_src, const int* __restrict__ row_start,
    const float* __restrict__ a_src, const float* __restrict__ a_dst,
    const float* __restrict__ h2, const float* __restrict__ b,
    float* __restrict__ out, int n) {
  const int d = blockIdx.x * 4 + (threadIdx.x >> 6);
  const int lane = threadIdx.x & 63;
  if (d >= n) return;
  const int rs = row_start[d];
  const int deg = row_start[d + 1] - rs;
  const float adv = a_dst[d];

  float lsum = 0.f;
  for (int i = lane; i < deg; i += 64) {
    int s = csr_src[rs + i];
    float x = a_src[s] + adv;
    x = (x >= 0.f) ? x : NEG_SLOPE * x;
    lsum += __expf(x);
  }
  #pragma unroll
  for (int off = 32; off > 0; off >>= 1) lsum += __shfl_xor(lsum, off, 64);
  const float den = lsum;

  float acc = 0.f;
  for (int i = 0; i < deg; ++i) {
    int s = csr_src[rs + i];
    float x = a_src[s] + adv;
    x = (x >= 0.f) ? x : NEG_SLOPE * x;
    acc += (__expf(x) / den) * h2[(size_t)s * F2 + lane];
  }

  float v = acc + b[lane];
  float m = v;
  #pragma unroll
  for (int off = 32; off > 0; off >>= 1) m = fmaxf(m, __shfl_xor(m, off, 64));
  float ex = __expf(v - m);
  float ss = ex;
  #pragma unroll
  for (int off = 32; off > 0; off >>= 1) ss += __shfl_xor(ss, off, 64);
  out[(size_t)d * F2 + lane] = v - m - __logf(ss);
}

// ------------------------------- launch -------------------------------------
extern "C" void kernel_launch(void* const* d_in, const int* in_sizes, int n_in,
                              void* d_out, int out_size, void* d_ws,
                              size_t ws_size, hipStream_t stream) {
  const float* x        = (const float*)d_in[0];
  const int*   ei       = (const int*)d_in[1];
  const float* W1       = (const float*)d_in[2];
  const float* att_src1 = (const float*)d_in[3];
  const float* att_dst1 = (const float*)d_in[4];
  const float* b1       = (const float*)d_in[5];
  const float* W2       = (const float*)d_in[6];
  const float* att_src2 = (const float*)d_in[7];
  const float* att_dst2 = (const float*)d_in[8];
  const float* b2       = (const float*)d_in[9];

  const int N = in_sizes[0] / 128;   // 50000
  const int E0 = in_sizes[1] / 2;    // 800000
  const int Etot = E0 + N;

  // ---- workspace layout: ALL buffers disjoint (~97.4MB total) ----
  char* w = (char*)d_ws;
  size_t off = 0;
  auto alloc = [&](size_t bytes) {
    char* p = w + off;
    off += (bytes + 255) & ~(size_t)255;
    return p;
  };
  float*           h1        = (float*)          alloc((size_t)N * F1 * 4);  // 51.2MB
  __hip_bfloat16*  h1out     = (__hip_bfloat16*) alloc((size_t)N * F1 * 2);  // 25.6MB
  float*           h2        = (float*)          alloc((size_t)N * F2 * 4);  // 12.8MB
  int*             csr_src   = (int*)            alloc((size_t)Etot * 4);    // 3.4MB
  int*             row_start = (int*)            alloc((size_t)(N + 1) * 4);
  int*             counts    = (int*)            alloc((size_t)N * 4);
  int*             cursor    = (int*)            alloc((size_t)N * 4);
  float*           a_src1    = (float*)          alloc((size_t)N * HEADS1 * 4);
  float*           a_dst1    = (float*)          alloc((size_t)N * HEADS1 * 4);
  float*           a_src2    = (float*)          alloc((size_t)N * 4);
  float*           a_dst2    = (float*)          alloc((size_t)N * 4);

  hipMemsetAsync(counts, 0, (size_t)N * 4, stream);
  hipMemsetAsync(cursor, 0, (size_t)N * 4, stream);

  dim3 blk(256);
  const int eb = (Etot + 255) / 256;
  const int gy = (N + BM - 1) / BM;

  // CSR build (shared by both layers)
  deg_count<<<eb, blk, 0, stream>>>(ei, E0, Etot, counts);
  scan_kernel<<<1, 1024, 0, stream>>>(counts, row_start, N);
  fill_csr<<<eb, blk, 0, stream>>>(ei, E0, Etot, row_start, cursor, csr_src);

  // layer 1
  gemm_f32<<<dim3(F1 / BN, gy), blk, 0, stream>>>(x, W1, h1, N, F1, 128);
  att1_kernel<<<N, 256, 0, stream>>>(h1, att_src1, att_dst1, a_src1, a_dst1);
  gather1<<<N, blk, 0, stream>>>(csr_src, row_start, a_src1, a_dst1, h1, b1,
                                 h1out);

  // layer 2
  gemm_abf16<<<dim3(F2 / BN, gy), blk, 0, stream>>>(h1out, W2, h2, N, F2, F1);
  att2_kernel<<<N, 64, 0, stream>>>(h2, att_src2, att_dst2, a_src2, a_dst2);
  gather2<<<(N + 3) / 4, blk, 0, stream>>>(csr_src, row_start, a_src2, a_dst2,
                                           h2, b2, (float*)d_out, N);
}

// Round 5
// 442.739 us; speedup vs baseline: 8.8647x; 1.4827x over previous
//
#include <hip/hip_runtime.h>
#include <hip/hip_bf16.h>
#include <cmath>

// ---------------------------------------------------------------------------
// GAT 2-layer forward. R5: bf16 h1 + LDS/shuffle-staged softmax coefs in the
// gathers; exact attention logits via pre-projected weights; grid scan.
// ---------------------------------------------------------------------------

#define HEADS1 8
#define F1 256
#define F2 64
#define NEG_SLOPE 0.2f

#define BM 64
#define BN 64
#define BK 32
#define TM 4
#define TN 4

__device__ __forceinline__ float lrelu(float x) {
  return x >= 0.f ? x : NEG_SLOPE * x;
}

// ------------------- GEMM fp32 in, bf16 out (layer 1) -----------------------
__global__ __launch_bounds__(256) void gemm_f32_bf16out(
    const float* __restrict__ A, const float* __restrict__ B,
    __hip_bfloat16* __restrict__ C, int M, int N, int K) {
  __shared__ float As[BK][BM];
  __shared__ float Bs[BK][BN];
  const int tid = threadIdx.x;
  const int row0 = blockIdx.y * BM;
  const int col0 = blockIdx.x * BN;
  const int tx = tid & 15;
  const int ty = tid >> 4;
  float acc[TM][TN] = {};
  for (int k0 = 0; k0 < K; k0 += BK) {
    #pragma unroll
    for (int i = 0; i < (BM * BK) / 256; ++i) {
      int idx = tid + i * 256;
      int m = idx >> 5, k = idx & 31;
      int gr = row0 + m;
      As[k][m] = (gr < M) ? A[(size_t)gr * K + k0 + k] : 0.f;
    }
    #pragma unroll
    for (int i = 0; i < (BK * BN) / 256; ++i) {
      int idx = tid + i * 256;
      int k = idx >> 6, n = idx & 63;
      Bs[k][n] = B[(size_t)(k0 + k) * N + col0 + n];
    }
    __syncthreads();
    #pragma unroll
    for (int k = 0; k < BK; ++k) {
      float ra[TM], rb[TN];
      #pragma unroll
      for (int i = 0; i < TM; ++i) ra[i] = As[k][ty * TM + i];
      #pragma unroll
      for (int j = 0; j < TN; ++j) rb[j] = Bs[k][tx * TN + j];
      #pragma unroll
      for (int i = 0; i < TM; ++i)
        #pragma unroll
        for (int j = 0; j < TN; ++j) acc[i][j] += ra[i] * rb[j];
    }
    __syncthreads();
  }
  #pragma unroll
  for (int i = 0; i < TM; ++i) {
    int gr = row0 + ty * TM + i;
    if (gr >= M) continue;
    #pragma unroll
    for (int j = 0; j < TN; ++j)
      C[(size_t)gr * N + col0 + tx * TN + j] = __float2bfloat16(acc[i][j]);
  }
}

// ------------------- GEMM bf16 A, fp32 B/C (layer 2) ------------------------
__global__ __launch_bounds__(256) void gemm_abf16(
    const __hip_bfloat16* __restrict__ A, const float* __restrict__ B,
    float* __restrict__ C, int M, int N, int K) {
  __shared__ float As[BK][BM];
  __shared__ float Bs[BK][BN];
  const int tid = threadIdx.x;
  const int row0 = blockIdx.y * BM;
  const int col0 = blockIdx.x * BN;
  const int tx = tid & 15;
  const int ty = tid >> 4;
  float acc[TM][TN] = {};
  for (int k0 = 0; k0 < K; k0 += BK) {
    #pragma unroll
    for (int i = 0; i < (BM * BK) / 256; ++i) {
      int idx = tid + i * 256;
      int m = idx >> 5, k = idx & 31;
      int gr = row0 + m;
      As[k][m] = (gr < M) ? __bfloat162float(A[(size_t)gr * K + k0 + k]) : 0.f;
    }
    #pragma unroll
    for (int i = 0; i < (BK * BN) / 256; ++i) {
      int idx = tid + i * 256;
      int k = idx >> 6, n = idx & 63;
      Bs[k][n] = B[(size_t)(k0 + k) * N + col0 + n];
    }
    __syncthreads();
    #pragma unroll
    for (int k = 0; k < BK; ++k) {
      float ra[TM], rb[TN];
      #pragma unroll
      for (int i = 0; i < TM; ++i) ra[i] = As[k][ty * TM + i];
      #pragma unroll
      for (int j = 0; j < TN; ++j) rb[j] = Bs[k][tx * TN + j];
      #pragma unroll
      for (int i = 0; i < TM; ++i)
        #pragma unroll
        for (int j = 0; j < TN; ++j) acc[i][j] += ra[i] * rb[j];
    }
    __syncthreads();
  }
  #pragma unroll
  for (int i = 0; i < TM; ++i) {
    int gr = row0 + ty * TM + i;
    if (gr >= M) continue;
    #pragma unroll
    for (int j = 0; j < TN; ++j)
      C[(size_t)gr * N + col0 + tx * TN + j] = acc[i][j];
  }
}

// ------------------ attention weight pre-projection -------------------------
// Wsrc1[k*8+h] = sum_c W1[k*256 + h*32+c] * att_src1[h*32+c]; same for dst.
__global__ __launch_bounds__(256) void prep_w1(
    const float* __restrict__ W1, const float* __restrict__ att_src,
    const float* __restrict__ att_dst, float* __restrict__ Wsrc,
    float* __restrict__ Wdst) {
  int idx = blockIdx.x * 256 + threadIdx.x;   // 1024 total
  if (idx >= 128 * 8) return;
  int k = idx >> 3, h = idx & 7;
  float as = 0.f, ad = 0.f;
  #pragma unroll
  for (int c = 0; c < 32; ++c) {
    float wv = W1[(size_t)k * 256 + h * 32 + c];
    as += wv * att_src[h * 32 + c];
    ad += wv * att_dst[h * 32 + c];
  }
  Wsrc[idx] = as;
  Wdst[idx] = ad;
}

// w_s2[k] = sum_c W2[k*64+c]*att_src2[c]
__global__ __launch_bounds__(256) void prep_w2(
    const float* __restrict__ W2, const float* __restrict__ att_src,
    const float* __restrict__ att_dst, float* __restrict__ ws,
    float* __restrict__ wd) {
  int k = threadIdx.x;  // 256
  float as = 0.f, ad = 0.f;
  #pragma unroll
  for (int c = 0; c < 64; ++c) {
    float wv = W2[(size_t)k * 64 + c];
    as += wv * att_src[c];
    ad += wv * att_dst[c];
  }
  ws[k] = as;
  wd[k] = ad;
}

// a_src1[n,h] = sum_k x[n,k] * Wsrc1[k,h]  (exact fp32, from x)
// block: 32 nodes x 8 heads
__global__ __launch_bounds__(256) void attproj1(
    const float* __restrict__ x, const float* __restrict__ Wsrc,
    const float* __restrict__ Wdst, float* __restrict__ a_src,
    float* __restrict__ a_dst, int n) {
  __shared__ float ws[128 * 8];
  __shared__ float wd[128 * 8];
  const int tid = threadIdx.x;
  #pragma unroll
  for (int i = 0; i < 4; ++i) {
    ws[tid + i * 256] = Wsrc[tid + i * 256];
    wd[tid + i * 256] = Wdst[tid + i * 256];
  }
  __syncthreads();
  const int node = blockIdx.x * 32 + (tid >> 3);
  const int h = tid & 7;
  if (node >= n) return;
  float as = 0.f, ad = 0.f;
  const float* xr = &x[(size_t)node * 128];
  for (int k = 0; k < 128; ++k) {
    float xv = xr[k];
    as += xv * ws[k * 8 + h];
    ad += xv * wd[k * 8 + h];
  }
  a_src[node * 8 + h] = as;
  a_dst[node * 8 + h] = ad;
}

// a_src2[n] = sum_k h1out_bf16[n,k]*w_s2[k]; wave per node, 4 waves/block
__global__ __launch_bounds__(256) void attproj2(
    const __hip_bfloat16* __restrict__ h1out, const float* __restrict__ ws,
    const float* __restrict__ wd, float* __restrict__ a_src,
    float* __restrict__ a_dst, int n) {
  __shared__ float wsl[256], wdl[256];
  const int tid = threadIdx.x;
  wsl[tid] = ws[tid];
  wdl[tid] = wd[tid];
  __syncthreads();
  const int node = blockIdx.x * 4 + (tid >> 6);
  const int lane = tid & 63;
  if (node >= n) return;
  float as = 0.f, ad = 0.f;
  #pragma unroll
  for (int j = 0; j < 4; ++j) {
    int k = lane + j * 64;
    float v = __bfloat162float(h1out[(size_t)node * F1 + k]);
    as += v * wsl[k];
    ad += v * wdl[k];
  }
  #pragma unroll
  for (int off = 32; off > 0; off >>= 1) {
    as += __shfl_xor(as, off, 64);
    ad += __shfl_xor(ad, off, 64);
  }
  if (lane == 0) {
    a_src[node] = as;
    a_dst[node] = ad;
  }
}

// ------------------------------- CSR build ----------------------------------
__global__ __launch_bounds__(256) void deg_count(
    const int* __restrict__ ei, int E0, int Etot, int* __restrict__ counts) {
  int e = blockIdx.x * 256 + threadIdx.x;
  if (e >= Etot) return;
  int d = (e < E0) ? ei[E0 + e] : (e - E0);
  atomicAdd(&counts[d], 1);
}

// grid scan, 1024 elems/block (256 thr x 4). row_start[i+1] = local incl scan.
__global__ __launch_bounds__(256) void scanA(
    const int* __restrict__ counts, int* __restrict__ row_start,
    int* __restrict__ btot, int n) {
  __shared__ int wsum[4];
  const int tid = threadIdx.x;
  const int lane = tid & 63;
  const int wid = tid >> 6;
  const int base = blockIdx.x * 1024 + tid * 4;
  int c[4], inc[4];
  #pragma unroll
  for (int j = 0; j < 4; ++j)
    c[j] = (base + j < n) ? counts[base + j] : 0;
  inc[0] = c[0];
  #pragma unroll
  for (int j = 1; j < 4; ++j) inc[j] = inc[j - 1] + c[j];
  int tsum = inc[3];
  int wincl = tsum;
  #pragma unroll
  for (int off = 1; off < 64; off <<= 1) {
    int v = __shfl_up(wincl, off, 64);
    if (lane >= off) wincl += v;
  }
  if (lane == 63) wsum[wid] = wincl;
  __syncthreads();
  int woff = 0;
  #pragma unroll
  for (int j = 0; j < 4; ++j)
    if (j < wid) woff += wsum[j];
  int prefix = woff + (wincl - tsum);   // exclusive prefix of this thread
  #pragma unroll
  for (int j = 0; j < 4; ++j)
    if (base + j < n) row_start[base + j + 1] = prefix + inc[j];
  if (tid == 255) btot[blockIdx.x] = woff + wincl;
}

__global__ __launch_bounds__(64) void scanB(const int* __restrict__ btot,
                                            int* __restrict__ boff, int nb) {
  if (threadIdx.x == 0) {
    int run = 0;
    for (int b = 0; b < nb; ++b) {
      boff[b] = run;
      run += btot[b];
    }
  }
}

__global__ __launch_bounds__(256) void scanC(int* __restrict__ row_start,
                                             const int* __restrict__ boff,
                                             int n) {
  int i = blockIdx.x * 256 + threadIdx.x;
  if (i < n) row_start[i + 1] += boff[i >> 10];
  if (i == 0) row_start[0] = 0;
}

__global__ __launch_bounds__(256) void fill_csr(
    const int* __restrict__ ei, int E0, int Etot,
    const int* __restrict__ row_start, int* __restrict__ cursor,
    int* __restrict__ csr_src) {
  int e = blockIdx.x * 256 + threadIdx.x;
  if (e >= Etot) return;
  int s, d;
  if (e < E0) { s = ei[e]; d = ei[E0 + e]; } else { s = d = e - E0; }
  int slot = row_start[d] + atomicAdd(&cursor[d], 1);
  csr_src[slot] = s;
}

// ------------------------- gather aggregation (layer 1) ---------------------
// block per dst node. Pass1: denominators (one expf per (edge,head)).
// Then 32-edge tiles: phase A = 256 threads map 1:1 to (edge,head) coefs in
// LDS; phase B = thread-per-channel fma with bf16 h1.
__global__ __launch_bounds__(256) void gather1(
    const int* __restrict__ csr_src, const int* __restrict__ row_start,
    const float* __restrict__ a_src, const float* __restrict__ a_dst,
    const __hip_bfloat16* __restrict__ h1, const float* __restrict__ b,
    __hip_bfloat16* __restrict__ out) {
  const int d = blockIdx.x;
  const int tid = threadIdx.x;
  const int rs = row_start[d];
  const int deg = row_start[d + 1] - rs;
  __shared__ float red[256];
  __shared__ float coef[256];   // [e][h] = coef[e*8+h]
  __shared__ int s_lds[32];

  const int hA = tid & 7;                    // head for pass1/phaseA
  const float adv = a_dst[d * HEADS1 + hA];

  // pass 1: denominators (slot = tid>>3 strided over edges)
  {
    const int slot = tid >> 3;
    float lsum = 0.f;
    for (int i = slot; i < deg; i += 32) {
      int s = csr_src[rs + i];
      lsum += __expf(lrelu(a_src[s * HEADS1 + hA] + adv));
    }
    red[tid] = lsum;
  }
  __syncthreads();
  #pragma unroll
  for (int off = 128; off >= 8; off >>= 1) {
    if (tid < off) red[tid] += red[tid + off];
    __syncthreads();
  }
  if (tid < 8) red[tid] = 1.f / red[tid];   // rden per head

  // tiles of 32 edges
  const int ch = tid;
  const int hh = ch >> 5;
  float acc = 0.f;
  for (int t0 = 0; t0 < deg; t0 += 32) {
    __syncthreads();   // rden ready (1st iter) / prev phase-B done
    const int nt = min(32, deg - t0);
    if (tid < nt * 8) {
      const int e = tid >> 3;
      const int s = csr_src[rs + t0 + e];
      if (hA == 0) s_lds[e] = s;
      coef[tid] = __expf(lrelu(a_src[s * HEADS1 + hA] + adv)) * red[hA];
    }
    __syncthreads();
    for (int i = 0; i < nt; ++i) {
      float hv = __bfloat162float(h1[(size_t)s_lds[i] * F1 + ch]);
      acc += coef[i * 8 + hh] * hv;
    }
  }
  out[(size_t)d * F1 + ch] = __float2bfloat16(fmaxf(acc + b[ch], 0.f));
}

// ------------------- gather aggregation (layer 2) + log_softmax -------------
// wave per dst node; coef computed once per edge by its lane, shfl-broadcast.
__global__ __launch_bounds__(256) void gather2(
    const int* __restrict__ csr_src, const int* __restrict__ row_start,
    const float* __restrict__ a_src, const float* __restrict__ a_dst,
    const float* __restrict__ h2, const float* __restrict__ b,
    float* __restrict__ out, int n) {
  const int d = blockIdx.x * 4 + (threadIdx.x >> 6);
  const int lane = threadIdx.x & 63;
  if (d >= n) return;
  const int rs = row_start[d];
  const int deg = row_start[d + 1] - rs;
  const float adv = a_dst[d];

  float lsum = 0.f;
  for (int i = lane; i < deg; i += 64) {
    int s = csr_src[rs + i];
    lsum += __expf(lrelu(a_src[s] + adv));
  }
  #pragma unroll
  for (int off = 32; off > 0; off >>= 1) lsum += __shfl_xor(lsum, off, 64);
  const float rden = 1.f / lsum;

  float acc = 0.f;
  for (int t0 = 0; t0 < deg; t0 += 64) {
    int i = t0 + lane;
    int mys = 0;
    float myc = 0.f;
    if (i < deg) {
      mys = csr_src[rs + i];
      myc = __expf(lrelu(a_src[mys] + adv)) * rden;
    }
    int nt = min(64, deg - t0);
    for (int j = 0; j < nt; ++j) {
      int s = __shfl(mys, j, 64);
      float cf = __shfl(myc, j, 64);
      acc += cf * h2[(size_t)s * F2 + lane];
    }
  }

  float v = acc + b[lane];
  float m = v;
  #pragma unroll
  for (int off = 32; off > 0; off >>= 1) m = fmaxf(m, __shfl_xor(m, off, 64));
  float ex = __expf(v - m);
  float ss = ex;
  #pragma unroll
  for (int off = 32; off > 0; off >>= 1) ss += __shfl_xor(ss, off, 64);
  out[(size_t)d * F2 + lane] = v - m - __logf(ss);
}

// ------------------------------- launch -------------------------------------
extern "C" void kernel_launch(void* const* d_in, const int* in_sizes, int n_in,
                              void* d_out, int out_size, void* d_ws,
                              size_t ws_size, hipStream_t stream) {
  const float* x        = (const float*)d_in[0];
  const int*   ei       = (const int*)d_in[1];
  const float* W1       = (const float*)d_in[2];
  const float* att_src1 = (const float*)d_in[3];
  const float* att_dst1 = (const float*)d_in[4];
  const float* b1       = (const float*)d_in[5];
  const float* W2       = (const float*)d_in[6];
  const float* att_src2 = (const float*)d_in[7];
  const float* att_dst2 = (const float*)d_in[8];
  const float* b2       = (const float*)d_in[9];

  const int N = in_sizes[0] / 128;   // 50000
  const int E0 = in_sizes[1] / 2;    // 800000
  const int Etot = E0 + N;
  const int nb1024 = (N + 1023) / 1024;

  // ---- workspace: all disjoint (~72MB) ----
  char* w = (char*)d_ws;
  size_t off = 0;
  auto alloc = [&](size_t bytes) {
    char* p = w + off;
    off += (bytes + 255) & ~(size_t)255;
    return p;
  };
  __hip_bfloat16* h1        = (__hip_bfloat16*) alloc((size_t)N * F1 * 2);  // 25.6MB
  __hip_bfloat16* h1out     = (__hip_bfloat16*) alloc((size_t)N * F1 * 2);  // 25.6MB
  float*          h2        = (float*)          alloc((size_t)N * F2 * 4);  // 12.8MB
  int*            csr_src   = (int*)            alloc((size_t)Etot * 4);    // 3.4MB
  int*            row_start = (int*)            alloc((size_t)(N + 1) * 4);
  int*            counts    = (int*)            alloc((size_t)N * 4);
  int*            cursor    = (int*)            alloc((size_t)N * 4);
  int*            btot      = (int*)            alloc((size_t)nb1024 * 4);
  int*            boff      = (int*)            alloc((size_t)nb1024 * 4);
  float*          a_src1    = (float*)          alloc((size_t)N * HEADS1 * 4);
  float*          a_dst1    = (float*)          alloc((size_t)N * HEADS1 * 4);
  float*          a_src2    = (float*)          alloc((size_t)N * 4);
  float*          a_dst2    = (float*)          alloc((size_t)N * 4);
  float*          Wsrc1     = (float*)          alloc(128 * 8 * 4);
  float*          Wdst1     = (float*)          alloc(128 * 8 * 4);
  float*          w_s2      = (float*)          alloc(256 * 4);
  float*          w_d2      = (float*)          alloc(256 * 4);

  hipMemsetAsync(counts, 0, (size_t)N * 4, stream);
  hipMemsetAsync(cursor, 0, (size_t)N * 4, stream);

  dim3 blk(256);
  const int eb = (Etot + 255) / 256;
  const int gy = (N + BM - 1) / BM;

  // CSR build
  deg_count<<<eb, blk, 0, stream>>>(ei, E0, Etot, counts);
  scanA<<<nb1024, blk, 0, stream>>>(counts, row_start, btot, N);
  scanB<<<1, 64, 0, stream>>>(btot, boff, nb1024);
  scanC<<<(N + 255) / 256, blk, 0, stream>>>(row_start, boff, N);
  fill_csr<<<eb, blk, 0, stream>>>(ei, E0, Etot, row_start, cursor, csr_src);

  // attention weight projections
  prep_w1<<<4, blk, 0, stream>>>(W1, att_src1, att_dst1, Wsrc1, Wdst1);
  prep_w2<<<1, blk, 0, stream>>>(W2, att_src2, att_dst2, w_s2, w_d2);

  // layer 1
  gemm_f32_bf16out<<<dim3(F1 / BN, gy), blk, 0, stream>>>(x, W1, h1, N, F1, 128);
  attproj1<<<(N + 31) / 32, blk, 0, stream>>>(x, Wsrc1, Wdst1, a_src1, a_dst1, N);
  gather1<<<N, blk, 0, stream>>>(csr_src, row_start, a_src1, a_dst1, h1, b1,
                                 h1out);

  // layer 2
  gemm_abf16<<<dim3(F2 / BN, gy), blk, 0, stream>>>(h1out, W2, h2, N, F2, F1);
  attproj2<<<(N + 3) / 4, blk, 0, stream>>>(h1out, w_s2, w_d2, a_src2, a_dst2, N);
  gather2<<<(N + 3) / 4, blk, 0, stream>>>(csr_src, row_start, a_src2, a_dst2,
                                           h2, b2, (float*)d_out, N);
}

// Round 8
// 375.952 us; speedup vs baseline: 10.4395x; 1.1776x over previous
//
#include <hip/hip_runtime.h>
#include <hip/hip_bf16.h>
#include <cmath>

// ---------------------------------------------------------------------------
// GAT 2-layer forward. R8 BISECT: R7's split-bf16 MFMA GEMMs + preps, with
// gathers reverted to R5's proven kernels (block-per-node gather1, sequential
// shfl gather2, separate attproj2).
// ---------------------------------------------------------------------------

#define HEADS1 8
#define F1 256
#define F2 64
#define NEG_SLOPE 0.2f

typedef unsigned int uint;
typedef unsigned short ushort_t;
typedef __attribute__((ext_vector_type(8))) short bf16x8;
typedef __attribute__((ext_vector_type(4))) float f32x4;

__device__ __forceinline__ float lrelu(float x) {
  return x >= 0.f ? x : NEG_SLOPE * x;
}
__device__ __forceinline__ ushort_t f2bf(float f) {
  uint u = __float_as_uint(f);
  return (ushort_t)((u + 0x7FFFu + ((u >> 16) & 1u)) >> 16);
}
__device__ __forceinline__ float bf2f(ushort_t u) {
  return __uint_as_float(((uint)u) << 16);
}

// ----------------------- conversion / split preps ---------------------------
__global__ __launch_bounds__(256) void cvt_split(const float* __restrict__ in,
                                                 ushort_t* __restrict__ hi,
                                                 ushort_t* __restrict__ lo,
                                                 int n) {
  int i = blockIdx.x * 256 + threadIdx.x;
  if (i >= n) return;
  float v = in[i];
  ushort_t h = f2bf(v);
  hi[i] = h;
  lo[i] = f2bf(v - bf2f(h));
}

__global__ __launch_bounds__(256) void trcvt_split(const float* __restrict__ in,
                                                   ushort_t* __restrict__ ohi,
                                                   ushort_t* __restrict__ olo,
                                                   int R, int C) {
  int idx = blockIdx.x * 256 + threadIdx.x;
  if (idx >= R * C) return;
  int r = idx / C, c = idx - r * C;
  float v = in[idx];
  ushort_t h = f2bf(v);
  ohi[(size_t)c * R + r] = h;
  olo[(size_t)c * R + r] = f2bf(v - bf2f(h));
}

// ----------------------------- MFMA GEMM (split) ----------------------------
__global__ __launch_bounds__(256) void gemm_mfma2(
    const ushort_t* __restrict__ Ah, const ushort_t* __restrict__ Al,
    const ushort_t* __restrict__ Bh, const ushort_t* __restrict__ Bl,
    ushort_t* __restrict__ Cb, float* __restrict__ Cf, int M, int N, int K) {
  __shared__ ushort_t AsH[64 * 40];
  __shared__ ushort_t AsL[64 * 40];
  __shared__ ushort_t BsH[64 * 40];
  __shared__ ushort_t BsL[64 * 40];
  const int tid = threadIdx.x;
  const int lane = tid & 63;
  const int wave = tid >> 6;
  const int wr = wave >> 1, wc = wave & 1;
  const int row0 = blockIdx.y * 64, col0 = blockIdx.x * 64;
  const int sr = tid >> 2;
  const int sk = (tid & 3) * 8;
  const int l15 = lane & 15;
  const int lk8 = (lane >> 4) * 8;

  f32x4 acc[2][2];
  #pragma unroll
  for (int i = 0; i < 2; ++i)
    #pragma unroll
    for (int j = 0; j < 2; ++j) acc[i][j] = (f32x4){0.f, 0.f, 0.f, 0.f};

  for (int k0 = 0; k0 < K; k0 += 32) {
    const int gr = row0 + sr;
    uint4 av = {0u, 0u, 0u, 0u};
    if (gr < M) av = *(const uint4*)&Ah[(size_t)gr * K + k0 + sk];
    *(uint4*)&AsH[sr * 40 + sk] = av;
    if (Al) {
      uint4 avl = {0u, 0u, 0u, 0u};
      if (gr < M) avl = *(const uint4*)&Al[(size_t)gr * K + k0 + sk];
      *(uint4*)&AsL[sr * 40 + sk] = avl;
    }
    uint4 bv = *(const uint4*)&Bh[(size_t)(col0 + sr) * K + k0 + sk];
    *(uint4*)&BsH[sr * 40 + sk] = bv;
    if (Bl) {
      uint4 bvl = *(const uint4*)&Bl[(size_t)(col0 + sr) * K + k0 + sk];
      *(uint4*)&BsL[sr * 40 + sk] = bvl;
    }
    __syncthreads();

    bf16x8 afh[2], bfh[2];
    #pragma unroll
    for (int mi = 0; mi < 2; ++mi)
      afh[mi] = *(const bf16x8*)&AsH[(wr * 32 + mi * 16 + l15) * 40 + lk8];
    #pragma unroll
    for (int ni = 0; ni < 2; ++ni)
      bfh[ni] = *(const bf16x8*)&BsH[(wc * 32 + ni * 16 + l15) * 40 + lk8];
    #pragma unroll
    for (int mi = 0; mi < 2; ++mi)
      #pragma unroll
      for (int ni = 0; ni < 2; ++ni)
        acc[mi][ni] = __builtin_amdgcn_mfma_f32_16x16x32_bf16(
            afh[mi], bfh[ni], acc[mi][ni], 0, 0, 0);
    if (Al) {
      bf16x8 afl[2];
      #pragma unroll
      for (int mi = 0; mi < 2; ++mi)
        afl[mi] = *(const bf16x8*)&AsL[(wr * 32 + mi * 16 + l15) * 40 + lk8];
      #pragma unroll
      for (int mi = 0; mi < 2; ++mi)
        #pragma unroll
        for (int ni = 0; ni < 2; ++ni)
          acc[mi][ni] = __builtin_amdgcn_mfma_f32_16x16x32_bf16(
              afl[mi], bfh[ni], acc[mi][ni], 0, 0, 0);
    }
    if (Bl) {
      bf16x8 bfl[2];
      #pragma unroll
      for (int ni = 0; ni < 2; ++ni)
        bfl[ni] = *(const bf16x8*)&BsL[(wc * 32 + ni * 16 + l15) * 40 + lk8];
      #pragma unroll
      for (int mi = 0; mi < 2; ++mi)
        #pragma unroll
        for (int ni = 0; ni < 2; ++ni)
          acc[mi][ni] = __builtin_amdgcn_mfma_f32_16x16x32_bf16(
              afh[mi], bfl[ni], acc[mi][ni], 0, 0, 0);
    }
    __syncthreads();
  }

  #pragma unroll
  for (int mi = 0; mi < 2; ++mi) {
    #pragma unroll
    for (int ni = 0; ni < 2; ++ni) {
      #pragma unroll
      for (int r = 0; r < 4; ++r) {
        int grow = row0 + wr * 32 + mi * 16 + (lane >> 4) * 4 + r;
        int gcol = col0 + wc * 32 + ni * 16 + l15;
        if (grow < M) {
          float v = acc[mi][ni][r];
          if (Cb) Cb[(size_t)grow * N + gcol] = f2bf(v);
          else    Cf[(size_t)grow * N + gcol] = v;
        }
      }
    }
  }
}

// ------------------ attention weight pre-projection (fp32 exact) ------------
__global__ __launch_bounds__(256) void prep_w1(
    const float* __restrict__ W1, const float* __restrict__ att_src,
    const float* __restrict__ att_dst, float* __restrict__ Wsrc,
    float* __restrict__ Wdst) {
  int idx = blockIdx.x * 256 + threadIdx.x;
  if (idx >= 128 * 8) return;
  int k = idx >> 3, h = idx & 7;
  float as = 0.f, ad = 0.f;
  #pragma unroll
  for (int c = 0; c < 32; ++c) {
    float wv = W1[(size_t)k * 256 + h * 32 + c];
    as += wv * att_src[h * 32 + c];
    ad += wv * att_dst[h * 32 + c];
  }
  Wsrc[idx] = as;
  Wdst[idx] = ad;
}

__global__ __launch_bounds__(256) void prep_w2(
    const float* __restrict__ W2, const float* __restrict__ att_src,
    const float* __restrict__ att_dst, float* __restrict__ ws,
    float* __restrict__ wd) {
  int k = threadIdx.x;
  float as = 0.f, ad = 0.f;
  #pragma unroll
  for (int c = 0; c < 64; ++c) {
    float wv = W2[(size_t)k * 64 + c];
    as += wv * att_src[c];
    ad += wv * att_dst[c];
  }
  ws[k] = as;
  wd[k] = ad;
}

__global__ __launch_bounds__(256) void attproj1(
    const float* __restrict__ x, const float* __restrict__ Wsrc,
    const float* __restrict__ Wdst, float* __restrict__ a_src,
    float* __restrict__ a_dst, int n) {
  __shared__ float ws[128 * 8];
  __shared__ float wd[128 * 8];
  const int tid = threadIdx.x;
  #pragma unroll
  for (int i = 0; i < 4; ++i) {
    ws[tid + i * 256] = Wsrc[tid + i * 256];
    wd[tid + i * 256] = Wdst[tid + i * 256];
  }
  __syncthreads();
  const int node = blockIdx.x * 32 + (tid >> 3);
  const int h = tid & 7;
  if (node >= n) return;
  float as = 0.f, ad = 0.f;
  const float* xr = &x[(size_t)node * 128];
  for (int k = 0; k < 128; ++k) {
    float xv = xr[k];
    as += xv * ws[k * 8 + h];
    ad += xv * wd[k * 8 + h];
  }
  a_src[node * 8 + h] = as;
  a_dst[node * 8 + h] = ad;
}

// R5's attproj2: a_src2[n] = sum_k h1out[n,k]*ws[k]; wave per node
__global__ __launch_bounds__(256) void attproj2(
    const ushort_t* __restrict__ h1out, const float* __restrict__ ws,
    const float* __restrict__ wd, float* __restrict__ a_src,
    float* __restrict__ a_dst, int n) {
  __shared__ float wsl[256], wdl[256];
  const int tid = threadIdx.x;
  wsl[tid] = ws[tid];
  wdl[tid] = wd[tid];
  __syncthreads();
  const int node = blockIdx.x * 4 + (tid >> 6);
  const int lane = tid & 63;
  if (node >= n) return;
  float as = 0.f, ad = 0.f;
  #pragma unroll
  for (int j = 0; j < 4; ++j) {
    int k = lane + j * 64;
    float v = bf2f(h1out[(size_t)node * F1 + k]);
    as += v * wsl[k];
    ad += v * wdl[k];
  }
  #pragma unroll
  for (int off = 32; off > 0; off >>= 1) {
    as += __shfl_xor(as, off, 64);
    ad += __shfl_xor(ad, off, 64);
  }
  if (lane == 0) {
    a_src[node] = as;
    a_dst[node] = ad;
  }
}

// ------------------------------- CSR build ----------------------------------
__global__ __launch_bounds__(256) void deg_count(
    const int* __restrict__ ei, int E0, int Etot, int* __restrict__ counts) {
  int e = blockIdx.x * 256 + threadIdx.x;
  if (e >= Etot) return;
  int d = (e < E0) ? ei[E0 + e] : (e - E0);
  atomicAdd(&counts[d], 1);
}

__global__ __launch_bounds__(256) void scanA(
    const int* __restrict__ counts, int* __restrict__ row_start,
    int* __restrict__ btot, int n) {
  __shared__ int wsum[4];
  const int tid = threadIdx.x;
  const int lane = tid & 63;
  const int wid = tid >> 6;
  const int base = blockIdx.x * 1024 + tid * 4;
  int c[4], inc[4];
  #pragma unroll
  for (int j = 0; j < 4; ++j)
    c[j] = (base + j < n) ? counts[base + j] : 0;
  inc[0] = c[0];
  #pragma unroll
  for (int j = 1; j < 4; ++j) inc[j] = inc[j - 1] + c[j];
  int tsum = inc[3];
  int wincl = tsum;
  #pragma unroll
  for (int off = 1; off < 64; off <<= 1) {
    int v = __shfl_up(wincl, off, 64);
    if (lane >= off) wincl += v;
  }
  if (lane == 63) wsum[wid] = wincl;
  __syncthreads();
  int woff = 0;
  #pragma unroll
  for (int j = 0; j < 4; ++j)
    if (j < wid) woff += wsum[j];
  int prefix = woff + (wincl - tsum);
  #pragma unroll
  for (int j = 0; j < 4; ++j)
    if (base + j < n) row_start[base + j + 1] = prefix + inc[j];
  if (tid == 255) btot[blockIdx.x] = woff + wincl;
}

__global__ __launch_bounds__(64) void scanB(const int* __restrict__ btot,
                                            int* __restrict__ boff, int nb) {
  if (threadIdx.x == 0) {
    int run = 0;
    for (int b = 0; b < nb; ++b) {
      boff[b] = run;
      run += btot[b];
    }
  }
}

__global__ __launch_bounds__(256) void scanC(int* __restrict__ row_start,
                                             const int* __restrict__ boff,
                                             int n) {
  int i = blockIdx.x * 256 + threadIdx.x;
  if (i < n) row_start[i + 1] += boff[i >> 10];
  if (i == 0) row_start[0] = 0;
}

__global__ __launch_bounds__(256) void fill_csr(
    const int* __restrict__ ei, int E0, int Etot,
    const int* __restrict__ row_start, int* __restrict__ cursor,
    int* __restrict__ csr_src) {
  int e = blockIdx.x * 256 + threadIdx.x;
  if (e >= Etot) return;
  int s, d;
  if (e < E0) { s = ei[e]; d = ei[E0 + e]; } else { s = d = e - E0; }
  int slot = row_start[d] + atomicAdd(&cursor[d], 1);
  csr_src[slot] = s;
}

// ------------------ gather layer 1 (R5: block per node) ---------------------
__global__ __launch_bounds__(256) void gather1(
    const int* __restrict__ csr_src, const int* __restrict__ row_start,
    const float* __restrict__ a_src, const float* __restrict__ a_dst,
    const ushort_t* __restrict__ h1, const float* __restrict__ b,
    ushort_t* __restrict__ out) {
  const int d = blockIdx.x;
  const int tid = threadIdx.x;
  const int rs = row_start[d];
  const int deg = row_start[d + 1] - rs;
  __shared__ float red[256];
  __shared__ float coef[256];   // [e][h]
  __shared__ int s_lds[32];

  const int hA = tid & 7;
  const float adv = a_dst[d * HEADS1 + hA];

  {
    const int slot = tid >> 3;
    float lsum = 0.f;
    for (int i = slot; i < deg; i += 32) {
      int s = csr_src[rs + i];
      lsum += __expf(lrelu(a_src[s * HEADS1 + hA] + adv));
    }
    red[tid] = lsum;
  }
  __syncthreads();
  #pragma unroll
  for (int off = 128; off >= 8; off >>= 1) {
    if (tid < off) red[tid] += red[tid + off];
    __syncthreads();
  }
  if (tid < 8) red[tid] = 1.f / red[tid];

  const int ch = tid;
  const int hh = ch >> 5;
  float acc = 0.f;
  for (int t0 = 0; t0 < deg; t0 += 32) {
    __syncthreads();
    const int nt = min(32, deg - t0);
    if (tid < nt * 8) {
      const int e = tid >> 3;
      const int s = csr_src[rs + t0 + e];
      if (hA == 0) s_lds[e] = s;
      coef[tid] = __expf(lrelu(a_src[s * HEADS1 + hA] + adv)) * red[hA];
    }
    __syncthreads();
    for (int i = 0; i < nt; ++i) {
      float hv = bf2f(h1[(size_t)s_lds[i] * F1 + ch]);
      acc += coef[i * 8 + hh] * hv;
    }
  }
  out[(size_t)d * F1 + ch] = f2bf(fmaxf(acc + b[ch], 0.f));
}

// --------- gather layer 2 + log_softmax (R5: wave/node sequential) ----------
__global__ __launch_bounds__(256) void gather2(
    const int* __restrict__ csr_src, const int* __restrict__ row_start,
    const float* __restrict__ a_src, const float* __restrict__ a_dst,
    const float* __restrict__ h2, const float* __restrict__ b,
    float* __restrict__ out, int n) {
  const int d = blockIdx.x * 4 + (threadIdx.x >> 6);
  const int lane = threadIdx.x & 63;
  if (d >= n) return;
  const int rs = row_start[d];
  const int deg = row_start[d + 1] - rs;
  const float adv = a_dst[d];

  float lsum = 0.f;
  for (int i = lane; i < deg; i += 64) {
    int s = csr_src[rs + i];
    lsum += __expf(lrelu(a_src[s] + adv));
  }
  #pragma unroll
  for (int off = 32; off > 0; off >>= 1) lsum += __shfl_xor(lsum, off, 64);
  const float rden = 1.f / lsum;

  float acc = 0.f;
  for (int t0 = 0; t0 < deg; t0 += 64) {
    int myi = t0 + lane;
    int mys = 0;
    float myc = 0.f;
    if (myi < deg) {
      mys = csr_src[rs + myi];
      myc = __expf(lrelu(a_src[mys] + adv)) * rden;
    }
    int nt = min(64, deg - t0);
    for (int j = 0; j < nt; ++j) {
      int s = __shfl(mys, j, 64);
      float cf = __shfl(myc, j, 64);
      acc += cf * h2[(size_t)s * F2 + lane];
    }
  }

  float v = acc + b[lane];
  float m = v;
  #pragma unroll
  for (int off = 32; off > 0; off >>= 1) m = fmaxf(m, __shfl_xor(m, off, 64));
  float ex = __expf(v - m);
  float ss = ex;
  #pragma unroll
  for (int off = 32; off > 0; off >>= 1) ss += __shfl_xor(ss, off, 64);
  out[(size_t)d * F2 + lane] = v - m - __logf(ss);
}

// ------------------------------- launch -------------------------------------
extern "C" void kernel_launch(void* const* d_in, const int* in_sizes, int n_in,
                              void* d_out, int out_size, void* d_ws,
                              size_t ws_size, hipStream_t stream) {
  const float* x        = (const float*)d_in[0];
  const int*   ei       = (const int*)d_in[1];
  const float* W1       = (const float*)d_in[2];
  const float* att_src1 = (const float*)d_in[3];
  const float* att_dst1 = (const float*)d_in[4];
  const float* b1       = (const float*)d_in[5];
  const float* W2       = (const float*)d_in[6];
  const float* att_src2 = (const float*)d_in[7];
  const float* att_dst2 = (const float*)d_in[8];
  const float* b2       = (const float*)d_in[9];

  const int N = in_sizes[0] / 128;
  const int E0 = in_sizes[1] / 2;
  const int Etot = E0 + N;
  const int nb1024 = (N + 1023) / 1024;

  char* w = (char*)d_ws;
  size_t off = 0;
  auto alloc = [&](size_t bytes) {
    char* p = w + off;
    off += (bytes + 255) & ~(size_t)255;
    return p;
  };
  ushort_t* xb_hi     = (ushort_t*)alloc((size_t)N * 128 * 2);
  ushort_t* xb_lo     = (ushort_t*)alloc((size_t)N * 128 * 2);
  ushort_t* h1        = (ushort_t*)alloc((size_t)N * F1 * 2);
  ushort_t* h1out     = (ushort_t*)alloc((size_t)N * F1 * 2);
  float*    h2        = (float*)   alloc((size_t)N * F2 * 4);
  int*      csr_src   = (int*)     alloc((size_t)Etot * 4);
  int*      row_start = (int*)     alloc((size_t)(N + 1) * 4);
  int*      counts    = (int*)     alloc((size_t)N * 4);
  int*      cursor    = (int*)     alloc((size_t)N * 4);
  int*      btot      = (int*)     alloc((size_t)nb1024 * 4);
  int*      boff      = (int*)     alloc((size_t)nb1024 * 4);
  float*    a_src1    = (float*)   alloc((size_t)N * HEADS1 * 4);
  float*    a_dst1    = (float*)   alloc((size_t)N * HEADS1 * 4);
  float*    a_src2    = (float*)   alloc((size_t)N * 4);
  float*    a_dst2    = (float*)   alloc((size_t)N * 4);
  ushort_t* W1t_hi    = (ushort_t*)alloc(128 * 256 * 2);
  ushort_t* W1t_lo    = (ushort_t*)alloc(128 * 256 * 2);
  ushort_t* W2t_hi    = (ushort_t*)alloc(256 * 64 * 2);
  ushort_t* W2t_lo    = (ushort_t*)alloc(256 * 64 * 2);
  float*    Wsrc1     = (float*)   alloc(128 * 8 * 4);
  float*    Wdst1     = (float*)   alloc(128 * 8 * 4);
  float*    w_s2      = (float*)   alloc(256 * 4);
  float*    w_d2      = (float*)   alloc(256 * 4);

  hipMemsetAsync(counts, 0, (size_t)N * 4, stream);
  hipMemsetAsync(cursor, 0, (size_t)N * 4, stream);

  dim3 blk(256);
  const int eb = (Etot + 255) / 256;
  const int gy = (N + 63) / 64;

  deg_count<<<eb, blk, 0, stream>>>(ei, E0, Etot, counts);
  scanA<<<nb1024, blk, 0, stream>>>(counts, row_start, btot, N);
  scanB<<<1, 64, 0, stream>>>(btot, boff, nb1024);
  scanC<<<(N + 255) / 256, blk, 0, stream>>>(row_start, boff, N);
  fill_csr<<<eb, blk, 0, stream>>>(ei, E0, Etot, row_start, cursor, csr_src);

  cvt_split<<<((size_t)N * 128 + 255) / 256, blk, 0, stream>>>(x, xb_hi, xb_lo,
                                                               N * 128);
  trcvt_split<<<(128 * 256 + 255) / 256, blk, 0, stream>>>(W1, W1t_hi, W1t_lo,
                                                           128, 256);
  trcvt_split<<<(256 * 64 + 255) / 256, blk, 0, stream>>>(W2, W2t_hi, W2t_lo,
                                                          256, 64);
  prep_w1<<<4, blk, 0, stream>>>(W1, att_src1, att_dst1, Wsrc1, Wdst1);
  prep_w2<<<1, blk, 0, stream>>>(W2, att_src2, att_dst2, w_s2, w_d2);

  // layer 1
  gemm_mfma2<<<dim3(F1 / 64, gy), blk, 0, stream>>>(
      xb_hi, xb_lo, W1t_hi, W1t_lo, h1, (float*)nullptr, N, F1, 128);
  attproj1<<<(N + 31) / 32, blk, 0, stream>>>(x, Wsrc1, Wdst1, a_src1, a_dst1, N);
  gather1<<<N, blk, 0, stream>>>(csr_src, row_start, a_src1, a_dst1, h1, b1,
                                 h1out);

  // layer 2
  gemm_mfma2<<<dim3(F2 / 64, gy), blk, 0, stream>>>(
      h1out, (const ushort_t*)nullptr, W2t_hi, W2t_lo, (ushort_t*)nullptr, h2,
      N, F2, F1);
  attproj2<<<(N + 3) / 4, blk, 0, stream>>>(h1out, w_s2, w_d2, a_src2, a_dst2, N);
  gather2<<<(N + 3) / 4, blk, 0, stream>>>(csr_src, row_start, a_src2, a_dst2,
                                           h2, b2, (float*)d_out, N);
}

// Round 9
// 356.312 us; speedup vs baseline: 11.0150x; 1.0551x over previous
//
#include <hip/hip_runtime.h>
#include <hip/hip_bf16.h>
#include <cmath>

// ---------------------------------------------------------------------------
// GAT 2-layer forward. R9: R8 base (split-bf16 MFMA GEMMs + proven gathers)
// with gather1 accumulation re-tiled to 4-edge-parallel ushort4 loads and
// h2 stored bf16 (halves gather2 L3 traffic).
// ---------------------------------------------------------------------------

#define HEADS1 8
#define F1 256
#define F2 64
#define NEG_SLOPE 0.2f

typedef unsigned int uint;
typedef unsigned short ushort_t;
typedef __attribute__((ext_vector_type(8))) short bf16x8;
typedef __attribute__((ext_vector_type(4))) float f32x4;

__device__ __forceinline__ float lrelu(float x) {
  return x >= 0.f ? x : NEG_SLOPE * x;
}
__device__ __forceinline__ ushort_t f2bf(float f) {
  uint u = __float_as_uint(f);
  return (ushort_t)((u + 0x7FFFu + ((u >> 16) & 1u)) >> 16);
}
__device__ __forceinline__ float bf2f(ushort_t u) {
  return __uint_as_float(((uint)u) << 16);
}

// ----------------------- conversion / split preps ---------------------------
__global__ __launch_bounds__(256) void cvt_split(const float* __restrict__ in,
                                                 ushort_t* __restrict__ hi,
                                                 ushort_t* __restrict__ lo,
                                                 int n) {
  int i = blockIdx.x * 256 + threadIdx.x;
  if (i >= n) return;
  float v = in[i];
  ushort_t h = f2bf(v);
  hi[i] = h;
  lo[i] = f2bf(v - bf2f(h));
}

__global__ __launch_bounds__(256) void trcvt_split(const float* __restrict__ in,
                                                   ushort_t* __restrict__ ohi,
                                                   ushort_t* __restrict__ olo,
                                                   int R, int C) {
  int idx = blockIdx.x * 256 + threadIdx.x;
  if (idx >= R * C) return;
  int r = idx / C, c = idx - r * C;
  float v = in[idx];
  ushort_t h = f2bf(v);
  ohi[(size_t)c * R + r] = h;
  olo[(size_t)c * R + r] = f2bf(v - bf2f(h));
}

// ----------------------------- MFMA GEMM (split) ----------------------------
__global__ __launch_bounds__(256) void gemm_mfma2(
    const ushort_t* __restrict__ Ah, const ushort_t* __restrict__ Al,
    const ushort_t* __restrict__ Bh, const ushort_t* __restrict__ Bl,
    ushort_t* __restrict__ Cb, float* __restrict__ Cf, int M, int N, int K) {
  __shared__ ushort_t AsH[64 * 40];
  __shared__ ushort_t AsL[64 * 40];
  __shared__ ushort_t BsH[64 * 40];
  __shared__ ushort_t BsL[64 * 40];
  const int tid = threadIdx.x;
  const int lane = tid & 63;
  const int wave = tid >> 6;
  const int wr = wave >> 1, wc = wave & 1;
  const int row0 = blockIdx.y * 64, col0 = blockIdx.x * 64;
  const int sr = tid >> 2;
  const int sk = (tid & 3) * 8;
  const int l15 = lane & 15;
  const int lk8 = (lane >> 4) * 8;

  f32x4 acc[2][2];
  #pragma unroll
  for (int i = 0; i < 2; ++i)
    #pragma unroll
    for (int j = 0; j < 2; ++j) acc[i][j] = (f32x4){0.f, 0.f, 0.f, 0.f};

  for (int k0 = 0; k0 < K; k0 += 32) {
    const int gr = row0 + sr;
    uint4 av = {0u, 0u, 0u, 0u};
    if (gr < M) av = *(const uint4*)&Ah[(size_t)gr * K + k0 + sk];
    *(uint4*)&AsH[sr * 40 + sk] = av;
    if (Al) {
      uint4 avl = {0u, 0u, 0u, 0u};
      if (gr < M) avl = *(const uint4*)&Al[(size_t)gr * K + k0 + sk];
      *(uint4*)&AsL[sr * 40 + sk] = avl;
    }
    uint4 bv = *(const uint4*)&Bh[(size_t)(col0 + sr) * K + k0 + sk];
    *(uint4*)&BsH[sr * 40 + sk] = bv;
    if (Bl) {
      uint4 bvl = *(const uint4*)&Bl[(size_t)(col0 + sr) * K + k0 + sk];
      *(uint4*)&BsL[sr * 40 + sk] = bvl;
    }
    __syncthreads();

    bf16x8 afh[2], bfh[2];
    #pragma unroll
    for (int mi = 0; mi < 2; ++mi)
      afh[mi] = *(const bf16x8*)&AsH[(wr * 32 + mi * 16 + l15) * 40 + lk8];
    #pragma unroll
    for (int ni = 0; ni < 2; ++ni)
      bfh[ni] = *(const bf16x8*)&BsH[(wc * 32 + ni * 16 + l15) * 40 + lk8];
    #pragma unroll
    for (int mi = 0; mi < 2; ++mi)
      #pragma unroll
      for (int ni = 0; ni < 2; ++ni)
        acc[mi][ni] = __builtin_amdgcn_mfma_f32_16x16x32_bf16(
            afh[mi], bfh[ni], acc[mi][ni], 0, 0, 0);
    if (Al) {
      bf16x8 afl[2];
      #pragma unroll
      for (int mi = 0; mi < 2; ++mi)
        afl[mi] = *(const bf16x8*)&AsL[(wr * 32 + mi * 16 + l15) * 40 + lk8];
      #pragma unroll
      for (int mi = 0; mi < 2; ++mi)
        #pragma unroll
        for (int ni = 0; ni < 2; ++ni)
          acc[mi][ni] = __builtin_amdgcn_mfma_f32_16x16x32_bf16(
              afl[mi], bfh[ni], acc[mi][ni], 0, 0, 0);
    }
    if (Bl) {
      bf16x8 bfl[2];
      #pragma unroll
      for (int ni = 0; ni < 2; ++ni)
        bfl[ni] = *(const bf16x8*)&BsL[(wc * 32 + ni * 16 + l15) * 40 + lk8];
      #pragma unroll
      for (int mi = 0; mi < 2; ++mi)
        #pragma unroll
        for (int ni = 0; ni < 2; ++ni)
          acc[mi][ni] = __builtin_amdgcn_mfma_f32_16x16x32_bf16(
              afh[mi], bfl[ni], acc[mi][ni], 0, 0, 0);
    }
    __syncthreads();
  }

  #pragma unroll
  for (int mi = 0; mi < 2; ++mi) {
    #pragma unroll
    for (int ni = 0; ni < 2; ++ni) {
      #pragma unroll
      for (int r = 0; r < 4; ++r) {
        int grow = row0 + wr * 32 + mi * 16 + (lane >> 4) * 4 + r;
        int gcol = col0 + wc * 32 + ni * 16 + l15;
        if (grow < M) {
          float v = acc[mi][ni][r];
          if (Cb) Cb[(size_t)grow * N + gcol] = f2bf(v);
          else    Cf[(size_t)grow * N + gcol] = v;
        }
      }
    }
  }
}

// ------------------ attention weight pre-projection (fp32 exact) ------------
__global__ __launch_bounds__(256) void prep_w1(
    const float* __restrict__ W1, const float* __restrict__ att_src,
    const float* __restrict__ att_dst, float* __restrict__ Wsrc,
    float* __restrict__ Wdst) {
  int idx = blockIdx.x * 256 + threadIdx.x;
  if (idx >= 128 * 8) return;
  int k = idx >> 3, h = idx & 7;
  float as = 0.f, ad = 0.f;
  #pragma unroll
  for (int c = 0; c < 32; ++c) {
    float wv = W1[(size_t)k * 256 + h * 32 + c];
    as += wv * att_src[h * 32 + c];
    ad += wv * att_dst[h * 32 + c];
  }
  Wsrc[idx] = as;
  Wdst[idx] = ad;
}

__global__ __launch_bounds__(256) void prep_w2(
    const float* __restrict__ W2, const float* __restrict__ att_src,
    const float* __restrict__ att_dst, float* __restrict__ ws,
    float* __restrict__ wd) {
  int k = threadIdx.x;
  float as = 0.f, ad = 0.f;
  #pragma unroll
  for (int c = 0; c < 64; ++c) {
    float wv = W2[(size_t)k * 64 + c];
    as += wv * att_src[c];
    ad += wv * att_dst[c];
  }
  ws[k] = as;
  wd[k] = ad;
}

__global__ __launch_bounds__(256) void attproj1(
    const float* __restrict__ x, const float* __restrict__ Wsrc,
    const float* __restrict__ Wdst, float* __restrict__ a_src,
    float* __restrict__ a_dst, int n) {
  __shared__ float ws[128 * 8];
  __shared__ float wd[128 * 8];
  const int tid = threadIdx.x;
  #pragma unroll
  for (int i = 0; i < 4; ++i) {
    ws[tid + i * 256] = Wsrc[tid + i * 256];
    wd[tid + i * 256] = Wdst[tid + i * 256];
  }
  __syncthreads();
  const int node = blockIdx.x * 32 + (tid >> 3);
  const int h = tid & 7;
  if (node >= n) return;
  float as = 0.f, ad = 0.f;
  const float* xr = &x[(size_t)node * 128];
  for (int k = 0; k < 128; ++k) {
    float xv = xr[k];
    as += xv * ws[k * 8 + h];
    ad += xv * wd[k * 8 + h];
  }
  a_src[node * 8 + h] = as;
  a_dst[node * 8 + h] = ad;
}

// attproj2: a_src2[n] = sum_k h1out[n,k]*ws[k]; wave per node
__global__ __launch_bounds__(256) void attproj2(
    const ushort_t* __restrict__ h1out, const float* __restrict__ ws,
    const float* __restrict__ wd, float* __restrict__ a_src,
    float* __restrict__ a_dst, int n) {
  __shared__ float wsl[256], wdl[256];
  const int tid = threadIdx.x;
  wsl[tid] = ws[tid];
  wdl[tid] = wd[tid];
  __syncthreads();
  const int node = blockIdx.x * 4 + (tid >> 6);
  const int lane = tid & 63;
  if (node >= n) return;
  float as = 0.f, ad = 0.f;
  #pragma unroll
  for (int j = 0; j < 4; ++j) {
    int k = lane + j * 64;
    float v = bf2f(h1out[(size_t)node * F1 + k]);
    as += v * wsl[k];
    ad += v * wdl[k];
  }
  #pragma unroll
  for (int off = 32; off > 0; off >>= 1) {
    as += __shfl_xor(as, off, 64);
    ad += __shfl_xor(ad, off, 64);
  }
  if (lane == 0) {
    a_src[node] = as;
    a_dst[node] = ad;
  }
}

// ------------------------------- CSR build ----------------------------------
__global__ __launch_bounds__(256) void deg_count(
    const int* __restrict__ ei, int E0, int Etot, int* __restrict__ counts) {
  int e = blockIdx.x * 256 + threadIdx.x;
  if (e >= Etot) return;
  int d = (e < E0) ? ei[E0 + e] : (e - E0);
  atomicAdd(&counts[d], 1);
}

__global__ __launch_bounds__(256) void scanA(
    const int* __restrict__ counts, int* __restrict__ row_start,
    int* __restrict__ btot, int n) {
  __shared__ int wsum[4];
  const int tid = threadIdx.x;
  const int lane = tid & 63;
  const int wid = tid >> 6;
  const int base = blockIdx.x * 1024 + tid * 4;
  int c[4], inc[4];
  #pragma unroll
  for (int j = 0; j < 4; ++j)
    c[j] = (base + j < n) ? counts[base + j] : 0;
  inc[0] = c[0];
  #pragma unroll
  for (int j = 1; j < 4; ++j) inc[j] = inc[j - 1] + c[j];
  int tsum = inc[3];
  int wincl = tsum;
  #pragma unroll
  for (int off = 1; off < 64; off <<= 1) {
    int v = __shfl_up(wincl, off, 64);
    if (lane >= off) wincl += v;
  }
  if (lane == 63) wsum[wid] = wincl;
  __syncthreads();
  int woff = 0;
  #pragma unroll
  for (int j = 0; j < 4; ++j)
    if (j < wid) woff += wsum[j];
  int prefix = woff + (wincl - tsum);
  #pragma unroll
  for (int j = 0; j < 4; ++j)
    if (base + j < n) row_start[base + j + 1] = prefix + inc[j];
  if (tid == 255) btot[blockIdx.x] = woff + wincl;
}

__global__ __launch_bounds__(64) void scanB(const int* __restrict__ btot,
                                            int* __restrict__ boff, int nb) {
  if (threadIdx.x == 0) {
    int run = 0;
    for (int b = 0; b < nb; ++b) {
      boff[b] = run;
      run += btot[b];
    }
  }
}

__global__ __launch_bounds__(256) void scanC(int* __restrict__ row_start,
                                             const int* __restrict__ boff,
                                             int n) {
  int i = blockIdx.x * 256 + threadIdx.x;
  if (i < n) row_start[i + 1] += boff[i >> 10];
  if (i == 0) row_start[0] = 0;
}

__global__ __launch_bounds__(256) void fill_csr(
    const int* __restrict__ ei, int E0, int Etot,
    const int* __restrict__ row_start, int* __restrict__ cursor,
    int* __restrict__ csr_src) {
  int e = blockIdx.x * 256 + threadIdx.x;
  if (e >= Etot) return;
  int s, d;
  if (e < E0) { s = ei[e]; d = ei[E0 + e]; } else { s = d = e - E0; }
  int slot = row_start[d] + atomicAdd(&cursor[d], 1);
  csr_src[slot] = s;
}

// ------------------ gather layer 1 (block per node, 4-edge ushort4) ---------
// Pass 1 + coef phase identical to R8 (proven). Accumulation: thread
// (wv=tid>>6, cg=tid&63) handles edges i==wv mod 4, channels cg*4..cg*4+3
// via ushort4 loads; final 4-way cross-wave LDS reduce.
__global__ __launch_bounds__(256) void gather1(
    const int* __restrict__ csr_src, const int* __restrict__ row_start,
    const float* __restrict__ a_src, const float* __restrict__ a_dst,
    const ushort_t* __restrict__ h1, const float* __restrict__ b,
    ushort_t* __restrict__ out) {
  const int d = blockIdx.x;
  const int tid = threadIdx.x;
  const int rs = row_start[d];
  const int deg = row_start[d + 1] - rs;
  __shared__ float red[256];
  __shared__ float coef[256];   // [e][h]
  __shared__ int s_lds[32];
  __shared__ float part[256][4];

  const int hA = tid & 7;
  const float adv = a_dst[d * HEADS1 + hA];

  // pass 1: denominators (identical to R8)
  {
    const int slot = tid >> 3;
    float lsum = 0.f;
    for (int i = slot; i < deg; i += 32) {
      int s = csr_src[rs + i];
      lsum += __expf(lrelu(a_src[s * HEADS1 + hA] + adv));
    }
    red[tid] = lsum;
  }
  __syncthreads();
  #pragma unroll
  for (int off = 128; off >= 8; off >>= 1) {
    if (tid < off) red[tid] += red[tid + off];
    __syncthreads();
  }
  if (tid < 8) red[tid] = 1.f / red[tid];

  // accumulation: 4 edge sub-slots x 64 channel-quads
  const int wv = tid >> 6;       // edge sub-slot
  const int cg = tid & 63;       // channel quad
  const int hh = cg >> 3;        // head of channels cg*4..cg*4+3
  f32x4 acc = {0.f, 0.f, 0.f, 0.f};
  for (int t0 = 0; t0 < deg; t0 += 32) {
    __syncthreads();
    const int nt = min(32, deg - t0);
    if (tid < nt * 8) {
      const int e = tid >> 3;
      const int s = csr_src[rs + t0 + e];
      if (hA == 0) s_lds[e] = s;
      coef[tid] = __expf(lrelu(a_src[s * HEADS1 + hA] + adv)) * red[hA];
    }
    __syncthreads();
    for (int i = wv; i < nt; i += 4) {
      const int s = s_lds[i];
      const float cf = coef[i * 8 + hh];
      ushort4 hv = *(const ushort4*)&h1[(size_t)s * F1 + cg * 4];
      acc[0] += cf * bf2f(hv.x);
      acc[1] += cf * bf2f(hv.y);
      acc[2] += cf * bf2f(hv.z);
      acc[3] += cf * bf2f(hv.w);
    }
  }
  part[tid][0] = acc[0];
  part[tid][1] = acc[1];
  part[tid][2] = acc[2];
  part[tid][3] = acc[3];
  __syncthreads();
  if (tid < 64) {
    const int ch = tid * 4;
    ushort4 ob;
    #pragma unroll
    for (int j = 0; j < 4; ++j) {
      float v = part[tid][j] + part[tid + 64][j] + part[tid + 128][j] +
                part[tid + 192][j];
      v = fmaxf(v + b[ch + j], 0.f);
      ((ushort_t*)&ob)[j] = f2bf(v);
    }
    *(ushort4*)&out[(size_t)d * F1 + ch] = ob;
  }
}

// --------- gather layer 2 + log_softmax (wave/node, bf16 h2) ----------------
__global__ __launch_bounds__(256) void gather2(
    const int* __restrict__ csr_src, const int* __restrict__ row_start,
    const float* __restrict__ a_src, const float* __restrict__ a_dst,
    const ushort_t* __restrict__ h2, const float* __restrict__ b,
    float* __restrict__ out, int n) {
  const int d = blockIdx.x * 4 + (threadIdx.x >> 6);
  const int lane = threadIdx.x & 63;
  if (d >= n) return;
  const int rs = row_start[d];
  const int deg = row_start[d + 1] - rs;
  const float adv = a_dst[d];

  float lsum = 0.f;
  for (int i = lane; i < deg; i += 64) {
    int s = csr_src[rs + i];
    lsum += __expf(lrelu(a_src[s] + adv));
  }
  #pragma unroll
  for (int off = 32; off > 0; off >>= 1) lsum += __shfl_xor(lsum, off, 64);
  const float rden = 1.f / lsum;

  float acc = 0.f;
  for (int t0 = 0; t0 < deg; t0 += 64) {
    int myi = t0 + lane;
    int mys = 0;
    float myc = 0.f;
    if (myi < deg) {
      mys = csr_src[rs + myi];
      myc = __expf(lrelu(a_src[mys] + adv)) * rden;
    }
    int nt = min(64, deg - t0);
    for (int j = 0; j < nt; ++j) {
      int s = __shfl(mys, j, 64);
      float cf = __shfl(myc, j, 64);
      acc += cf * bf2f(h2[(size_t)s * F2 + lane]);
    }
  }

  float v = acc + b[lane];
  float m = v;
  #pragma unroll
  for (int off = 32; off > 0; off >>= 1) m = fmaxf(m, __shfl_xor(m, off, 64));
  float ex = __expf(v - m);
  float ss = ex;
  #pragma unroll
  for (int off = 32; off > 0; off >>= 1) ss += __shfl_xor(ss, off, 64);
  out[(size_t)d * F2 + lane] = v - m - __logf(ss);
}

// ------------------------------- launch -------------------------------------
extern "C" void kernel_launch(void* const* d_in, const int* in_sizes, int n_in,
                              void* d_out, int out_size, void* d_ws,
                              size_t ws_size, hipStream_t stream) {
  const float* x        = (const float*)d_in[0];
  const int*   ei       = (const int*)d_in[1];
  const float* W1       = (const float*)d_in[2];
  const float* att_src1 = (const float*)d_in[3];
  const float* att_dst1 = (const float*)d_in[4];
  const float* b1       = (const float*)d_in[5];
  const float* W2       = (const float*)d_in[6];
  const float* att_src2 = (const float*)d_in[7];
  const float* att_dst2 = (const float*)d_in[8];
  const float* b2       = (const float*)d_in[9];

  const int N = in_sizes[0] / 128;
  const int E0 = in_sizes[1] / 2;
  const int Etot = E0 + N;
  const int nb1024 = (N + 1023) / 1024;

  char* w = (char*)d_ws;
  size_t off = 0;
  auto alloc = [&](size_t bytes) {
    char* p = w + off;
    off += (bytes + 255) & ~(size_t)255;
    return p;
  };
  ushort_t* xb_hi     = (ushort_t*)alloc((size_t)N * 128 * 2);
  ushort_t* xb_lo     = (ushort_t*)alloc((size_t)N * 128 * 2);
  ushort_t* h1        = (ushort_t*)alloc((size_t)N * F1 * 2);
  ushort_t* h1out     = (ushort_t*)alloc((size_t)N * F1 * 2);
  ushort_t* h2b       = (ushort_t*)alloc((size_t)N * F2 * 2);
  int*      csr_src   = (int*)     alloc((size_t)Etot * 4);
  int*      row_start = (int*)     alloc((size_t)(N + 1) * 4);
  int*      counts    = (int*)     alloc((size_t)N * 4);
  int*      cursor    = (int*)     alloc((size_t)N * 4);
  int*      btot      = (int*)     alloc((size_t)nb1024 * 4);
  int*      boff      = (int*)     alloc((size_t)nb1024 * 4);
  float*    a_src1    = (float*)   alloc((size_t)N * HEADS1 * 4);
  float*    a_dst1    = (float*)   alloc((size_t)N * HEADS1 * 4);
  float*    a_src2    = (float*)   alloc((size_t)N * 4);
  float*    a_dst2    = (float*)   alloc((size_t)N * 4);
  ushort_t* W1t_hi    = (ushort_t*)alloc(128 * 256 * 2);
  ushort_t* W1t_lo    = (ushort_t*)alloc(128 * 256 * 2);
  ushort_t* W2t_hi    = (ushort_t*)alloc(256 * 64 * 2);
  ushort_t* W2t_lo    = (ushort_t*)alloc(256 * 64 * 2);
  float*    Wsrc1     = (float*)   alloc(128 * 8 * 4);
  float*    Wdst1     = (float*)   alloc(128 * 8 * 4);
  float*    w_s2      = (float*)   alloc(256 * 4);
  float*    w_d2      = (float*)   alloc(256 * 4);

  hipMemsetAsync(counts, 0, (size_t)N * 4, stream);
  hipMemsetAsync(cursor, 0, (size_t)N * 4, stream);

  dim3 blk(256);
  const int eb = (Etot + 255) / 256;
  const int gy = (N + 63) / 64;

  deg_count<<<eb, blk, 0, stream>>>(ei, E0, Etot, counts);
  scanA<<<nb1024, blk, 0, stream>>>(counts, row_start, btot, N);
  scanB<<<1, 64, 0, stream>>>(btot, boff, nb1024);
  scanC<<<(N + 255) / 256, blk, 0, stream>>>(row_start, boff, N);
  fill_csr<<<eb, blk, 0, stream>>>(ei, E0, Etot, row_start, cursor, csr_src);

  cvt_split<<<((size_t)N * 128 + 255) / 256, blk, 0, stream>>>(x, xb_hi, xb_lo,
                                                               N * 128);
  trcvt_split<<<(128 * 256 + 255) / 256, blk, 0, stream>>>(W1, W1t_hi, W1t_lo,
                                                           128, 256);
  trcvt_split<<<(256 * 64 + 255) / 256, blk, 0, stream>>>(W2, W2t_hi, W2t_lo,
                                                          256, 64);
  prep_w1<<<4, blk, 0, stream>>>(W1, att_src1, att_dst1, Wsrc1, Wdst1);
  prep_w2<<<1, blk, 0, stream>>>(W2, att_src2, att_dst2, w_s2, w_d2);

  // layer 1
  gemm_mfma2<<<dim3(F1 / 64, gy), blk, 0, stream>>>(
      xb_hi, xb_lo, W1t_hi, W1t_lo, h1, (float*)nullptr, N, F1, 128);
  attproj1<<<(N + 31) / 32, blk, 0, stream>>>(x, Wsrc1, Wdst1, a_src1, a_dst1, N);
  gather1<<<N, blk, 0, stream>>>(csr_src, row_start, a_src1, a_dst1, h1, b1,
                                 h1out);

  // layer 2 (h2 stored bf16)
  gemm_mfma2<<<dim3(F2 / 64, gy), blk, 0, stream>>>(
      h1out, (const ushort_t*)nullptr, W2t_hi, W2t_lo, h2b, (float*)nullptr,
      N, F2, F1);
  attproj2<<<(N + 3) / 4, blk, 0, stream>>>(h1out, w_s2, w_d2, a_src2, a_dst2, N);
  gather2<<<(N + 3) / 4, blk, 0, stream>>>(csr_src, row_start, a_src2, a_dst2,
                                           h2b, b2, (float*)d_out, N);
}

// Round 10
// 336.602 us; speedup vs baseline: 11.6599x; 1.0586x over previous
//
#include <hip/hip_runtime.h>
#include <hip/hip_bf16.h>
#include <cmath>

// ---------------------------------------------------------------------------
// GAT 2-layer forward. R10: gather1 rewritten single-pass (raw-exp staging,
// scale-at-end normalization, 4 barriers); everything else identical to R9.
// ---------------------------------------------------------------------------

#define HEADS1 8
#define F1 256
#define F2 64
#define NEG_SLOPE 0.2f

typedef unsigned int uint;
typedef unsigned short ushort_t;
typedef __attribute__((ext_vector_type(8))) short bf16x8;
typedef __attribute__((ext_vector_type(4))) float f32x4;

__device__ __forceinline__ float lrelu(float x) {
  return x >= 0.f ? x : NEG_SLOPE * x;
}
__device__ __forceinline__ ushort_t f2bf(float f) {
  uint u = __float_as_uint(f);
  return (ushort_t)((u + 0x7FFFu + ((u >> 16) & 1u)) >> 16);
}
__device__ __forceinline__ float bf2f(ushort_t u) {
  return __uint_as_float(((uint)u) << 16);
}

// ----------------------- conversion / split preps ---------------------------
__global__ __launch_bounds__(256) void cvt_split(const float* __restrict__ in,
                                                 ushort_t* __restrict__ hi,
                                                 ushort_t* __restrict__ lo,
                                                 int n) {
  int i = blockIdx.x * 256 + threadIdx.x;
  if (i >= n) return;
  float v = in[i];
  ushort_t h = f2bf(v);
  hi[i] = h;
  lo[i] = f2bf(v - bf2f(h));
}

__global__ __launch_bounds__(256) void trcvt_split(const float* __restrict__ in,
                                                   ushort_t* __restrict__ ohi,
                                                   ushort_t* __restrict__ olo,
                                                   int R, int C) {
  int idx = blockIdx.x * 256 + threadIdx.x;
  if (idx >= R * C) return;
  int r = idx / C, c = idx - r * C;
  float v = in[idx];
  ushort_t h = f2bf(v);
  ohi[(size_t)c * R + r] = h;
  olo[(size_t)c * R + r] = f2bf(v - bf2f(h));
}

// ----------------------------- MFMA GEMM (split) ----------------------------
__global__ __launch_bounds__(256) void gemm_mfma2(
    const ushort_t* __restrict__ Ah, const ushort_t* __restrict__ Al,
    const ushort_t* __restrict__ Bh, const ushort_t* __restrict__ Bl,
    ushort_t* __restrict__ Cb, float* __restrict__ Cf, int M, int N, int K) {
  __shared__ ushort_t AsH[64 * 40];
  __shared__ ushort_t AsL[64 * 40];
  __shared__ ushort_t BsH[64 * 40];
  __shared__ ushort_t BsL[64 * 40];
  const int tid = threadIdx.x;
  const int lane = tid & 63;
  const int wave = tid >> 6;
  const int wr = wave >> 1, wc = wave & 1;
  const int row0 = blockIdx.y * 64, col0 = blockIdx.x * 64;
  const int sr = tid >> 2;
  const int sk = (tid & 3) * 8;
  const int l15 = lane & 15;
  const int lk8 = (lane >> 4) * 8;

  f32x4 acc[2][2];
  #pragma unroll
  for (int i = 0; i < 2; ++i)
    #pragma unroll
    for (int j = 0; j < 2; ++j) acc[i][j] = (f32x4){0.f, 0.f, 0.f, 0.f};

  for (int k0 = 0; k0 < K; k0 += 32) {
    const int gr = row0 + sr;
    uint4 av = {0u, 0u, 0u, 0u};
    if (gr < M) av = *(const uint4*)&Ah[(size_t)gr * K + k0 + sk];
    *(uint4*)&AsH[sr * 40 + sk] = av;
    if (Al) {
      uint4 avl = {0u, 0u, 0u, 0u};
      if (gr < M) avl = *(const uint4*)&Al[(size_t)gr * K + k0 + sk];
      *(uint4*)&AsL[sr * 40 + sk] = avl;
    }
    uint4 bv = *(const uint4*)&Bh[(size_t)(col0 + sr) * K + k0 + sk];
    *(uint4*)&BsH[sr * 40 + sk] = bv;
    if (Bl) {
      uint4 bvl = *(const uint4*)&Bl[(size_t)(col0 + sr) * K + k0 + sk];
      *(uint4*)&BsL[sr * 40 + sk] = bvl;
    }
    __syncthreads();

    bf16x8 afh[2], bfh[2];
    #pragma unroll
    for (int mi = 0; mi < 2; ++mi)
      afh[mi] = *(const bf16x8*)&AsH[(wr * 32 + mi * 16 + l15) * 40 + lk8];
    #pragma unroll
    for (int ni = 0; ni < 2; ++ni)
      bfh[ni] = *(const bf16x8*)&BsH[(wc * 32 + ni * 16 + l15) * 40 + lk8];
    #pragma unroll
    for (int mi = 0; mi < 2; ++mi)
      #pragma unroll
      for (int ni = 0; ni < 2; ++ni)
        acc[mi][ni] = __builtin_amdgcn_mfma_f32_16x16x32_bf16(
            afh[mi], bfh[ni], acc[mi][ni], 0, 0, 0);
    if (Al) {
      bf16x8 afl[2];
      #pragma unroll
      for (int mi = 0; mi < 2; ++mi)
        afl[mi] = *(const bf16x8*)&AsL[(wr * 32 + mi * 16 + l15) * 40 + lk8];
      #pragma unroll
      for (int mi = 0; mi < 2; ++mi)
        #pragma unroll
        for (int ni = 0; ni < 2; ++ni)
          acc[mi][ni] = __builtin_amdgcn_mfma_f32_16x16x32_bf16(
              afl[mi], bfh[ni], acc[mi][ni], 0, 0, 0);
    }
    if (Bl) {
      bf16x8 bfl[2];
      #pragma unroll
      for (int ni = 0; ni < 2; ++ni)
        bfl[ni] = *(const bf16x8*)&BsL[(wc * 32 + ni * 16 + l15) * 40 + lk8];
      #pragma unroll
      for (int mi = 0; mi < 2; ++mi)
        #pragma unroll
        for (int ni = 0; ni < 2; ++ni)
          acc[mi][ni] = __builtin_amdgcn_mfma_f32_16x16x32_bf16(
              afh[mi], bfl[ni], acc[mi][ni], 0, 0, 0);
    }
    __syncthreads();
  }

  #pragma unroll
  for (int mi = 0; mi < 2; ++mi) {
    #pragma unroll
    for (int ni = 0; ni < 2; ++ni) {
      #pragma unroll
      for (int r = 0; r < 4; ++r) {
        int grow = row0 + wr * 32 + mi * 16 + (lane >> 4) * 4 + r;
        int gcol = col0 + wc * 32 + ni * 16 + l15;
        if (grow < M) {
          float v = acc[mi][ni][r];
          if (Cb) Cb[(size_t)grow * N + gcol] = f2bf(v);
          else    Cf[(size_t)grow * N + gcol] = v;
        }
      }
    }
  }
}

// ------------------ attention weight pre-projection (fp32 exact) ------------
__global__ __launch_bounds__(256) void prep_w1(
    const float* __restrict__ W1, const float* __restrict__ att_src,
    const float* __restrict__ att_dst, float* __restrict__ Wsrc,
    float* __restrict__ Wdst) {
  int idx = blockIdx.x * 256 + threadIdx.x;
  if (idx >= 128 * 8) return;
  int k = idx >> 3, h = idx & 7;
  float as = 0.f, ad = 0.f;
  #pragma unroll
  for (int c = 0; c < 32; ++c) {
    float wv = W1[(size_t)k * 256 + h * 32 + c];
    as += wv * att_src[h * 32 + c];
    ad += wv * att_dst[h * 32 + c];
  }
  Wsrc[idx] = as;
  Wdst[idx] = ad;
}

__global__ __launch_bounds__(256) void prep_w2(
    const float* __restrict__ W2, const float* __restrict__ att_src,
    const float* __restrict__ att_dst, float* __restrict__ ws,
    float* __restrict__ wd) {
  int k = threadIdx.x;
  float as = 0.f, ad = 0.f;
  #pragma unroll
  for (int c = 0; c < 64; ++c) {
    float wv = W2[(size_t)k * 64 + c];
    as += wv * att_src[c];
    ad += wv * att_dst[c];
  }
  ws[k] = as;
  wd[k] = ad;
}

__global__ __launch_bounds__(256) void attproj1(
    const float* __restrict__ x, const float* __restrict__ Wsrc,
    const float* __restrict__ Wdst, float* __restrict__ a_src,
    float* __restrict__ a_dst, int n) {
  __shared__ float ws[128 * 8];
  __shared__ float wd[128 * 8];
  const int tid = threadIdx.x;
  #pragma unroll
  for (int i = 0; i < 4; ++i) {
    ws[tid + i * 256] = Wsrc[tid + i * 256];
    wd[tid + i * 256] = Wdst[tid + i * 256];
  }
  __syncthreads();
  const int node = blockIdx.x * 32 + (tid >> 3);
  const int h = tid & 7;
  if (node >= n) return;
  float as = 0.f, ad = 0.f;
  const float* xr = &x[(size_t)node * 128];
  for (int k = 0; k < 128; ++k) {
    float xv = xr[k];
    as += xv * ws[k * 8 + h];
    ad += xv * wd[k * 8 + h];
  }
  a_src[node * 8 + h] = as;
  a_dst[node * 8 + h] = ad;
}

// attproj2: a_src2[n] = sum_k h1out[n,k]*ws[k]; wave per node
__global__ __launch_bounds__(256) void attproj2(
    const ushort_t* __restrict__ h1out, const float* __restrict__ ws,
    const float* __restrict__ wd, float* __restrict__ a_src,
    float* __restrict__ a_dst, int n) {
  __shared__ float wsl[256], wdl[256];
  const int tid = threadIdx.x;
  wsl[tid] = ws[tid];
  wdl[tid] = wd[tid];
  __syncthreads();
  const int node = blockIdx.x * 4 + (tid >> 6);
  const int lane = tid & 63;
  if (node >= n) return;
  float as = 0.f, ad = 0.f;
  #pragma unroll
  for (int j = 0; j < 4; ++j) {
    int k = lane + j * 64;
    float v = bf2f(h1out[(size_t)node * F1 + k]);
    as += v * wsl[k];
    ad += v * wdl[k];
  }
  #pragma unroll
  for (int off = 32; off > 0; off >>= 1) {
    as += __shfl_xor(as, off, 64);
    ad += __shfl_xor(ad, off, 64);
  }
  if (lane == 0) {
    a_src[node] = as;
    a_dst[node] = ad;
  }
}

// ------------------------------- CSR build ----------------------------------
__global__ __launch_bounds__(256) void deg_count(
    const int* __restrict__ ei, int E0, int Etot, int* __restrict__ counts) {
  int e = blockIdx.x * 256 + threadIdx.x;
  if (e >= Etot) return;
  int d = (e < E0) ? ei[E0 + e] : (e - E0);
  atomicAdd(&counts[d], 1);
}

__global__ __launch_bounds__(256) void scanA(
    const int* __restrict__ counts, int* __restrict__ row_start,
    int* __restrict__ btot, int n) {
  __shared__ int wsum[4];
  const int tid = threadIdx.x;
  const int lane = tid & 63;
  const int wid = tid >> 6;
  const int base = blockIdx.x * 1024 + tid * 4;
  int c[4], inc[4];
  #pragma unroll
  for (int j = 0; j < 4; ++j)
    c[j] = (base + j < n) ? counts[base + j] : 0;
  inc[0] = c[0];
  #pragma unroll
  for (int j = 1; j < 4; ++j) inc[j] = inc[j - 1] + c[j];
  int tsum = inc[3];
  int wincl = tsum;
  #pragma unroll
  for (int off = 1; off < 64; off <<= 1) {
    int v = __shfl_up(wincl, off, 64);
    if (lane >= off) wincl += v;
  }
  if (lane == 63) wsum[wid] = wincl;
  __syncthreads();
  int woff = 0;
  #pragma unroll
  for (int j = 0; j < 4; ++j)
    if (j < wid) woff += wsum[j];
  int prefix = woff + (wincl - tsum);
  #pragma unroll
  for (int j = 0; j < 4; ++j)
    if (base + j < n) row_start[base + j + 1] = prefix + inc[j];
  if (tid == 255) btot[blockIdx.x] = woff + wincl;
}

__global__ __launch_bounds__(64) void scanB(const int* __restrict__ btot,
                                            int* __restrict__ boff, int nb) {
  if (threadIdx.x == 0) {
    int run = 0;
    for (int b = 0; b < nb; ++b) {
      boff[b] = run;
      run += btot[b];
    }
  }
}

__global__ __launch_bounds__(256) void scanC(int* __restrict__ row_start,
                                             const int* __restrict__ boff,
                                             int n) {
  int i = blockIdx.x * 256 + threadIdx.x;
  if (i < n) row_start[i + 1] += boff[i >> 10];
  if (i == 0) row_start[0] = 0;
}

__global__ __launch_bounds__(256) void fill_csr(
    const int* __restrict__ ei, int E0, int Etot,
    const int* __restrict__ row_start, int* __restrict__ cursor,
    int* __restrict__ csr_src) {
  int e = blockIdx.x * 256 + threadIdx.x;
  if (e >= Etot) return;
  int s, d;
  if (e < E0) { s = ei[e]; d = ei[E0 + e]; } else { s = d = e - E0; }
  int slot = row_start[d] + atomicAdd(&cursor[d], 1);
  csr_src[slot] = s;
}

// ---------- gather layer 1: single-pass, raw-exp staging, scale-at-end ------
// Per 64-edge tile: stage (slot=tid>>3 [+32], h=tid&7) raw exps into LDS +
// register denom partial; consumers (wv=tid>>6, cg=tid&63) accumulate raw.
// Normalize once at the final write: out = rden * acc + b.
__global__ __launch_bounds__(256) void gather1(
    const int* __restrict__ csr_src, const int* __restrict__ row_start,
    const float* __restrict__ a_src, const float* __restrict__ a_dst,
    const ushort_t* __restrict__ h1, const float* __restrict__ b,
    ushort_t* __restrict__ out) {
  const int d = blockIdx.x;
  const int tid = threadIdx.x;
  const int rs = row_start[d];
  const int deg = row_start[d + 1] - rs;
  __shared__ float coef[64 * 8];   // raw exps, [e][h]
  __shared__ int s_lds[64];
  __shared__ float red8[32];       // per-wave denom partials [w][h]
  __shared__ float rdeninv[8];
  __shared__ float part[256][4];

  const int h8 = tid & 7;        // producer head
  const int slot = tid >> 3;     // producer slot 0..31 (+32 second half)
  const int wv = tid >> 6;       // wave id = accumulation edge sub-slot
  const int lane = tid & 63;
  const int cg = tid & 63;       // channel quad
  const int hh = cg >> 3;        // head of channels cg*4..cg*4+3
  const float adv = a_dst[d * 8 + h8];

  float dpart = 0.f;
  f32x4 acc = {0.f, 0.f, 0.f, 0.f};

  for (int t0 = 0; t0 < deg; t0 += 64) {
    const int nt = min(64, deg - t0);
    __syncthreads();   // protect coef/s_lds reuse across tiles
    #pragma unroll
    for (int half = 0; half < 2; ++half) {
      const int e = slot + half * 32;
      if (e < nt) {
        const int s = csr_src[rs + t0 + e];
        if (h8 == 0) s_lds[e] = s;
        const float ex = __expf(lrelu(a_src[s * 8 + h8] + adv));
        coef[e * 8 + h8] = ex;
        dpart += ex;
      }
    }
    __syncthreads();
    for (int i = wv; i < nt; i += 4) {
      const int s = s_lds[i];
      const float cf = coef[i * 8 + hh];
      ushort4 hv = *(const ushort4*)&h1[(size_t)s * F1 + cg * 4];
      acc[0] += cf * bf2f(hv.x);
      acc[1] += cf * bf2f(hv.y);
      acc[2] += cf * bf2f(hv.z);
      acc[3] += cf * bf2f(hv.w);
    }
  }

  // denominator: dpart holds (head h8, slots {slot, slot+32} over all tiles).
  // within-wave slots differ in lane bits 3,4,5 -> xor-reduce those.
  dpart += __shfl_xor(dpart, 8, 64);
  dpart += __shfl_xor(dpart, 16, 64);
  dpart += __shfl_xor(dpart, 32, 64);
  part[tid][0] = acc[0];
  part[tid][1] = acc[1];
  part[tid][2] = acc[2];
  part[tid][3] = acc[3];
  if (lane < 8) red8[wv * 8 + lane] = dpart;
  __syncthreads();
  if (tid < 8)
    rdeninv[tid] = 1.f / (red8[tid] + red8[8 + tid] + red8[16 + tid] +
                          red8[24 + tid]);
  __syncthreads();
  if (tid < 64) {
    const int ch = tid * 4;
    const float rden = rdeninv[tid >> 3];
    ushort4 ob;
    #pragma unroll
    for (int j = 0; j < 4; ++j) {
      float v = part[tid][j] + part[tid + 64][j] + part[tid + 128][j] +
                part[tid + 192][j];
      v = fmaxf(v * rden + b[ch + j], 0.f);
      ((ushort_t*)&ob)[j] = f2bf(v);
    }
    *(ushort4*)&out[(size_t)d * F1 + ch] = ob;
  }
}

// --------- gather layer 2 + log_softmax (wave/node, bf16 h2) ----------------
__global__ __launch_bounds__(256) void gather2(
    const int* __restrict__ csr_src, const int* __restrict__ row_start,
    const float* __restrict__ a_src, const float* __restrict__ a_dst,
    const ushort_t* __restrict__ h2, const float* __restrict__ b,
    float* __restrict__ out, int n) {
  const int d = blockIdx.x * 4 + (threadIdx.x >> 6);
  const int lane = threadIdx.x & 63;
  if (d >= n) return;
  const int rs = row_start[d];
  const int deg = row_start[d + 1] - rs;
  const float adv = a_dst[d];

  float lsum = 0.f;
  for (int i = lane; i < deg; i += 64) {
    int s = csr_src[rs + i];
    lsum += __expf(lrelu(a_src[s] + adv));
  }
  #pragma unroll
  for (int off = 32; off > 0; off >>= 1) lsum += __shfl_xor(lsum, off, 64);
  const float rden = 1.f / lsum;

  float acc = 0.f;
  for (int t0 = 0; t0 < deg; t0 += 64) {
    int myi = t0 + lane;
    int mys = 0;
    float myc = 0.f;
    if (myi < deg) {
      mys = csr_src[rs + myi];
      myc = __expf(lrelu(a_src[mys] + adv)) * rden;
    }
    int nt = min(64, deg - t0);
    for (int j = 0; j < nt; ++j) {
      int s = __shfl(mys, j, 64);
      float cf = __shfl(myc, j, 64);
      acc += cf * bf2f(h2[(size_t)s * F2 + lane]);
    }
  }

  float v = acc + b[lane];
  float m = v;
  #pragma unroll
  for (int off = 32; off > 0; off >>= 1) m = fmaxf(m, __shfl_xor(m, off, 64));
  float ex = __expf(v - m);
  float ss = ex;
  #pragma unroll
  for (int off = 32; off > 0; off >>= 1) ss += __shfl_xor(ss, off, 64);
  out[(size_t)d * F2 + lane] = v - m - __logf(ss);
}

// ------------------------------- launch -------------------------------------
extern "C" void kernel_launch(void* const* d_in, const int* in_sizes, int n_in,
                              void* d_out, int out_size, void* d_ws,
                              size_t ws_size, hipStream_t stream) {
  const float* x        = (const float*)d_in[0];
  const int*   ei       = (const int*)d_in[1];
  const float* W1       = (const float*)d_in[2];
  const float* att_src1 = (const float*)d_in[3];
  const float* att_dst1 = (const float*)d_in[4];
  const float* b1       = (const float*)d_in[5];
  const float* W2       = (const float*)d_in[6];
  const float* att_src2 = (const float*)d_in[7];
  const float* att_dst2 = (const float*)d_in[8];
  const float* b2       = (const float*)d_in[9];

  const int N = in_sizes[0] / 128;
  const int E0 = in_sizes[1] / 2;
  const int Etot = E0 + N;
  const int nb1024 = (N + 1023) / 1024;

  char* w = (char*)d_ws;
  size_t off = 0;
  auto alloc = [&](size_t bytes) {
    char* p = w + off;
    off += (bytes + 255) & ~(size_t)255;
    return p;
  };
  ushort_t* xb_hi     = (ushort_t*)alloc((size_t)N * 128 * 2);
  ushort_t* xb_lo     = (ushort_t*)alloc((size_t)N * 128 * 2);
  ushort_t* h1        = (ushort_t*)alloc((size_t)N * F1 * 2);
  ushort_t* h1out     = (ushort_t*)alloc((size_t)N * F1 * 2);
  ushort_t* h2b       = (ushort_t*)alloc((size_t)N * F2 * 2);
  int*      csr_src   = (int*)     alloc((size_t)Etot * 4);
  int*      row_start = (int*)     alloc((size_t)(N + 1) * 4);
  int*      counts    = (int*)     alloc((size_t)N * 4);
  int*      cursor    = (int*)     alloc((size_t)N * 4);
  int*      btot      = (int*)     alloc((size_t)nb1024 * 4);
  int*      boff      = (int*)     alloc((size_t)nb1024 * 4);
  float*    a_src1    = (float*)   alloc((size_t)N * HEADS1 * 4);
  float*    a_dst1    = (float*)   alloc((size_t)N * HEADS1 * 4);
  float*    a_src2    = (float*)   alloc((size_t)N * 4);
  float*    a_dst2    = (float*)   alloc((size_t)N * 4);
  ushort_t* W1t_hi    = (ushort_t*)alloc(128 * 256 * 2);
  ushort_t* W1t_lo    = (ushort_t*)alloc(128 * 256 * 2);
  ushort_t* W2t_hi    = (ushort_t*)alloc(256 * 64 * 2);
  ushort_t* W2t_lo    = (ushort_t*)alloc(256 * 64 * 2);
  float*    Wsrc1     = (float*)   alloc(128 * 8 * 4);
  float*    Wdst1     = (float*)   alloc(128 * 8 * 4);
  float*    w_s2      = (float*)   alloc(256 * 4);
  float*    w_d2      = (float*)   alloc(256 * 4);

  hipMemsetAsync(counts, 0, (size_t)N * 4, stream);
  hipMemsetAsync(cursor, 0, (size_t)N * 4, stream);

  dim3 blk(256);
  const int eb = (Etot + 255) / 256;
  const int gy = (N + 63) / 64;

  deg_count<<<eb, blk, 0, stream>>>(ei, E0, Etot, counts);
  scanA<<<nb1024, blk, 0, stream>>>(counts, row_start, btot, N);
  scanB<<<1, 64, 0, stream>>>(btot, boff, nb1024);
  scanC<<<(N + 255) / 256, blk, 0, stream>>>(row_start, boff, N);
  fill_csr<<<eb, blk, 0, stream>>>(ei, E0, Etot, row_start, cursor, csr_src);

  cvt_split<<<((size_t)N * 128 + 255) / 256, blk, 0, stream>>>(x, xb_hi, xb_lo,
                                                               N * 128);
  trcvt_split<<<(128 * 256 + 255) / 256, blk, 0, stream>>>(W1, W1t_hi, W1t_lo,
                                                           128, 256);
  trcvt_split<<<(256 * 64 + 255) / 256, blk, 0, stream>>>(W2, W2t_hi, W2t_lo,
                                                          256, 64);
  prep_w1<<<4, blk, 0, stream>>>(W1, att_src1, att_dst1, Wsrc1, Wdst1);
  prep_w2<<<1, blk, 0, stream>>>(W2, att_src2, att_dst2, w_s2, w_d2);

  // layer 1
  gemm_mfma2<<<dim3(F1 / 64, gy), blk, 0, stream>>>(
      xb_hi, xb_lo, W1t_hi, W1t_lo, h1, (float*)nullptr, N, F1, 128);
  attproj1<<<(N + 31) / 32, blk, 0, stream>>>(x, Wsrc1, Wdst1, a_src1, a_dst1, N);
  gather1<<<N, blk, 0, stream>>>(csr_src, row_start, a_src1, a_dst1, h1, b1,
                                 h1out);

  // layer 2 (h2 stored bf16)
  gemm_mfma2<<<dim3(F2 / 64, gy), blk, 0, stream>>>(
      h1out, (const ushort_t*)nullptr, W2t_hi, W2t_lo, h2b, (float*)nullptr,
      N, F2, F1);
  attproj2<<<(N + 3) / 4, blk, 0, stream>>>(h1out, w_s2, w_d2, a_src2, a_dst2, N);
  gather2<<<(N + 3) / 4, blk, 0, stream>>>(csr_src, row_start, a_src2, a_dst2,
                                           h2b, b2, (float*)d_out, N);
}

// Round 11
// 315.835 us; speedup vs baseline: 12.4266x; 1.0658x over previous
//
#include <hip/hip_runtime.h>
#include <hip/hip_bf16.h>
#include <cmath>

// ---------------------------------------------------------------------------
// GAT 2-layer forward. R11: single-pass bf16 MFMA GEMMs (A staged straight
// from fp32 for layer 1); attproj2 fused into gather1 epilogue; cvt_split
// eliminated. Gathers identical to R10 (proven).
// ---------------------------------------------------------------------------

#define HEADS1 8
#define F1 256
#define F2 64
#define NEG_SLOPE 0.2f

typedef unsigned int uint;
typedef unsigned short ushort_t;
typedef __attribute__((ext_vector_type(8))) short bf16x8;
typedef __attribute__((ext_vector_type(4))) float f32x4;

__device__ __forceinline__ float lrelu(float x) {
  return x >= 0.f ? x : NEG_SLOPE * x;
}
__device__ __forceinline__ ushort_t f2bf(float f) {
  uint u = __float_as_uint(f);
  return (ushort_t)((u + 0x7FFFu + ((u >> 16) & 1u)) >> 16);
}
__device__ __forceinline__ float bf2f(ushort_t u) {
  return __uint_as_float(((uint)u) << 16);
}
__device__ __forceinline__ uint pack2(float a, float b) {
  return (uint)f2bf(a) | ((uint)f2bf(b) << 16);
}

// --------------------- transpose+convert (weights) --------------------------
// out[c*R + r] = bf16(in[r*C + c])
__global__ __launch_bounds__(256) void trcvt(const float* __restrict__ in,
                                             ushort_t* __restrict__ out,
                                             int R, int C) {
  int idx = blockIdx.x * 256 + threadIdx.x;
  if (idx >= R * C) return;
  int r = idx / C, c = idx - r * C;
  out[(size_t)c * R + r] = f2bf(in[idx]);
}

// -------------------------- MFMA GEMM (single pass) -------------------------
// C[M,N](bf16) = A[M,K] @ B[K,N].  A: fp32 (Af) or bf16 (Ab), row-major.
// B passed transposed: Bt[N,K] bf16. 64x64 tile, BK=32, 4 waves 2x2.
__global__ __launch_bounds__(256) void gemm_bf16(
    const float* __restrict__ Af, const ushort_t* __restrict__ Ab,
    const ushort_t* __restrict__ Bt, ushort_t* __restrict__ Cb,
    int M, int N, int K) {
  __shared__ ushort_t As[64 * 40];
  __shared__ ushort_t Bs[64 * 40];
  const int tid = threadIdx.x;
  const int lane = tid & 63;
  const int wave = tid >> 6;
  const int wr = wave >> 1, wc = wave & 1;
  const int row0 = blockIdx.y * 64, col0 = blockIdx.x * 64;
  const int sr = tid >> 2;
  const int sk = (tid & 3) * 8;
  const int l15 = lane & 15;
  const int lk8 = (lane >> 4) * 8;

  f32x4 acc[2][2];
  #pragma unroll
  for (int i = 0; i < 2; ++i)
    #pragma unroll
    for (int j = 0; j < 2; ++j) acc[i][j] = (f32x4){0.f, 0.f, 0.f, 0.f};

  for (int k0 = 0; k0 < K; k0 += 32) {
    const int gr = row0 + sr;
    if (Af) {
      float4 f0 = {0.f, 0.f, 0.f, 0.f}, f1 = {0.f, 0.f, 0.f, 0.f};
      if (gr < M) {
        f0 = *(const float4*)&Af[(size_t)gr * K + k0 + sk];
        f1 = *(const float4*)&Af[(size_t)gr * K + k0 + sk + 4];
      }
      uint4 av;
      av.x = pack2(f0.x, f0.y);
      av.y = pack2(f0.z, f0.w);
      av.z = pack2(f1.x, f1.y);
      av.w = pack2(f1.z, f1.w);
      *(uint4*)&As[sr * 40 + sk] = av;
    } else {
      uint4 av = {0u, 0u, 0u, 0u};
      if (gr < M) av = *(const uint4*)&Ab[(size_t)gr * K + k0 + sk];
      *(uint4*)&As[sr * 40 + sk] = av;
    }
    uint4 bv = *(const uint4*)&Bt[(size_t)(col0 + sr) * K + k0 + sk];
    *(uint4*)&Bs[sr * 40 + sk] = bv;
    __syncthreads();

    bf16x8 af[2], bfr[2];
    #pragma unroll
    for (int mi = 0; mi < 2; ++mi)
      af[mi] = *(const bf16x8*)&As[(wr * 32 + mi * 16 + l15) * 40 + lk8];
    #pragma unroll
    for (int ni = 0; ni < 2; ++ni)
      bfr[ni] = *(const bf16x8*)&Bs[(wc * 32 + ni * 16 + l15) * 40 + lk8];
    #pragma unroll
    for (int mi = 0; mi < 2; ++mi)
      #pragma unroll
      for (int ni = 0; ni < 2; ++ni)
        acc[mi][ni] = __builtin_amdgcn_mfma_f32_16x16x32_bf16(
            af[mi], bfr[ni], acc[mi][ni], 0, 0, 0);
    __syncthreads();
  }

  // D row = (lane>>4)*4 + r, col = lane&15
  #pragma unroll
  for (int mi = 0; mi < 2; ++mi) {
    #pragma unroll
    for (int ni = 0; ni < 2; ++ni) {
      #pragma unroll
      for (int r = 0; r < 4; ++r) {
        int grow = row0 + wr * 32 + mi * 16 + (lane >> 4) * 4 + r;
        int gcol = col0 + wc * 32 + ni * 16 + l15;
        if (grow < M) Cb[(size_t)grow * N + gcol] = f2bf(acc[mi][ni][r]);
      }
    }
  }
}

// ------------------ attention weight pre-projection (fp32 exact) ------------
__global__ __launch_bounds__(256) void prep_w1(
    const float* __restrict__ W1, const float* __restrict__ att_src,
    const float* __restrict__ att_dst, float* __restrict__ Wsrc,
    float* __restrict__ Wdst) {
  int idx = blockIdx.x * 256 + threadIdx.x;
  if (idx >= 128 * 8) return;
  int k = idx >> 3, h = idx & 7;
  float as = 0.f, ad = 0.f;
  #pragma unroll
  for (int c = 0; c < 32; ++c) {
    float wv = W1[(size_t)k * 256 + h * 32 + c];
    as += wv * att_src[h * 32 + c];
    ad += wv * att_dst[h * 32 + c];
  }
  Wsrc[idx] = as;
  Wdst[idx] = ad;
}

__global__ __launch_bounds__(256) void prep_w2(
    const float* __restrict__ W2, const float* __restrict__ att_src,
    const float* __restrict__ att_dst, float* __restrict__ ws,
    float* __restrict__ wd) {
  int k = threadIdx.x;
  float as = 0.f, ad = 0.f;
  #pragma unroll
  for (int c = 0; c < 64; ++c) {
    float wv = W2[(size_t)k * 64 + c];
    as += wv * att_src[c];
    ad += wv * att_dst[c];
  }
  ws[k] = as;
  wd[k] = ad;
}

__global__ __launch_bounds__(256) void attproj1(
    const float* __restrict__ x, const float* __restrict__ Wsrc,
    const float* __restrict__ Wdst, float* __restrict__ a_src,
    float* __restrict__ a_dst, int n) {
  __shared__ float ws[128 * 8];
  __shared__ float wd[128 * 8];
  const int tid = threadIdx.x;
  #pragma unroll
  for (int i = 0; i < 4; ++i) {
    ws[tid + i * 256] = Wsrc[tid + i * 256];
    wd[tid + i * 256] = Wdst[tid + i * 256];
  }
  __syncthreads();
  const int node = blockIdx.x * 32 + (tid >> 3);
  const int h = tid & 7;
  if (node >= n) return;
  float as = 0.f, ad = 0.f;
  const float* xr = &x[(size_t)node * 128];
  for (int k = 0; k < 128; ++k) {
    float xv = xr[k];
    as += xv * ws[k * 8 + h];
    ad += xv * wd[k * 8 + h];
  }
  a_src[node * 8 + h] = as;
  a_dst[node * 8 + h] = ad;
}

// ------------------------------- CSR build ----------------------------------
__global__ __launch_bounds__(256) void deg_count(
    const int* __restrict__ ei, int E0, int Etot, int* __restrict__ counts) {
  int e = blockIdx.x * 256 + threadIdx.x;
  if (e >= Etot) return;
  int d = (e < E0) ? ei[E0 + e] : (e - E0);
  atomicAdd(&counts[d], 1);
}

__global__ __launch_bounds__(256) void scanA(
    const int* __restrict__ counts, int* __restrict__ row_start,
    int* __restrict__ btot, int n) {
  __shared__ int wsum[4];
  const int tid = threadIdx.x;
  const int lane = tid & 63;
  const int wid = tid >> 6;
  const int base = blockIdx.x * 1024 + tid * 4;
  int c[4], inc[4];
  #pragma unroll
  for (int j = 0; j < 4; ++j)
    c[j] = (base + j < n) ? counts[base + j] : 0;
  inc[0] = c[0];
  #pragma unroll
  for (int j = 1; j < 4; ++j) inc[j] = inc[j - 1] + c[j];
  int tsum = inc[3];
  int wincl = tsum;
  #pragma unroll
  for (int off = 1; off < 64; off <<= 1) {
    int v = __shfl_up(wincl, off, 64);
    if (lane >= off) wincl += v;
  }
  if (lane == 63) wsum[wid] = wincl;
  __syncthreads();
  int woff = 0;
  #pragma unroll
  for (int j = 0; j < 4; ++j)
    if (j < wid) woff += wsum[j];
  int prefix = woff + (wincl - tsum);
  #pragma unroll
  for (int j = 0; j < 4; ++j)
    if (base + j < n) row_start[base + j + 1] = prefix + inc[j];
  if (tid == 255) btot[blockIdx.x] = woff + wincl;
}

__global__ __launch_bounds__(64) void scanB(const int* __restrict__ btot,
                                            int* __restrict__ boff, int nb) {
  if (threadIdx.x == 0) {
    int run = 0;
    for (int b = 0; b < nb; ++b) {
      boff[b] = run;
      run += btot[b];
    }
  }
}

__global__ __launch_bounds__(256) void scanC(int* __restrict__ row_start,
                                             const int* __restrict__ boff,
                                             int n) {
  int i = blockIdx.x * 256 + threadIdx.x;
  if (i < n) row_start[i + 1] += boff[i >> 10];
  if (i == 0) row_start[0] = 0;
}

__global__ __launch_bounds__(256) void fill_csr(
    const int* __restrict__ ei, int E0, int Etot,
    const int* __restrict__ row_start, int* __restrict__ cursor,
    int* __restrict__ csr_src) {
  int e = blockIdx.x * 256 + threadIdx.x;
  if (e >= Etot) return;
  int s, d;
  if (e < E0) { s = ei[e]; d = ei[E0 + e]; } else { s = d = e - E0; }
  int slot = row_start[d] + atomicAdd(&cursor[d], 1);
  csr_src[slot] = s;
}

// ---------- gather layer 1: single-pass + fused attproj2 epilogue -----------
__global__ __launch_bounds__(256) void gather1(
    const int* __restrict__ csr_src, const int* __restrict__ row_start,
    const float* __restrict__ a_src, const float* __restrict__ a_dst,
    const ushort_t* __restrict__ h1, const float* __restrict__ b,
    const float* __restrict__ ws2, const float* __restrict__ wd2,
    ushort_t* __restrict__ out, float* __restrict__ a_src2,
    float* __restrict__ a_dst2) {
  const int d = blockIdx.x;
  const int tid = threadIdx.x;
  const int rs = row_start[d];
  const int deg = row_start[d + 1] - rs;
  __shared__ float coef[64 * 8];   // raw exps, [e][h]
  __shared__ int s_lds[64];
  __shared__ float red8[32];       // per-wave denom partials [w][h]
  __shared__ float rdeninv[8];
  __shared__ float part[256][4];

  const int h8 = tid & 7;
  const int slot = tid >> 3;
  const int wv = tid >> 6;
  const int lane = tid & 63;
  const int cg = tid & 63;
  const int hh = cg >> 3;
  const float adv = a_dst[d * 8 + h8];

  float dpart = 0.f;
  f32x4 acc = {0.f, 0.f, 0.f, 0.f};

  for (int t0 = 0; t0 < deg; t0 += 64) {
    const int nt = min(64, deg - t0);
    __syncthreads();
    #pragma unroll
    for (int half = 0; half < 2; ++half) {
      const int e = slot + half * 32;
      if (e < nt) {
        const int s = csr_src[rs + t0 + e];
        if (h8 == 0) s_lds[e] = s;
        const float ex = __expf(lrelu(a_src[s * 8 + h8] + adv));
        coef[e * 8 + h8] = ex;
        dpart += ex;
      }
    }
    __syncthreads();
    for (int i = wv; i < nt; i += 4) {
      const int s = s_lds[i];
      const float cf = coef[i * 8 + hh];
      ushort4 hv = *(const ushort4*)&h1[(size_t)s * F1 + cg * 4];
      acc[0] += cf * bf2f(hv.x);
      acc[1] += cf * bf2f(hv.y);
      acc[2] += cf * bf2f(hv.z);
      acc[3] += cf * bf2f(hv.w);
    }
  }

  dpart += __shfl_xor(dpart, 8, 64);
  dpart += __shfl_xor(dpart, 16, 64);
  dpart += __shfl_xor(dpart, 32, 64);
  part[tid][0] = acc[0];
  part[tid][1] = acc[1];
  part[tid][2] = acc[2];
  part[tid][3] = acc[3];
  if (lane < 8) red8[wv * 8 + lane] = dpart;
  __syncthreads();
  if (tid < 8)
    rdeninv[tid] = 1.f / (red8[tid] + red8[8 + tid] + red8[16 + tid] +
                          red8[24 + tid]);
  __syncthreads();
  if (tid < 64) {
    const int ch = tid * 4;
    const float rden = rdeninv[tid >> 3];
    ushort4 ob;
    float ps = 0.f, pd = 0.f;
    #pragma unroll
    for (int j = 0; j < 4; ++j) {
      float v = part[tid][j] + part[tid + 64][j] + part[tid + 128][j] +
                part[tid + 192][j];
      v = fmaxf(v * rden + b[ch + j], 0.f);
      ushort_t bv = f2bf(v);
      ((ushort_t*)&ob)[j] = bv;
      float r = bf2f(bv);
      ps += r * ws2[ch + j];
      pd += r * wd2[ch + j];
    }
    *(ushort4*)&out[(size_t)d * F1 + ch] = ob;
    // fused attproj2: reduce over the 64 lanes of wave 0
    #pragma unroll
    for (int off = 32; off > 0; off >>= 1) {
      ps += __shfl_xor(ps, off, 64);
      pd += __shfl_xor(pd, off, 64);
    }
    if (tid == 0) {
      a_src2[d] = ps;
      a_dst2[d] = pd;
    }
  }
}

// --------- gather layer 2 + log_softmax (wave/node, bf16 h2) ----------------
__global__ __launch_bounds__(256) void gather2(
    const int* __restrict__ csr_src, const int* __restrict__ row_start,
    const float* __restrict__ a_src, const float* __restrict__ a_dst,
    const ushort_t* __restrict__ h2, const float* __restrict__ b,
    float* __restrict__ out, int n) {
  const int d = blockIdx.x * 4 + (threadIdx.x >> 6);
  const int lane = threadIdx.x & 63;
  if (d >= n) return;
  const int rs = row_start[d];
  const int deg = row_start[d + 1] - rs;
  const float adv = a_dst[d];

  float lsum = 0.f;
  for (int i = lane; i < deg; i += 64) {
    int s = csr_src[rs + i];
    lsum += __expf(lrelu(a_src[s] + adv));
  }
  #pragma unroll
  for (int off = 32; off > 0; off >>= 1) lsum += __shfl_xor(lsum, off, 64);
  const float rden = 1.f / lsum;

  float acc = 0.f;
  for (int t0 = 0; t0 < deg; t0 += 64) {
    int myi = t0 + lane;
    int mys = 0;
    float myc = 0.f;
    if (myi < deg) {
      mys = csr_src[rs + myi];
      myc = __expf(lrelu(a_src[mys] + adv)) * rden;
    }
    int nt = min(64, deg - t0);
    for (int j = 0; j < nt; ++j) {
      int s = __shfl(mys, j, 64);
      float cf = __shfl(myc, j, 64);
      acc += cf * bf2f(h2[(size_t)s * F2 + lane]);
    }
  }

  float v = acc + b[lane];
  float m = v;
  #pragma unroll
  for (int off = 32; off > 0; off >>= 1) m = fmaxf(m, __shfl_xor(m, off, 64));
  float ex = __expf(v - m);
  float ss = ex;
  #pragma unroll
  for (int off = 32; off > 0; off >>= 1) ss += __shfl_xor(ss, off, 64);
  out[(size_t)d * F2 + lane] = v - m - __logf(ss);
}

// ------------------------------- launch -------------------------------------
extern "C" void kernel_launch(void* const* d_in, const int* in_sizes, int n_in,
                              void* d_out, int out_size, void* d_ws,
                              size_t ws_size, hipStream_t stream) {
  const float* x        = (const float*)d_in[0];
  const int*   ei       = (const int*)d_in[1];
  const float* W1       = (const float*)d_in[2];
  const float* att_src1 = (const float*)d_in[3];
  const float* att_dst1 = (const float*)d_in[4];
  const float* b1       = (const float*)d_in[5];
  const float* W2       = (const float*)d_in[6];
  const float* att_src2 = (const float*)d_in[7];
  const float* att_dst2 = (const float*)d_in[8];
  const float* b2       = (const float*)d_in[9];

  const int N = in_sizes[0] / 128;
  const int E0 = in_sizes[1] / 2;
  const int Etot = E0 + N;
  const int nb1024 = (N + 1023) / 1024;

  char* w = (char*)d_ws;
  size_t off = 0;
  auto alloc = [&](size_t bytes) {
    char* p = w + off;
    off += (bytes + 255) & ~(size_t)255;
    return p;
  };
  ushort_t* h1        = (ushort_t*)alloc((size_t)N * F1 * 2);   // 25.6MB
  ushort_t* h1out     = (ushort_t*)alloc((size_t)N * F1 * 2);   // 25.6MB
  ushort_t* h2b       = (ushort_t*)alloc((size_t)N * F2 * 2);   // 6.4MB
  int*      csr_src   = (int*)     alloc((size_t)Etot * 4);     // 3.4MB
  int*      row_start = (int*)     alloc((size_t)(N + 1) * 4);
  int*      counts    = (int*)     alloc((size_t)N * 4);
  int*      cursor    = (int*)     alloc((size_t)N * 4);
  int*      btot      = (int*)     alloc((size_t)nb1024 * 4);
  int*      boff      = (int*)     alloc((size_t)nb1024 * 4);
  float*    a_src1    = (float*)   alloc((size_t)N * HEADS1 * 4);
  float*    a_dst1    = (float*)   alloc((size_t)N * HEADS1 * 4);
  float*    a_src2    = (float*)   alloc((size_t)N * 4);
  float*    a_dst2    = (float*)   alloc((size_t)N * 4);
  ushort_t* W1t       = (ushort_t*)alloc(128 * 256 * 2);
  ushort_t* W2t       = (ushort_t*)alloc(256 * 64 * 2);
  float*    Wsrc1     = (float*)   alloc(128 * 8 * 4);
  float*    Wdst1     = (float*)   alloc(128 * 8 * 4);
  float*    w_s2      = (float*)   alloc(256 * 4);
  float*    w_d2      = (float*)   alloc(256 * 4);

  hipMemsetAsync(counts, 0, (size_t)N * 4, stream);
  hipMemsetAsync(cursor, 0, (size_t)N * 4, stream);

  dim3 blk(256);
  const int eb = (Etot + 255) / 256;
  const int gy = (N + 63) / 64;

  deg_count<<<eb, blk, 0, stream>>>(ei, E0, Etot, counts);
  scanA<<<nb1024, blk, 0, stream>>>(counts, row_start, btot, N);
  scanB<<<1, 64, 0, stream>>>(btot, boff, nb1024);
  scanC<<<(N + 255) / 256, blk, 0, stream>>>(row_start, boff, N);
  fill_csr<<<eb, blk, 0, stream>>>(ei, E0, Etot, row_start, cursor, csr_src);

  trcvt<<<(128 * 256 + 255) / 256, blk, 0, stream>>>(W1, W1t, 128, 256);
  trcvt<<<(256 * 64 + 255) / 256, blk, 0, stream>>>(W2, W2t, 256, 64);
  prep_w1<<<4, blk, 0, stream>>>(W1, att_src1, att_dst1, Wsrc1, Wdst1);
  prep_w2<<<1, blk, 0, stream>>>(W2, att_src2, att_dst2, w_s2, w_d2);

  // layer 1 (A staged from fp32 x, converted in-kernel)
  gemm_bf16<<<dim3(F1 / 64, gy), blk, 0, stream>>>(x, (const ushort_t*)nullptr,
                                                   W1t, h1, N, F1, 128);
  attproj1<<<(N + 31) / 32, blk, 0, stream>>>(x, Wsrc1, Wdst1, a_src1, a_dst1, N);
  gather1<<<N, blk, 0, stream>>>(csr_src, row_start, a_src1, a_dst1, h1, b1,
                                 w_s2, w_d2, h1out, a_src2, a_dst2);

  // layer 2
  gemm_bf16<<<dim3(F2 / 64, gy), blk, 0, stream>>>((const float*)nullptr, h1out,
                                                   W2t, h2b, N, F2, F1);
  gather2<<<(N + 3) / 4, blk, 0, stream>>>(csr_src, row_start, a_src2, a_dst2,
                                           h2b, b2, (float*)d_out, N);
}

// Round 12
// 294.376 us; speedup vs baseline: 13.3325x; 1.0729x over previous
//
#include <hip/hip_runtime.h>
#include <hip/hip_bf16.h>
#include <cmath>

// ---------------------------------------------------------------------------
// GAT 2-layer forward. R12: gather2 single-pass (scale-at-end); prep kernels
// fused into one launch; single memset. Everything else identical to R11.
// ---------------------------------------------------------------------------

#define HEADS1 8
#define F1 256
#define F2 64
#define NEG_SLOPE 0.2f

typedef unsigned int uint;
typedef unsigned short ushort_t;
typedef __attribute__((ext_vector_type(8))) short bf16x8;
typedef __attribute__((ext_vector_type(4))) float f32x4;

__device__ __forceinline__ float lrelu(float x) {
  return x >= 0.f ? x : NEG_SLOPE * x;
}
__device__ __forceinline__ ushort_t f2bf(float f) {
  uint u = __float_as_uint(f);
  return (ushort_t)((u + 0x7FFFu + ((u >> 16) & 1u)) >> 16);
}
__device__ __forceinline__ float bf2f(ushort_t u) {
  return __uint_as_float(((uint)u) << 16);
}
__device__ __forceinline__ uint pack2(float a, float b) {
  return (uint)f2bf(a) | ((uint)f2bf(b) << 16);
}

// ---------------- fused weight prep: trcvt W1/W2 + att projections ----------
// blocks [0,128): W1t[c*128+r] = bf16(W1[r*256+c])        (32768 elems)
// blocks [128,192): W2t[c*256+r] = bf16(W2[r*64+c])       (16384 elems)
// blocks [192,196): Wsrc1/Wdst1 (1024 items)
// block  196: w_s2/w_d2 (256 items)
__global__ __launch_bounds__(256) void prep_all(
    const float* __restrict__ W1, const float* __restrict__ W2,
    const float* __restrict__ att_src1, const float* __restrict__ att_dst1,
    const float* __restrict__ att_src2, const float* __restrict__ att_dst2,
    ushort_t* __restrict__ W1t, ushort_t* __restrict__ W2t,
    float* __restrict__ Wsrc1, float* __restrict__ Wdst1,
    float* __restrict__ w_s2, float* __restrict__ w_d2) {
  const int bid = blockIdx.x;
  const int tid = threadIdx.x;
  if (bid < 128) {
    int idx = bid * 256 + tid;            // < 32768
    int r = idx >> 8, c = idx & 255;
    W1t[(size_t)c * 128 + r] = f2bf(W1[idx]);
  } else if (bid < 192) {
    int idx = (bid - 128) * 256 + tid;    // < 16384
    int r = idx >> 6, c = idx & 63;
    W2t[(size_t)c * 256 + r] = f2bf(W2[idx]);
  } else if (bid < 196) {
    int idx = (bid - 192) * 256 + tid;    // < 1024
    int k = idx >> 3, h = idx & 7;
    float as = 0.f, ad = 0.f;
    #pragma unroll
    for (int c = 0; c < 32; ++c) {
      float wv = W1[(size_t)k * 256 + h * 32 + c];
      as += wv * att_src1[h * 32 + c];
      ad += wv * att_dst1[h * 32 + c];
    }
    Wsrc1[idx] = as;
    Wdst1[idx] = ad;
  } else {
    int k = tid;
    float as = 0.f, ad = 0.f;
    #pragma unroll
    for (int c = 0; c < 64; ++c) {
      float wv = W2[(size_t)k * 64 + c];
      as += wv * att_src2[c];
      ad += wv * att_dst2[c];
    }
    w_s2[k] = as;
    w_d2[k] = ad;
  }
}

// -------------------------- MFMA GEMM (single pass) -------------------------
__global__ __launch_bounds__(256) void gemm_bf16(
    const float* __restrict__ Af, const ushort_t* __restrict__ Ab,
    const ushort_t* __restrict__ Bt, ushort_t* __restrict__ Cb,
    int M, int N, int K) {
  __shared__ ushort_t As[64 * 40];
  __shared__ ushort_t Bs[64 * 40];
  const int tid = threadIdx.x;
  const int lane = tid & 63;
  const int wave = tid >> 6;
  const int wr = wave >> 1, wc = wave & 1;
  const int row0 = blockIdx.y * 64, col0 = blockIdx.x * 64;
  const int sr = tid >> 2;
  const int sk = (tid & 3) * 8;
  const int l15 = lane & 15;
  const int lk8 = (lane >> 4) * 8;

  f32x4 acc[2][2];
  #pragma unroll
  for (int i = 0; i < 2; ++i)
    #pragma unroll
    for (int j = 0; j < 2; ++j) acc[i][j] = (f32x4){0.f, 0.f, 0.f, 0.f};

  for (int k0 = 0; k0 < K; k0 += 32) {
    const int gr = row0 + sr;
    if (Af) {
      float4 f0 = {0.f, 0.f, 0.f, 0.f}, f1 = {0.f, 0.f, 0.f, 0.f};
      if (gr < M) {
        f0 = *(const float4*)&Af[(size_t)gr * K + k0 + sk];
        f1 = *(const float4*)&Af[(size_t)gr * K + k0 + sk + 4];
      }
      uint4 av;
      av.x = pack2(f0.x, f0.y);
      av.y = pack2(f0.z, f0.w);
      av.z = pack2(f1.x, f1.y);
      av.w = pack2(f1.z, f1.w);
      *(uint4*)&As[sr * 40 + sk] = av;
    } else {
      uint4 av = {0u, 0u, 0u, 0u};
      if (gr < M) av = *(const uint4*)&Ab[(size_t)gr * K + k0 + sk];
      *(uint4*)&As[sr * 40 + sk] = av;
    }
    uint4 bv = *(const uint4*)&Bt[(size_t)(col0 + sr) * K + k0 + sk];
    *(uint4*)&Bs[sr * 40 + sk] = bv;
    __syncthreads();

    bf16x8 af[2], bfr[2];
    #pragma unroll
    for (int mi = 0; mi < 2; ++mi)
      af[mi] = *(const bf16x8*)&As[(wr * 32 + mi * 16 + l15) * 40 + lk8];
    #pragma unroll
    for (int ni = 0; ni < 2; ++ni)
      bfr[ni] = *(const bf16x8*)&Bs[(wc * 32 + ni * 16 + l15) * 40 + lk8];
    #pragma unroll
    for (int mi = 0; mi < 2; ++mi)
      #pragma unroll
      for (int ni = 0; ni < 2; ++ni)
        acc[mi][ni] = __builtin_amdgcn_mfma_f32_16x16x32_bf16(
            af[mi], bfr[ni], acc[mi][ni], 0, 0, 0);
    __syncthreads();
  }

  #pragma unroll
  for (int mi = 0; mi < 2; ++mi) {
    #pragma unroll
    for (int ni = 0; ni < 2; ++ni) {
      #pragma unroll
      for (int r = 0; r < 4; ++r) {
        int grow = row0 + wr * 32 + mi * 16 + (lane >> 4) * 4 + r;
        int gcol = col0 + wc * 32 + ni * 16 + l15;
        if (grow < M) Cb[(size_t)grow * N + gcol] = f2bf(acc[mi][ni][r]);
      }
    }
  }
}

// ------------------------------ attproj1 ------------------------------------
__global__ __launch_bounds__(256) void attproj1(
    const float* __restrict__ x, const float* __restrict__ Wsrc,
    const float* __restrict__ Wdst, float* __restrict__ a_src,
    float* __restrict__ a_dst, int n) {
  __shared__ float ws[128 * 8];
  __shared__ float wd[128 * 8];
  const int tid = threadIdx.x;
  #pragma unroll
  for (int i = 0; i < 4; ++i) {
    ws[tid + i * 256] = Wsrc[tid + i * 256];
    wd[tid + i * 256] = Wdst[tid + i * 256];
  }
  __syncthreads();
  const int node = blockIdx.x * 32 + (tid >> 3);
  const int h = tid & 7;
  if (node >= n) return;
  float as = 0.f, ad = 0.f;
  const float* xr = &x[(size_t)node * 128];
  for (int k = 0; k < 128; ++k) {
    float xv = xr[k];
    as += xv * ws[k * 8 + h];
    ad += xv * wd[k * 8 + h];
  }
  a_src[node * 8 + h] = as;
  a_dst[node * 8 + h] = ad;
}

// ------------------------------- CSR build ----------------------------------
__global__ __launch_bounds__(256) void deg_count(
    const int* __restrict__ ei, int E0, int Etot, int* __restrict__ counts) {
  int e = blockIdx.x * 256 + threadIdx.x;
  if (e >= Etot) return;
  int d = (e < E0) ? ei[E0 + e] : (e - E0);
  atomicAdd(&counts[d], 1);
}

__global__ __launch_bounds__(256) void scanA(
    const int* __restrict__ counts, int* __restrict__ row_start,
    int* __restrict__ btot, int n) {
  __shared__ int wsum[4];
  const int tid = threadIdx.x;
  const int lane = tid & 63;
  const int wid = tid >> 6;
  const int base = blockIdx.x * 1024 + tid * 4;
  int c[4], inc[4];
  #pragma unroll
  for (int j = 0; j < 4; ++j)
    c[j] = (base + j < n) ? counts[base + j] : 0;
  inc[0] = c[0];
  #pragma unroll
  for (int j = 1; j < 4; ++j) inc[j] = inc[j - 1] + c[j];
  int tsum = inc[3];
  int wincl = tsum;
  #pragma unroll
  for (int off = 1; off < 64; off <<= 1) {
    int v = __shfl_up(wincl, off, 64);
    if (lane >= off) wincl += v;
  }
  if (lane == 63) wsum[wid] = wincl;
  __syncthreads();
  int woff = 0;
  #pragma unroll
  for (int j = 0; j < 4; ++j)
    if (j < wid) woff += wsum[j];
  int prefix = woff + (wincl - tsum);
  #pragma unroll
  for (int j = 0; j < 4; ++j)
    if (base + j < n) row_start[base + j + 1] = prefix + inc[j];
  if (tid == 255) btot[blockIdx.x] = woff + wincl;
}

__global__ __launch_bounds__(64) void scanB(const int* __restrict__ btot,
                                            int* __restrict__ boff, int nb) {
  if (threadIdx.x == 0) {
    int run = 0;
    for (int b = 0; b < nb; ++b) {
      boff[b] = run;
      run += btot[b];
    }
  }
}

__global__ __launch_bounds__(256) void scanC(int* __restrict__ row_start,
                                             const int* __restrict__ boff,
                                             int n) {
  int i = blockIdx.x * 256 + threadIdx.x;
  if (i < n) row_start[i + 1] += boff[i >> 10];
  if (i == 0) row_start[0] = 0;
}

__global__ __launch_bounds__(256) void fill_csr(
    const int* __restrict__ ei, int E0, int Etot,
    const int* __restrict__ row_start, int* __restrict__ cursor,
    int* __restrict__ csr_src) {
  int e = blockIdx.x * 256 + threadIdx.x;
  if (e >= Etot) return;
  int s, d;
  if (e < E0) { s = ei[e]; d = ei[E0 + e]; } else { s = d = e - E0; }
  int slot = row_start[d] + atomicAdd(&cursor[d], 1);
  csr_src[slot] = s;
}

// ---------- gather layer 1: single-pass + fused attproj2 epilogue -----------
__global__ __launch_bounds__(256) void gather1(
    const int* __restrict__ csr_src, const int* __restrict__ row_start,
    const float* __restrict__ a_src, const float* __restrict__ a_dst,
    const ushort_t* __restrict__ h1, const float* __restrict__ b,
    const float* __restrict__ ws2, const float* __restrict__ wd2,
    ushort_t* __restrict__ out, float* __restrict__ a_src2,
    float* __restrict__ a_dst2) {
  const int d = blockIdx.x;
  const int tid = threadIdx.x;
  const int rs = row_start[d];
  const int deg = row_start[d + 1] - rs;
  __shared__ float coef[64 * 8];
  __shared__ int s_lds[64];
  __shared__ float red8[32];
  __shared__ float rdeninv[8];
  __shared__ float part[256][4];

  const int h8 = tid & 7;
  const int slot = tid >> 3;
  const int wv = tid >> 6;
  const int lane = tid & 63;
  const int cg = tid & 63;
  const int hh = cg >> 3;
  const float adv = a_dst[d * 8 + h8];

  float dpart = 0.f;
  f32x4 acc = {0.f, 0.f, 0.f, 0.f};

  for (int t0 = 0; t0 < deg; t0 += 64) {
    const int nt = min(64, deg - t0);
    __syncthreads();
    #pragma unroll
    for (int half = 0; half < 2; ++half) {
      const int e = slot + half * 32;
      if (e < nt) {
        const int s = csr_src[rs + t0 + e];
        if (h8 == 0) s_lds[e] = s;
        const float ex = __expf(lrelu(a_src[s * 8 + h8] + adv));
        coef[e * 8 + h8] = ex;
        dpart += ex;
      }
    }
    __syncthreads();
    for (int i = wv; i < nt; i += 4) {
      const int s = s_lds[i];
      const float cf = coef[i * 8 + hh];
      ushort4 hv = *(const ushort4*)&h1[(size_t)s * F1 + cg * 4];
      acc[0] += cf * bf2f(hv.x);
      acc[1] += cf * bf2f(hv.y);
      acc[2] += cf * bf2f(hv.z);
      acc[3] += cf * bf2f(hv.w);
    }
  }

  dpart += __shfl_xor(dpart, 8, 64);
  dpart += __shfl_xor(dpart, 16, 64);
  dpart += __shfl_xor(dpart, 32, 64);
  part[tid][0] = acc[0];
  part[tid][1] = acc[1];
  part[tid][2] = acc[2];
  part[tid][3] = acc[3];
  if (lane < 8) red8[wv * 8 + lane] = dpart;
  __syncthreads();
  if (tid < 8)
    rdeninv[tid] = 1.f / (red8[tid] + red8[8 + tid] + red8[16 + tid] +
                          red8[24 + tid]);
  __syncthreads();
  if (tid < 64) {
    const int ch = tid * 4;
    const float rden = rdeninv[tid >> 3];
    ushort4 ob;
    float ps = 0.f, pd = 0.f;
    #pragma unroll
    for (int j = 0; j < 4; ++j) {
      float v = part[tid][j] + part[tid + 64][j] + part[tid + 128][j] +
                part[tid + 192][j];
      v = fmaxf(v * rden + b[ch + j], 0.f);
      ushort_t bv = f2bf(v);
      ((ushort_t*)&ob)[j] = bv;
      float r = bf2f(bv);
      ps += r * ws2[ch + j];
      pd += r * wd2[ch + j];
    }
    *(ushort4*)&out[(size_t)d * F1 + ch] = ob;
    #pragma unroll
    for (int off = 32; off > 0; off >>= 1) {
      ps += __shfl_xor(ps, off, 64);
      pd += __shfl_xor(pd, off, 64);
    }
    if (tid == 0) {
      a_src2[d] = ps;
      a_dst2[d] = pd;
    }
  }
}

// ------ gather layer 2 + log_softmax: single-pass, scale-at-end -------------
__global__ __launch_bounds__(256) void gather2(
    const int* __restrict__ csr_src, const int* __restrict__ row_start,
    const float* __restrict__ a_src, const float* __restrict__ a_dst,
    const ushort_t* __restrict__ h2, const float* __restrict__ b,
    float* __restrict__ out, int n) {
  const int d = blockIdx.x * 4 + (threadIdx.x >> 6);
  const int lane = threadIdx.x & 63;
  if (d >= n) return;
  const int rs = row_start[d];
  const int deg = row_start[d + 1] - rs;
  const float adv = a_dst[d];

  float lsum = 0.f;
  float acc = 0.f;
  for (int t0 = 0; t0 < deg; t0 += 64) {
    int myi = t0 + lane;
    int mys = 0;
    float myc = 0.f;
    if (myi < deg) {
      mys = csr_src[rs + myi];
      myc = __expf(lrelu(a_src[mys] + adv));
      lsum += myc;
    }
    int nt = min(64, deg - t0);
    for (int j = 0; j < nt; ++j) {
      int s = __shfl(mys, j, 64);
      float cf = __shfl(myc, j, 64);
      acc += cf * bf2f(h2[(size_t)s * F2 + lane]);
    }
  }
  #pragma unroll
  for (int off = 32; off > 0; off >>= 1) lsum += __shfl_xor(lsum, off, 64);
  const float rden = 1.f / lsum;

  float v = acc * rden + b[lane];
  float m = v;
  #pragma unroll
  for (int off = 32; off > 0; off >>= 1) m = fmaxf(m, __shfl_xor(m, off, 64));
  float ex = __expf(v - m);
  float ss = ex;
  #pragma unroll
  for (int off = 32; off > 0; off >>= 1) ss += __shfl_xor(ss, off, 64);
  out[(size_t)d * F2 + lane] = v - m - __logf(ss);
}

// ------------------------------- launch -------------------------------------
extern "C" void kernel_launch(void* const* d_in, const int* in_sizes, int n_in,
                              void* d_out, int out_size, void* d_ws,
                              size_t ws_size, hipStream_t stream) {
  const float* x        = (const float*)d_in[0];
  const int*   ei       = (const int*)d_in[1];
  const float* W1       = (const float*)d_in[2];
  const float* att_src1 = (const float*)d_in[3];
  const float* att_dst1 = (const float*)d_in[4];
  const float* b1       = (const float*)d_in[5];
  const float* W2       = (const float*)d_in[6];
  const float* att_src2 = (const float*)d_in[7];
  const float* att_dst2 = (const float*)d_in[8];
  const float* b2       = (const float*)d_in[9];

  const int N = in_sizes[0] / 128;
  const int E0 = in_sizes[1] / 2;
  const int Etot = E0 + N;
  const int nb1024 = (N + 1023) / 1024;

  char* w = (char*)d_ws;
  size_t off = 0;
  auto alloc = [&](size_t bytes) {
    char* p = w + off;
    off += (bytes + 255) & ~(size_t)255;
    return p;
  };
  ushort_t* h1        = (ushort_t*)alloc((size_t)N * F1 * 2);
  ushort_t* h1out     = (ushort_t*)alloc((size_t)N * F1 * 2);
  ushort_t* h2b       = (ushort_t*)alloc((size_t)N * F2 * 2);
  int*      csr_src   = (int*)     alloc((size_t)Etot * 4);
  int*      row_start = (int*)     alloc((size_t)(N + 1) * 4);
  int*      cc        = (int*)     alloc((size_t)2 * N * 4);  // counts|cursor
  int*      counts    = cc;
  int*      cursor    = cc + N;
  int*      btot      = (int*)     alloc((size_t)nb1024 * 4);
  int*      boff      = (int*)     alloc((size_t)nb1024 * 4);
  float*    a_src1    = (float*)   alloc((size_t)N * HEADS1 * 4);
  float*    a_dst1    = (float*)   alloc((size_t)N * HEADS1 * 4);
  float*    a_src2    = (float*)   alloc((size_t)N * 4);
  float*    a_dst2    = (float*)   alloc((size_t)N * 4);
  ushort_t* W1t       = (ushort_t*)alloc(128 * 256 * 2);
  ushort_t* W2t       = (ushort_t*)alloc(256 * 64 * 2);
  float*    Wsrc1     = (float*)   alloc(128 * 8 * 4);
  float*    Wdst1     = (float*)   alloc(128 * 8 * 4);
  float*    w_s2      = (float*)   alloc(256 * 4);
  float*    w_d2      = (float*)   alloc(256 * 4);

  hipMemsetAsync(cc, 0, (size_t)2 * N * 4, stream);

  dim3 blk(256);
  const int eb = (Etot + 255) / 256;
  const int gy = (N + 63) / 64;

  deg_count<<<eb, blk, 0, stream>>>(ei, E0, Etot, counts);
  scanA<<<nb1024, blk, 0, stream>>>(counts, row_start, btot, N);
  scanB<<<1, 64, 0, stream>>>(btot, boff, nb1024);
  scanC<<<(N + 255) / 256, blk, 0, stream>>>(row_start, boff, N);
  fill_csr<<<eb, blk, 0, stream>>>(ei, E0, Etot, row_start, cursor, csr_src);

  prep_all<<<197, blk, 0, stream>>>(W1, W2, att_src1, att_dst1, att_src2,
                                    att_dst2, W1t, W2t, Wsrc1, Wdst1, w_s2,
                                    w_d2);

  // layer 1
  gemm_bf16<<<dim3(F1 / 64, gy), blk, 0, stream>>>(x, (const ushort_t*)nullptr,
                                                   W1t, h1, N, F1, 128);
  attproj1<<<(N + 31) / 32, blk, 0, stream>>>(x, Wsrc1, Wdst1, a_src1, a_dst1, N);
  gather1<<<N, blk, 0, stream>>>(csr_src, row_start, a_src1, a_dst1, h1, b1,
                                 w_s2, w_d2, h1out, a_src2, a_dst2);

  // layer 2
  gemm_bf16<<<dim3(F2 / 64, gy), blk, 0, stream>>>((const float*)nullptr, h1out,
                                                   W2t, h2b, N, F2, F1);
  gather2<<<(N + 3) / 4, blk, 0, stream>>>(csr_src, row_start, a_src2, a_dst2,
                                           h2b, b2, (float*)d_out, N);
}

// Round 13
// 277.640 us; speedup vs baseline: 14.1362x; 1.0603x over previous
//
#include <hip/hip_runtime.h>
#include <hip/hip_bf16.h>
#include <cmath>

// ---------------------------------------------------------------------------
// GAT 2-layer forward. R13: launch compaction — kernel A = prep+deg_count,
// kernel B = gemm1+fill_csr+attproj1 (block-range dispatch, shared-LDS
// union). All computational bodies identical to R12.
// ---------------------------------------------------------------------------

#define HEADS1 8
#define F1 256
#define F2 64
#define NEG_SLOPE 0.2f

typedef unsigned int uint;
typedef unsigned short ushort_t;
typedef __attribute__((ext_vector_type(8))) short bf16x8;
typedef __attribute__((ext_vector_type(4))) float f32x4;

__device__ __forceinline__ float lrelu(float x) {
  return x >= 0.f ? x : NEG_SLOPE * x;
}
__device__ __forceinline__ ushort_t f2bf(float f) {
  uint u = __float_as_uint(f);
  return (ushort_t)((u + 0x7FFFu + ((u >> 16) & 1u)) >> 16);
}
__device__ __forceinline__ float bf2f(ushort_t u) {
  return __uint_as_float(((uint)u) << 16);
}
__device__ __forceinline__ uint pack2(float a, float b) {
  return (uint)f2bf(a) | ((uint)f2bf(b) << 16);
}

// --------------- kernel A: weight prep (197 blocks) + deg_count -------------
__global__ __launch_bounds__(256) void kernelA(
    const float* __restrict__ W1, const float* __restrict__ W2,
    const float* __restrict__ att_src1, const float* __restrict__ att_dst1,
    const float* __restrict__ att_src2, const float* __restrict__ att_dst2,
    ushort_t* __restrict__ W1t, ushort_t* __restrict__ W2t,
    float* __restrict__ Wsrc1, float* __restrict__ Wdst1,
    float* __restrict__ w_s2, float* __restrict__ w_d2,
    const int* __restrict__ ei, int E0, int Etot, int* __restrict__ counts) {
  const int bid = blockIdx.x;
  const int tid = threadIdx.x;
  if (bid < 128) {
    int idx = bid * 256 + tid;
    int r = idx >> 8, c = idx & 255;
    W1t[(size_t)c * 128 + r] = f2bf(W1[idx]);
  } else if (bid < 192) {
    int idx = (bid - 128) * 256 + tid;
    int r = idx >> 6, c = idx & 63;
    W2t[(size_t)c * 256 + r] = f2bf(W2[idx]);
  } else if (bid < 196) {
    int idx = (bid - 192) * 256 + tid;
    int k = idx >> 3, h = idx & 7;
    float as = 0.f, ad = 0.f;
    #pragma unroll
    for (int c = 0; c < 32; ++c) {
      float wv = W1[(size_t)k * 256 + h * 32 + c];
      as += wv * att_src1[h * 32 + c];
      ad += wv * att_dst1[h * 32 + c];
    }
    Wsrc1[idx] = as;
    Wdst1[idx] = ad;
  } else if (bid < 197) {
    int k = tid;
    float as = 0.f, ad = 0.f;
    #pragma unroll
    for (int c = 0; c < 64; ++c) {
      float wv = W2[(size_t)k * 64 + c];
      as += wv * att_src2[c];
      ad += wv * att_dst2[c];
    }
    w_s2[k] = as;
    w_d2[k] = ad;
  } else {
    int e = (bid - 197) * 256 + tid;
    if (e >= Etot) return;
    int d = (e < E0) ? ei[E0 + e] : (e - E0);
    atomicAdd(&counts[d], 1);
  }
}

// -------------------------------- scans -------------------------------------
__global__ __launch_bounds__(256) void scanA(
    const int* __restrict__ counts, int* __restrict__ row_start,
    int* __restrict__ btot, int n) {
  __shared__ int wsum[4];
  const int tid = threadIdx.x;
  const int lane = tid & 63;
  const int wid = tid >> 6;
  const int base = blockIdx.x * 1024 + tid * 4;
  int c[4], inc[4];
  #pragma unroll
  for (int j = 0; j < 4; ++j)
    c[j] = (base + j < n) ? counts[base + j] : 0;
  inc[0] = c[0];
  #pragma unroll
  for (int j = 1; j < 4; ++j) inc[j] = inc[j - 1] + c[j];
  int tsum = inc[3];
  int wincl = tsum;
  #pragma unroll
  for (int off = 1; off < 64; off <<= 1) {
    int v = __shfl_up(wincl, off, 64);
    if (lane >= off) wincl += v;
  }
  if (lane == 63) wsum[wid] = wincl;
  __syncthreads();
  int woff = 0;
  #pragma unroll
  for (int j = 0; j < 4; ++j)
    if (j < wid) woff += wsum[j];
  int prefix = woff + (wincl - tsum);
  #pragma unroll
  for (int j = 0; j < 4; ++j)
    if (base + j < n) row_start[base + j + 1] = prefix + inc[j];
  if (tid == 255) btot[blockIdx.x] = woff + wincl;
}

__global__ __launch_bounds__(64) void scanB(const int* __restrict__ btot,
                                            int* __restrict__ boff, int nb) {
  if (threadIdx.x == 0) {
    int run = 0;
    for (int b = 0; b < nb; ++b) {
      boff[b] = run;
      run += btot[b];
    }
  }
}

__global__ __launch_bounds__(256) void scanC(int* __restrict__ row_start,
                                             const int* __restrict__ boff,
                                             int n) {
  int i = blockIdx.x * 256 + threadIdx.x;
  if (i < n) row_start[i + 1] += boff[i >> 10];
  if (i == 0) row_start[0] = 0;
}

// -------- kernel B: gemm1 (3128 blocks) + fill_csr + attproj1 ---------------
// LDS union: gemm needs 2*64*40*2 = 10240 B; attproj needs 8192 B.
__global__ __launch_bounds__(256) void kernelB(
    const float* __restrict__ x, const ushort_t* __restrict__ W1t,
    ushort_t* __restrict__ h1, int M,
    const int* __restrict__ ei, int E0, int Etot,
    const int* __restrict__ row_start, int* __restrict__ cursor,
    int* __restrict__ csr_src,
    const float* __restrict__ Wsrc, const float* __restrict__ Wdst,
    float* __restrict__ a_src, float* __restrict__ a_dst,
    int GB1, int FB) {
  __shared__ char smem[10240];
  const int bid = blockIdx.x;
  const int tid = threadIdx.x;

  if (bid < GB1) {
    // ---- gemm1: h1[M,256] = bf16(x[M,128] @ W1), W1t[256][128] bf16 ----
    ushort_t* As = (ushort_t*)smem;
    ushort_t* Bs = As + 64 * 40;
    const int lane = tid & 63;
    const int wave = tid >> 6;
    const int wr = wave >> 1, wc = wave & 1;
    const int row0 = (bid >> 2) * 64, col0 = (bid & 3) * 64;
    const int sr = tid >> 2;
    const int sk = (tid & 3) * 8;
    const int l15 = lane & 15;
    const int lk8 = (lane >> 4) * 8;
    const int K = 128;

    f32x4 acc[2][2];
    #pragma unroll
    for (int i = 0; i < 2; ++i)
      #pragma unroll
      for (int j = 0; j < 2; ++j) acc[i][j] = (f32x4){0.f, 0.f, 0.f, 0.f};

    for (int k0 = 0; k0 < K; k0 += 32) {
      const int gr = row0 + sr;
      float4 f0 = {0.f, 0.f, 0.f, 0.f}, f1 = {0.f, 0.f, 0.f, 0.f};
      if (gr < M) {
        f0 = *(const float4*)&x[(size_t)gr * K + k0 + sk];
        f1 = *(const float4*)&x[(size_t)gr * K + k0 + sk + 4];
      }
      uint4 av;
      av.x = pack2(f0.x, f0.y);
      av.y = pack2(f0.z, f0.w);
      av.z = pack2(f1.x, f1.y);
      av.w = pack2(f1.z, f1.w);
      *(uint4*)&As[sr * 40 + sk] = av;
      uint4 bv = *(const uint4*)&W1t[(size_t)(col0 + sr) * K + k0 + sk];
      *(uint4*)&Bs[sr * 40 + sk] = bv;
      __syncthreads();

      bf16x8 af[2], bfr[2];
      #pragma unroll
      for (int mi = 0; mi < 2; ++mi)
        af[mi] = *(const bf16x8*)&As[(wr * 32 + mi * 16 + l15) * 40 + lk8];
      #pragma unroll
      for (int ni = 0; ni < 2; ++ni)
        bfr[ni] = *(const bf16x8*)&Bs[(wc * 32 + ni * 16 + l15) * 40 + lk8];
      #pragma unroll
      for (int mi = 0; mi < 2; ++mi)
        #pragma unroll
        for (int ni = 0; ni < 2; ++ni)
          acc[mi][ni] = __builtin_amdgcn_mfma_f32_16x16x32_bf16(
              af[mi], bfr[ni], acc[mi][ni], 0, 0, 0);
      __syncthreads();
    }

    #pragma unroll
    for (int mi = 0; mi < 2; ++mi) {
      #pragma unroll
      for (int ni = 0; ni < 2; ++ni) {
        #pragma unroll
        for (int r = 0; r < 4; ++r) {
          int grow = row0 + wr * 32 + mi * 16 + (lane >> 4) * 4 + r;
          int gcol = col0 + wc * 32 + ni * 16 + l15;
          if (grow < M) h1[(size_t)grow * F1 + gcol] = f2bf(acc[mi][ni][r]);
        }
      }
    }
  } else if (bid < GB1 + FB) {
    // ---- fill_csr ----
    int e = (bid - GB1) * 256 + tid;
    if (e >= Etot) return;
    int s, d;
    if (e < E0) { s = ei[e]; d = ei[E0 + e]; } else { s = d = e - E0; }
    int slot = row_start[d] + atomicAdd(&cursor[d], 1);
    csr_src[slot] = s;
  } else {
    // ---- attproj1 ----
    float* ws = (float*)smem;
    float* wd = ws + 1024;
    #pragma unroll
    for (int i = 0; i < 4; ++i) {
      ws[tid + i * 256] = Wsrc[tid + i * 256];
      wd[tid + i * 256] = Wdst[tid + i * 256];
    }
    __syncthreads();
    const int node = (bid - GB1 - FB) * 32 + (tid >> 3);
    const int h = tid & 7;
    if (node >= M) return;
    float as = 0.f, ad = 0.f;
    const float* xr = &x[(size_t)node * 128];
    for (int k = 0; k < 128; ++k) {
      float xv = xr[k];
      as += xv * ws[k * 8 + h];
      ad += xv * wd[k * 8 + h];
    }
    a_src[node * 8 + h] = as;
    a_dst[node * 8 + h] = ad;
  }
}

// -------------------------- MFMA GEMM (layer 2) -----------------------------
__global__ __launch_bounds__(256) void gemm_bf16(
    const ushort_t* __restrict__ Ab, const ushort_t* __restrict__ Bt,
    ushort_t* __restrict__ Cb, int M, int N, int K) {
  __shared__ ushort_t As[64 * 40];
  __shared__ ushort_t Bs[64 * 40];
  const int tid = threadIdx.x;
  const int lane = tid & 63;
  const int wave = tid >> 6;
  const int wr = wave >> 1, wc = wave & 1;
  const int row0 = blockIdx.y * 64, col0 = blockIdx.x * 64;
  const int sr = tid >> 2;
  const int sk = (tid & 3) * 8;
  const int l15 = lane & 15;
  const int lk8 = (lane >> 4) * 8;

  f32x4 acc[2][2];
  #pragma unroll
  for (int i = 0; i < 2; ++i)
    #pragma unroll
    for (int j = 0; j < 2; ++j) acc[i][j] = (f32x4){0.f, 0.f, 0.f, 0.f};

  for (int k0 = 0; k0 < K; k0 += 32) {
    const int gr = row0 + sr;
    uint4 av = {0u, 0u, 0u, 0u};
    if (gr < M) av = *(const uint4*)&Ab[(size_t)gr * K + k0 + sk];
    *(uint4*)&As[sr * 40 + sk] = av;
    uint4 bv = *(const uint4*)&Bt[(size_t)(col0 + sr) * K + k0 + sk];
    *(uint4*)&Bs[sr * 40 + sk] = bv;
    __syncthreads();

    bf16x8 af[2], bfr[2];
    #pragma unroll
    for (int mi = 0; mi < 2; ++mi)
      af[mi] = *(const bf16x8*)&As[(wr * 32 + mi * 16 + l15) * 40 + lk8];
    #pragma unroll
    for (int ni = 0; ni < 2; ++ni)
      bfr[ni] = *(const bf16x8*)&Bs[(wc * 32 + ni * 16 + l15) * 40 + lk8];
    #pragma unroll
    for (int mi = 0; mi < 2; ++mi)
      #pragma unroll
      for (int ni = 0; ni < 2; ++ni)
        acc[mi][ni] = __builtin_amdgcn_mfma_f32_16x16x32_bf16(
            af[mi], bfr[ni], acc[mi][ni], 0, 0, 0);
    __syncthreads();
  }

  #pragma unroll
  for (int mi = 0; mi < 2; ++mi) {
    #pragma unroll
    for (int ni = 0; ni < 2; ++ni) {
      #pragma unroll
      for (int r = 0; r < 4; ++r) {
        int grow = row0 + wr * 32 + mi * 16 + (lane >> 4) * 4 + r;
        int gcol = col0 + wc * 32 + ni * 16 + l15;
        if (grow < M) Cb[(size_t)grow * N + gcol] = f2bf(acc[mi][ni][r]);
      }
    }
  }
}

// ---------- gather layer 1: single-pass + fused attproj2 epilogue -----------
__global__ __launch_bounds__(256) void gather1(
    const int* __restrict__ csr_src, const int* __restrict__ row_start,
    const float* __restrict__ a_src, const float* __restrict__ a_dst,
    const ushort_t* __restrict__ h1, const float* __restrict__ b,
    const float* __restrict__ ws2, const float* __restrict__ wd2,
    ushort_t* __restrict__ out, float* __restrict__ a_src2,
    float* __restrict__ a_dst2) {
  const int d = blockIdx.x;
  const int tid = threadIdx.x;
  const int rs = row_start[d];
  const int deg = row_start[d + 1] - rs;
  __shared__ float coef[64 * 8];
  __shared__ int s_lds[64];
  __shared__ float red8[32];
  __shared__ float rdeninv[8];
  __shared__ float part[256][4];

  const int h8 = tid & 7;
  const int slot = tid >> 3;
  const int wv = tid >> 6;
  const int lane = tid & 63;
  const int cg = tid & 63;
  const int hh = cg >> 3;
  const float adv = a_dst[d * 8 + h8];

  float dpart = 0.f;
  f32x4 acc = {0.f, 0.f, 0.f, 0.f};

  for (int t0 = 0; t0 < deg; t0 += 64) {
    const int nt = min(64, deg - t0);
    __syncthreads();
    #pragma unroll
    for (int half = 0; half < 2; ++half) {
      const int e = slot + half * 32;
      if (e < nt) {
        const int s = csr_src[rs + t0 + e];
        if (h8 == 0) s_lds[e] = s;
        const float ex = __expf(lrelu(a_src[s * 8 + h8] + adv));
        coef[e * 8 + h8] = ex;
        dpart += ex;
      }
    }
    __syncthreads();
    for (int i = wv; i < nt; i += 4) {
      const int s = s_lds[i];
      const float cf = coef[i * 8 + hh];
      ushort4 hv = *(const ushort4*)&h1[(size_t)s * F1 + cg * 4];
      acc[0] += cf * bf2f(hv.x);
      acc[1] += cf * bf2f(hv.y);
      acc[2] += cf * bf2f(hv.z);
      acc[3] += cf * bf2f(hv.w);
    }
  }

  dpart += __shfl_xor(dpart, 8, 64);
  dpart += __shfl_xor(dpart, 16, 64);
  dpart += __shfl_xor(dpart, 32, 64);
  part[tid][0] = acc[0];
  part[tid][1] = acc[1];
  part[tid][2] = acc[2];
  part[tid][3] = acc[3];
  if (lane < 8) red8[wv * 8 + lane] = dpart;
  __syncthreads();
  if (tid < 8)
    rdeninv[tid] = 1.f / (red8[tid] + red8[8 + tid] + red8[16 + tid] +
                          red8[24 + tid]);
  __syncthreads();
  if (tid < 64) {
    const int ch = tid * 4;
    const float rden = rdeninv[tid >> 3];
    ushort4 ob;
    float ps = 0.f, pd = 0.f;
    #pragma unroll
    for (int j = 0; j < 4; ++j) {
      float v = part[tid][j] + part[tid + 64][j] + part[tid + 128][j] +
                part[tid + 192][j];
      v = fmaxf(v * rden + b[ch + j], 0.f);
      ushort_t bv = f2bf(v);
      ((ushort_t*)&ob)[j] = bv;
      float r = bf2f(bv);
      ps += r * ws2[ch + j];
      pd += r * wd2[ch + j];
    }
    *(ushort4*)&out[(size_t)d * F1 + ch] = ob;
    #pragma unroll
    for (int off = 32; off > 0; off >>= 1) {
      ps += __shfl_xor(ps, off, 64);
      pd += __shfl_xor(pd, off, 64);
    }
    if (tid == 0) {
      a_src2[d] = ps;
      a_dst2[d] = pd;
    }
  }
}

// ------ gather layer 2 + log_softmax: single-pass, scale-at-end -------------
__global__ __launch_bounds__(256) void gather2(
    const int* __restrict__ csr_src, const int* __restrict__ row_start,
    const float* __restrict__ a_src, const float* __restrict__ a_dst,
    const ushort_t* __restrict__ h2, const float* __restrict__ b,
    float* __restrict__ out, int n) {
  const int d = blockIdx.x * 4 + (threadIdx.x >> 6);
  const int lane = threadIdx.x & 63;
  if (d >= n) return;
  const int rs = row_start[d];
  const int deg = row_start[d + 1] - rs;
  const float adv = a_dst[d];

  float lsum = 0.f;
  float acc = 0.f;
  for (int t0 = 0; t0 < deg; t0 += 64) {
    int myi = t0 + lane;
    int mys = 0;
    float myc = 0.f;
    if (myi < deg) {
      mys = csr_src[rs + myi];
      myc = __expf(lrelu(a_src[mys] + adv));
      lsum += myc;
    }
    int nt = min(64, deg - t0);
    for (int j = 0; j < nt; ++j) {
      int s = __shfl(mys, j, 64);
      float cf = __shfl(myc, j, 64);
      acc += cf * bf2f(h2[(size_t)s * F2 + lane]);
    }
  }
  #pragma unroll
  for (int off = 32; off > 0; off >>= 1) lsum += __shfl_xor(lsum, off, 64);
  const float rden = 1.f / lsum;

  float v = acc * rden + b[lane];
  float m = v;
  #pragma unroll
  for (int off = 32; off > 0; off >>= 1) m = fmaxf(m, __shfl_xor(m, off, 64));
  float ex = __expf(v - m);
  float ss = ex;
  #pragma unroll
  for (int off = 32; off > 0; off >>= 1) ss += __shfl_xor(ss, off, 64);
  out[(size_t)d * F2 + lane] = v - m - __logf(ss);
}

// ------------------------------- launch -------------------------------------
extern "C" void kernel_launch(void* const* d_in, const int* in_sizes, int n_in,
                              void* d_out, int out_size, void* d_ws,
                              size_t ws_size, hipStream_t stream) {
  const float* x        = (const float*)d_in[0];
  const int*   ei       = (const int*)d_in[1];
  const float* W1       = (const float*)d_in[2];
  const float* att_src1 = (const float*)d_in[3];
  const float* att_dst1 = (const float*)d_in[4];
  const float* b1       = (const float*)d_in[5];
  const float* W2       = (const float*)d_in[6];
  const float* att_src2 = (const float*)d_in[7];
  const float* att_dst2 = (const float*)d_in[8];
  const float* b2       = (const float*)d_in[9];

  const int N = in_sizes[0] / 128;
  const int E0 = in_sizes[1] / 2;
  const int Etot = E0 + N;
  const int nb1024 = (N + 1023) / 1024;

  char* w = (char*)d_ws;
  size_t off = 0;
  auto alloc = [&](size_t bytes) {
    char* p = w + off;
    off += (bytes + 255) & ~(size_t)255;
    return p;
  };
  ushort_t* h1        = (ushort_t*)alloc((size_t)N * F1 * 2);
  ushort_t* h1out     = (ushort_t*)alloc((size_t)N * F1 * 2);
  ushort_t* h2b       = (ushort_t*)alloc((size_t)N * F2 * 2);
  int*      csr_src   = (int*)     alloc((size_t)Etot * 4);
  int*      row_start = (int*)     alloc((size_t)(N + 1) * 4);
  int*      cc        = (int*)     alloc((size_t)2 * N * 4);
  int*      counts    = cc;
  int*      cursor    = cc + N;
  int*      btot      = (int*)     alloc((size_t)nb1024 * 4);
  int*      boff      = (int*)     alloc((size_t)nb1024 * 4);
  float*    a_src1    = (float*)   alloc((size_t)N * HEADS1 * 4);
  float*    a_dst1    = (float*)   alloc((size_t)N * HEADS1 * 4);
  float*    a_src2    = (float*)   alloc((size_t)N * 4);
  float*    a_dst2    = (float*)   alloc((size_t)N * 4);
  ushort_t* W1t       = (ushort_t*)alloc(128 * 256 * 2);
  ushort_t* W2t       = (ushort_t*)alloc(256 * 64 * 2);
  float*    Wsrc1     = (float*)   alloc(128 * 8 * 4);
  float*    Wdst1     = (float*)   alloc(128 * 8 * 4);
  float*    w_s2      = (float*)   alloc(256 * 4);
  float*    w_d2      = (float*)   alloc(256 * 4);

  hipMemsetAsync(cc, 0, (size_t)2 * N * 4, stream);

  dim3 blk(256);
  const int eb = (Etot + 255) / 256;
  const int gy = (N + 63) / 64;
  const int GB1 = 4 * gy;                 // gemm1 blocks
  const int attb = (N + 31) / 32;         // attproj1 blocks

  kernelA<<<197 + eb, blk, 0, stream>>>(W1, W2, att_src1, att_dst1, att_src2,
                                        att_dst2, W1t, W2t, Wsrc1, Wdst1,
                                        w_s2, w_d2, ei, E0, Etot, counts);
  scanA<<<nb1024, blk, 0, stream>>>(counts, row_start, btot, N);
  scanB<<<1, 64, 0, stream>>>(btot, boff, nb1024);
  scanC<<<(N + 255) / 256, blk, 0, stream>>>(row_start, boff, N);

  kernelB<<<GB1 + eb + attb, blk, 0, stream>>>(
      x, W1t, h1, N, ei, E0, Etot, row_start, cursor, csr_src, Wsrc1, Wdst1,
      a_src1, a_dst1, GB1, eb);

  gather1<<<N, blk, 0, stream>>>(csr_src, row_start, a_src1, a_dst1, h1, b1,
                                 w_s2, w_d2, h1out, a_src2, a_dst2);

  gemm_bf16<<<dim3(F2 / 64, gy), blk, 0, stream>>>(h1out, W2t, h2b, N, F2, F1);
  gather2<<<(N + 3) / 4, blk, 0, stream>>>(csr_src, row_start, a_src2, a_dst2,
                                           h2b, b2, (float*)d_out, N);
}

// Round 15
// 262.637 us; speedup vs baseline: 14.9437x; 1.0571x over previous
//
#include <hip/hip_runtime.h>
#include <hip/hip_bf16.h>
#include <cmath>

// ---------------------------------------------------------------------------
// GAT 2-layer forward. R15: R14's 4-edge-parallel gather2 with the divergent
// shfl fixed — trip count padded to a multiple of 4 so every __shfl source
// lane is active (CDNA ds_bpermute returns undefined data from inactive
// lanes; that was R6's and R14's 0.12-0.16 absmax bug).
// ---------------------------------------------------------------------------

#define HEADS1 8
#define F1 256
#define F2 64
#define NEG_SLOPE 0.2f

typedef unsigned int uint;
typedef unsigned short ushort_t;
typedef __attribute__((ext_vector_type(8))) short bf16x8;
typedef __attribute__((ext_vector_type(4))) float f32x4;

__device__ __forceinline__ float lrelu(float x) {
  return x >= 0.f ? x : NEG_SLOPE * x;
}
__device__ __forceinline__ ushort_t f2bf(float f) {
  uint u = __float_as_uint(f);
  return (ushort_t)((u + 0x7FFFu + ((u >> 16) & 1u)) >> 16);
}
__device__ __forceinline__ float bf2f(ushort_t u) {
  return __uint_as_float(((uint)u) << 16);
}
__device__ __forceinline__ uint pack2(float a, float b) {
  return (uint)f2bf(a) | ((uint)f2bf(b) << 16);
}

// --------------- kernel A: weight prep (197 blocks) + deg_count -------------
__global__ __launch_bounds__(256) void kernelA(
    const float* __restrict__ W1, const float* __restrict__ W2,
    const float* __restrict__ att_src1, const float* __restrict__ att_dst1,
    const float* __restrict__ att_src2, const float* __restrict__ att_dst2,
    ushort_t* __restrict__ W1t, ushort_t* __restrict__ W2t,
    float* __restrict__ Wsrc1, float* __restrict__ Wdst1,
    float* __restrict__ w_s2, float* __restrict__ w_d2,
    const int* __restrict__ ei, int E0, int Etot, int* __restrict__ counts) {
  const int bid = blockIdx.x;
  const int tid = threadIdx.x;
  if (bid < 128) {
    int idx = bid * 256 + tid;
    int r = idx >> 8, c = idx & 255;
    W1t[(size_t)c * 128 + r] = f2bf(W1[idx]);
  } else if (bid < 192) {
    int idx = (bid - 128) * 256 + tid;
    int r = idx >> 6, c = idx & 63;
    W2t[(size_t)c * 256 + r] = f2bf(W2[idx]);
  } else if (bid < 196) {
    int idx = (bid - 192) * 256 + tid;
    int k = idx >> 3, h = idx & 7;
    float as = 0.f, ad = 0.f;
    #pragma unroll
    for (int c = 0; c < 32; ++c) {
      float wv = W1[(size_t)k * 256 + h * 32 + c];
      as += wv * att_src1[h * 32 + c];
      ad += wv * att_dst1[h * 32 + c];
    }
    Wsrc1[idx] = as;
    Wdst1[idx] = ad;
  } else if (bid < 197) {
    int k = tid;
    float as = 0.f, ad = 0.f;
    #pragma unroll
    for (int c = 0; c < 64; ++c) {
      float wv = W2[(size_t)k * 64 + c];
      as += wv * att_src2[c];
      ad += wv * att_dst2[c];
    }
    w_s2[k] = as;
    w_d2[k] = ad;
  } else {
    int e = (bid - 197) * 256 + tid;
    if (e >= Etot) return;
    int d = (e < E0) ? ei[E0 + e] : (e - E0);
    atomicAdd(&counts[d], 1);
  }
}

// -------------------------------- scans -------------------------------------
__global__ __launch_bounds__(256) void scanA(
    const int* __restrict__ counts, int* __restrict__ row_start,
    int* __restrict__ btot, int n) {
  __shared__ int wsum[4];
  const int tid = threadIdx.x;
  const int lane = tid & 63;
  const int wid = tid >> 6;
  const int base = blockIdx.x * 1024 + tid * 4;
  int c[4], inc[4];
  #pragma unroll
  for (int j = 0; j < 4; ++j)
    c[j] = (base + j < n) ? counts[base + j] : 0;
  inc[0] = c[0];
  #pragma unroll
  for (int j = 1; j < 4; ++j) inc[j] = inc[j - 1] + c[j];
  int tsum = inc[3];
  int wincl = tsum;
  #pragma unroll
  for (int off = 1; off < 64; off <<= 1) {
    int v = __shfl_up(wincl, off, 64);
    if (lane >= off) wincl += v;
  }
  if (lane == 63) wsum[wid] = wincl;
  __syncthreads();
  int woff = 0;
  #pragma unroll
  for (int j = 0; j < 4; ++j)
    if (j < wid) woff += wsum[j];
  int prefix = woff + (wincl - tsum);
  #pragma unroll
  for (int j = 0; j < 4; ++j)
    if (base + j < n) row_start[base + j + 1] = prefix + inc[j];
  if (tid == 255) btot[blockIdx.x] = woff + wincl;
}

__global__ __launch_bounds__(64) void scanB(const int* __restrict__ btot,
                                            int* __restrict__ boff, int nb) {
  if (threadIdx.x == 0) {
    int run = 0;
    for (int b = 0; b < nb; ++b) {
      boff[b] = run;
      run += btot[b];
    }
  }
}

__global__ __launch_bounds__(256) void scanC(int* __restrict__ row_start,
                                             const int* __restrict__ boff,
                                             int n) {
  int i = blockIdx.x * 256 + threadIdx.x;
  if (i < n) row_start[i + 1] += boff[i >> 10];
  if (i == 0) row_start[0] = 0;
}

// -------- kernel B: gemm1 + fill_csr + attproj1 (block-range dispatch) ------
__global__ __launch_bounds__(256) void kernelB(
    const float* __restrict__ x, const ushort_t* __restrict__ W1t,
    ushort_t* __restrict__ h1, int M,
    const int* __restrict__ ei, int E0, int Etot,
    const int* __restrict__ row_start, int* __restrict__ cursor,
    int* __restrict__ csr_src,
    const float* __restrict__ Wsrc, const float* __restrict__ Wdst,
    float* __restrict__ a_src, float* __restrict__ a_dst,
    int GB1, int FB) {
  __shared__ char smem[10240];
  const int bid = blockIdx.x;
  const int tid = threadIdx.x;

  if (bid < GB1) {
    ushort_t* As = (ushort_t*)smem;
    ushort_t* Bs = As + 64 * 40;
    const int lane = tid & 63;
    const int wave = tid >> 6;
    const int wr = wave >> 1, wc = wave & 1;
    const int row0 = (bid >> 2) * 64, col0 = (bid & 3) * 64;
    const int sr = tid >> 2;
    const int sk = (tid & 3) * 8;
    const int l15 = lane & 15;
    const int lk8 = (lane >> 4) * 8;
    const int K = 128;

    f32x4 acc[2][2];
    #pragma unroll
    for (int i = 0; i < 2; ++i)
      #pragma unroll
      for (int j = 0; j < 2; ++j) acc[i][j] = (f32x4){0.f, 0.f, 0.f, 0.f};

    for (int k0 = 0; k0 < K; k0 += 32) {
      const int gr = row0 + sr;
      float4 f0 = {0.f, 0.f, 0.f, 0.f}, f1 = {0.f, 0.f, 0.f, 0.f};
      if (gr < M) {
        f0 = *(const float4*)&x[(size_t)gr * K + k0 + sk];
        f1 = *(const float4*)&x[(size_t)gr * K + k0 + sk + 4];
      }
      uint4 av;
      av.x = pack2(f0.x, f0.y);
      av.y = pack2(f0.z, f0.w);
      av.z = pack2(f1.x, f1.y);
      av.w = pack2(f1.z, f1.w);
      *(uint4*)&As[sr * 40 + sk] = av;
      uint4 bv = *(const uint4*)&W1t[(size_t)(col0 + sr) * K + k0 + sk];
      *(uint4*)&Bs[sr * 40 + sk] = bv;
      __syncthreads();

      bf16x8 af[2], bfr[2];
      #pragma unroll
      for (int mi = 0; mi < 2; ++mi)
        af[mi] = *(const bf16x8*)&As[(wr * 32 + mi * 16 + l15) * 40 + lk8];
      #pragma unroll
      for (int ni = 0; ni < 2; ++ni)
        bfr[ni] = *(const bf16x8*)&Bs[(wc * 32 + ni * 16 + l15) * 40 + lk8];
      #pragma unroll
      for (int mi = 0; mi < 2; ++mi)
        #pragma unroll
        for (int ni = 0; ni < 2; ++ni)
          acc[mi][ni] = __builtin_amdgcn_mfma_f32_16x16x32_bf16(
              af[mi], bfr[ni], acc[mi][ni], 0, 0, 0);
      __syncthreads();
    }

    #pragma unroll
    for (int mi = 0; mi < 2; ++mi) {
      #pragma unroll
      for (int ni = 0; ni < 2; ++ni) {
        #pragma unroll
        for (int r = 0; r < 4; ++r) {
          int grow = row0 + wr * 32 + mi * 16 + (lane >> 4) * 4 + r;
          int gcol = col0 + wc * 32 + ni * 16 + l15;
          if (grow < M) h1[(size_t)grow * F1 + gcol] = f2bf(acc[mi][ni][r]);
        }
      }
    }
  } else if (bid < GB1 + FB) {
    int e = (bid - GB1) * 256 + tid;
    if (e >= Etot) return;
    int s, d;
    if (e < E0) { s = ei[e]; d = ei[E0 + e]; } else { s = d = e - E0; }
    int slot = row_start[d] + atomicAdd(&cursor[d], 1);
    csr_src[slot] = s;
  } else {
    float* ws = (float*)smem;
    float* wd = ws + 1024;
    #pragma unroll
    for (int i = 0; i < 4; ++i) {
      ws[tid + i * 256] = Wsrc[tid + i * 256];
      wd[tid + i * 256] = Wdst[tid + i * 256];
    }
    __syncthreads();
    const int node = (bid - GB1 - FB) * 32 + (tid >> 3);
    const int h = tid & 7;
    if (node >= M) return;
    float as = 0.f, ad = 0.f;
    const float* xr = &x[(size_t)node * 128];
    for (int k = 0; k < 128; ++k) {
      float xv = xr[k];
      as += xv * ws[k * 8 + h];
      ad += xv * wd[k * 8 + h];
    }
    a_src[node * 8 + h] = as;
    a_dst[node * 8 + h] = ad;
  }
}

// -------------------------- MFMA GEMM (layer 2) -----------------------------
__global__ __launch_bounds__(256) void gemm_bf16(
    const ushort_t* __restrict__ Ab, const ushort_t* __restrict__ Bt,
    ushort_t* __restrict__ Cb, int M, int N, int K) {
  __shared__ ushort_t As[64 * 40];
  __shared__ ushort_t Bs[64 * 40];
  const int tid = threadIdx.x;
  const int lane = tid & 63;
  const int wave = tid >> 6;
  const int wr = wave >> 1, wc = wave & 1;
  const int row0 = blockIdx.y * 64, col0 = blockIdx.x * 64;
  const int sr = tid >> 2;
  const int sk = (tid & 3) * 8;
  const int l15 = lane & 15;
  const int lk8 = (lane >> 4) * 8;

  f32x4 acc[2][2];
  #pragma unroll
  for (int i = 0; i < 2; ++i)
    #pragma unroll
    for (int j = 0; j < 2; ++j) acc[i][j] = (f32x4){0.f, 0.f, 0.f, 0.f};

  for (int k0 = 0; k0 < K; k0 += 32) {
    const int gr = row0 + sr;
    uint4 av = {0u, 0u, 0u, 0u};
    if (gr < M) av = *(const uint4*)&Ab[(size_t)gr * K + k0 + sk];
    *(uint4*)&As[sr * 40 + sk] = av;
    uint4 bv = *(const uint4*)&Bt[(size_t)(col0 + sr) * K + k0 + sk];
    *(uint4*)&Bs[sr * 40 + sk] = bv;
    __syncthreads();

    bf16x8 af[2], bfr[2];
    #pragma unroll
    for (int mi = 0; mi < 2; ++mi)
      af[mi] = *(const bf16x8*)&As[(wr * 32 + mi * 16 + l15) * 40 + lk8];
    #pragma unroll
    for (int ni = 0; ni < 2; ++ni)
      bfr[ni] = *(const bf16x8*)&Bs[(wc * 32 + ni * 16 + l15) * 40 + lk8];
    #pragma unroll
    for (int mi = 0; mi < 2; ++mi)
      #pragma unroll
      for (int ni = 0; ni < 2; ++ni)
        acc[mi][ni] = __builtin_amdgcn_mfma_f32_16x16x32_bf16(
            af[mi], bfr[ni], acc[mi][ni], 0, 0, 0);
    __syncthreads();
  }

  #pragma unroll
  for (int mi = 0; mi < 2; ++mi) {
    #pragma unroll
    for (int ni = 0; ni < 2; ++ni) {
      #pragma unroll
      for (int r = 0; r < 4; ++r) {
        int grow = row0 + wr * 32 + mi * 16 + (lane >> 4) * 4 + r;
        int gcol = col0 + wc * 32 + ni * 16 + l15;
        if (grow < M) Cb[(size_t)grow * N + gcol] = f2bf(acc[mi][ni][r]);
      }
    }
  }
}

// ---------- gather layer 1: single-pass + fused attproj2 epilogue -----------
__global__ __launch_bounds__(256) void gather1(
    const int* __restrict__ csr_src, const int* __restrict__ row_start,
    const float* __restrict__ a_src, const float* __restrict__ a_dst,
    const ushort_t* __restrict__ h1, const float* __restrict__ b,
    const float* __restrict__ ws2, const float* __restrict__ wd2,
    ushort_t* __restrict__ out, float* __restrict__ a_src2,
    float* __restrict__ a_dst2) {
  const int d = blockIdx.x;
  const int tid = threadIdx.x;
  const int rs = row_start[d];
  const int deg = row_start[d + 1] - rs;
  __shared__ float coef[64 * 8];
  __shared__ int s_lds[64];
  __shared__ float red8[32];
  __shared__ float rdeninv[8];
  __shared__ float part[256][4];

  const int h8 = tid & 7;
  const int slot = tid >> 3;
  const int wv = tid >> 6;
  const int lane = tid & 63;
  const int cg = tid & 63;
  const int hh = cg >> 3;
  const float adv = a_dst[d * 8 + h8];

  float dpart = 0.f;
  f32x4 acc = {0.f, 0.f, 0.f, 0.f};

  for (int t0 = 0; t0 < deg; t0 += 64) {
    const int nt = min(64, deg - t0);
    __syncthreads();
    #pragma unroll
    for (int half = 0; half < 2; ++half) {
      const int e = slot + half * 32;
      if (e < nt) {
        const int s = csr_src[rs + t0 + e];
        if (h8 == 0) s_lds[e] = s;
        const float ex = __expf(lrelu(a_src[s * 8 + h8] + adv));
        coef[e * 8 + h8] = ex;
        dpart += ex;
      }
    }
    __syncthreads();
    for (int i = wv; i < nt; i += 4) {
      const int s = s_lds[i];
      const float cf = coef[i * 8 + hh];
      ushort4 hv = *(const ushort4*)&h1[(size_t)s * F1 + cg * 4];
      acc[0] += cf * bf2f(hv.x);
      acc[1] += cf * bf2f(hv.y);
      acc[2] += cf * bf2f(hv.z);
      acc[3] += cf * bf2f(hv.w);
    }
  }

  dpart += __shfl_xor(dpart, 8, 64);
  dpart += __shfl_xor(dpart, 16, 64);
  dpart += __shfl_xor(dpart, 32, 64);
  part[tid][0] = acc[0];
  part[tid][1] = acc[1];
  part[tid][2] = acc[2];
  part[tid][3] = acc[3];
  if (lane < 8) red8[wv * 8 + lane] = dpart;
  __syncthreads();
  if (tid < 8)
    rdeninv[tid] = 1.f / (red8[tid] + red8[8 + tid] + red8[16 + tid] +
                          red8[24 + tid]);
  __syncthreads();
  if (tid < 64) {
    const int ch = tid * 4;
    const float rden = rdeninv[tid >> 3];
    ushort4 ob;
    float ps = 0.f, pd = 0.f;
    #pragma unroll
    for (int j = 0; j < 4; ++j) {
      float v = part[tid][j] + part[tid + 64][j] + part[tid + 128][j] +
                part[tid + 192][j];
      v = fmaxf(v * rden + b[ch + j], 0.f);
      ushort_t bv = f2bf(v);
      ((ushort_t*)&ob)[j] = bv;
      float r = bf2f(bv);
      ps += r * ws2[ch + j];
      pd += r * wd2[ch + j];
    }
    *(ushort4*)&out[(size_t)d * F1 + ch] = ob;
    #pragma unroll
    for (int off = 32; off > 0; off >>= 1) {
      ps += __shfl_xor(ps, off, 64);
      pd += __shfl_xor(pd, off, 64);
    }
    if (tid == 0) {
      a_src2[d] = ps;
      a_dst2[d] = pd;
    }
  }
}

// ------ gather layer 2 + log_softmax: 4-edge-parallel, UNIFORM trip count ---
// lane = (sub=lane>>4, q=lane&15); 16-lane group loads one edge's 128B row.
// Trip count padded to a multiple of 4 so all 64 lanes stay active at every
// __shfl (padding edges broadcast myc=0 -> contribute nothing).
__global__ __launch_bounds__(256) void gather2(
    const int* __restrict__ csr_src, const int* __restrict__ row_start,
    const float* __restrict__ a_src, const float* __restrict__ a_dst,
    const ushort_t* __restrict__ h2, const float* __restrict__ b,
    float* __restrict__ out, int n) {
  const int d = blockIdx.x * 4 + (threadIdx.x >> 6);
  const int lane = threadIdx.x & 63;
  if (d >= n) return;
  const int rs = row_start[d];
  const int deg = row_start[d + 1] - rs;
  const float adv = a_dst[d];

  const int sub = lane >> 4;   // edge sub-group 0..3
  const int q = lane & 15;     // channel quad 0..15
  float lsum = 0.f;
  f32x4 acc = {0.f, 0.f, 0.f, 0.f};
  for (int t0 = 0; t0 < deg; t0 += 64) {
    int myi = t0 + lane;
    int mys = 0;
    float myc = 0.f;
    if (myi < deg) {
      mys = csr_src[rs + myi];
      myc = __expf(lrelu(a_src[mys] + adv));
      lsum += myc;
    }
    const int nt = min(64, deg - t0);
    const int ntp = (nt + 3) & ~3;   // uniform trips: ntp/4 per sub-group
    for (int e = sub; e < ntp; e += 4) {
      float cf = __shfl(myc, e, 64);  // src lane always active (uniform loop)
      int s = __shfl(mys, e, 64);
      ushort4 hv = *(const ushort4*)&h2[(size_t)s * F2 + q * 4];
      acc[0] += cf * bf2f(hv.x);
      acc[1] += cf * bf2f(hv.y);
      acc[2] += cf * bf2f(hv.z);
      acc[3] += cf * bf2f(hv.w);
    }
  }
  #pragma unroll
  for (int off = 32; off > 0; off >>= 1) lsum += __shfl_xor(lsum, off, 64);
  const float rden = 1.f / lsum;

  // reduce across the 4 edge sub-groups (lane bits 4,5)
  #pragma unroll
  for (int j = 0; j < 4; ++j) {
    acc[j] += __shfl_xor(acc[j], 16, 64);
    acc[j] += __shfl_xor(acc[j], 32, 64);
  }
  // redistribute: lane l wants channel l = (l>>2)*4 + (l&3)
  float vx = __shfl(acc[0], lane >> 2, 64);
  float vy = __shfl(acc[1], lane >> 2, 64);
  float vz = __shfl(acc[2], lane >> 2, 64);
  float vw = __shfl(acc[3], lane >> 2, 64);
  int c3 = lane & 3;
  float v = (c3 == 0) ? vx : (c3 == 1) ? vy : (c3 == 2) ? vz : vw;
  v = v * rden + b[lane];
  float m = v;
  #pragma unroll
  for (int off = 32; off > 0; off >>= 1) m = fmaxf(m, __shfl_xor(m, off, 64));
  float ex = __expf(v - m);
  float ss = ex;
  #pragma unroll
  for (int off = 32; off > 0; off >>= 1) ss += __shfl_xor(ss, off, 64);
  out[(size_t)d * F2 + lane] = v - m - __logf(ss);
}

// ------------------------------- launch -------------------------------------
extern "C" void kernel_launch(void* const* d_in, const int* in_sizes, int n_in,
                              void* d_out, int out_size, void* d_ws,
                              size_t ws_size, hipStream_t stream) {
  const float* x        = (const float*)d_in[0];
  const int*   ei       = (const int*)d_in[1];
  const float* W1       = (const float*)d_in[2];
  const float* att_src1 = (const float*)d_in[3];
  const float* att_dst1 = (const float*)d_in[4];
  const float* b1       = (const float*)d_in[5];
  const float* W2       = (const float*)d_in[6];
  const float* att_src2 = (const float*)d_in[7];
  const float* att_dst2 = (const float*)d_in[8];
  const float* b2       = (const float*)d_in[9];

  const int N = in_sizes[0] / 128;
  const int E0 = in_sizes[1] / 2;
  const int Etot = E0 + N;
  const int nb1024 = (N + 1023) / 1024;

  char* w = (char*)d_ws;
  size_t off = 0;
  auto alloc = [&](size_t bytes) {
    char* p = w + off;
    off += (bytes + 255) & ~(size_t)255;
    return p;
  };
  ushort_t* h1        = (ushort_t*)alloc((size_t)N * F1 * 2);
  ushort_t* h1out     = (ushort_t*)alloc((size_t)N * F1 * 2);
  ushort_t* h2b       = (ushort_t*)alloc((size_t)N * F2 * 2);
  int*      csr_src   = (int*)     alloc((size_t)Etot * 4);
  int*      row_start = (int*)     alloc((size_t)(N + 1) * 4);
  int*      cc        = (int*)     alloc((size_t)2 * N * 4);
  int*      counts    = cc;
  int*      cursor    = cc + N;
  int*      btot      = (int*)     alloc((size_t)nb1024 * 4);
  int*      boff      = (int*)     alloc((size_t)nb1024 * 4);
  float*    a_src1    = (float*)   alloc((size_t)N * HEADS1 * 4);
  float*    a_dst1    = (float*)   alloc((size_t)N * HEADS1 * 4);
  float*    a_src2    = (float*)   alloc((size_t)N * 4);
  float*    a_dst2    = (float*)   alloc((size_t)N * 4);
  ushort_t* W1t       = (ushort_t*)alloc(128 * 256 * 2);
  ushort_t* W2t       = (ushort_t*)alloc(256 * 64 * 2);
  float*    Wsrc1     = (float*)   alloc(128 * 8 * 4);
  float*    Wdst1     = (float*)   alloc(128 * 8 * 4);
  float*    w_s2      = (float*)   alloc(256 * 4);
  float*    w_d2      = (float*)   alloc(256 * 4);

  hipMemsetAsync(cc, 0, (size_t)2 * N * 4, stream);

  dim3 blk(256);
  const int eb = (Etot + 255) / 256;
  const int gy = (N + 63) / 64;
  const int GB1 = 4 * gy;
  const int attb = (N + 31) / 32;

  kernelA<<<197 + eb, blk, 0, stream>>>(W1, W2, att_src1, att_dst1, att_src2,
                                        att_dst2, W1t, W2t, Wsrc1, Wdst1,
                                        w_s2, w_d2, ei, E0, Etot, counts);
  scanA<<<nb1024, blk, 0, stream>>>(counts, row_start, btot, N);
  scanB<<<1, 64, 0, stream>>>(btot, boff, nb1024);
  scanC<<<(N + 255) / 256, blk, 0, stream>>>(row_start, boff, N);

  kernelB<<<GB1 + eb + attb, blk, 0, stream>>>(
      x, W1t, h1, N, ei, E0, Etot, row_start, cursor, csr_src, Wsrc1, Wdst1,
      a_src1, a_dst1, GB1, eb);

  gather1<<<N, blk, 0, stream>>>(csr_src, row_start, a_src1, a_dst1, h1, b1,
                                 w_s2, w_d2, h1out, a_src2, a_dst2);

  gemm_bf16<<<dim3(F2 / 64, gy), blk, 0, stream>>>(h1out, W2t, h2b, N, F2, F1);
  gather2<<<(N + 3) / 4, blk, 0, stream>>>(csr_src, row_start, a_src2, a_dst2,
                                           h2b, b2, (float*)d_out, N);
}

// Round 16
// 252.638 us; speedup vs baseline: 15.5352x; 1.0396x over previous
//
#include <hip/hip_runtime.h>
#include <hip/hip_bf16.h>
#include <cmath>

// ---------------------------------------------------------------------------
// GAT 2-layer forward. R16: scans fused into ONE decoupled-lookback kernel
// (publish block totals via atomicExch sentinel, spin-read predecessors).
// Everything else identical to R15.
// ---------------------------------------------------------------------------

#define HEADS1 8
#define F1 256
#define F2 64
#define NEG_SLOPE 0.2f

typedef unsigned int uint;
typedef unsigned short ushort_t;
typedef __attribute__((ext_vector_type(8))) short bf16x8;
typedef __attribute__((ext_vector_type(4))) float f32x4;

__device__ __forceinline__ float lrelu(float x) {
  return x >= 0.f ? x : NEG_SLOPE * x;
}
__device__ __forceinline__ ushort_t f2bf(float f) {
  uint u = __float_as_uint(f);
  return (ushort_t)((u + 0x7FFFu + ((u >> 16) & 1u)) >> 16);
}
__device__ __forceinline__ float bf2f(ushort_t u) {
  return __uint_as_float(((uint)u) << 16);
}
__device__ __forceinline__ uint pack2(float a, float b) {
  return (uint)f2bf(a) | ((uint)f2bf(b) << 16);
}

// --------------- kernel A: weight prep (197 blocks) + deg_count -------------
__global__ __launch_bounds__(256) void kernelA(
    const float* __restrict__ W1, const float* __restrict__ W2,
    const float* __restrict__ att_src1, const float* __restrict__ att_dst1,
    const float* __restrict__ att_src2, const float* __restrict__ att_dst2,
    ushort_t* __restrict__ W1t, ushort_t* __restrict__ W2t,
    float* __restrict__ Wsrc1, float* __restrict__ Wdst1,
    float* __restrict__ w_s2, float* __restrict__ w_d2,
    const int* __restrict__ ei, int E0, int Etot, int* __restrict__ counts) {
  const int bid = blockIdx.x;
  const int tid = threadIdx.x;
  if (bid < 128) {
    int idx = bid * 256 + tid;
    int r = idx >> 8, c = idx & 255;
    W1t[(size_t)c * 128 + r] = f2bf(W1[idx]);
  } else if (bid < 192) {
    int idx = (bid - 128) * 256 + tid;
    int r = idx >> 6, c = idx & 63;
    W2t[(size_t)c * 256 + r] = f2bf(W2[idx]);
  } else if (bid < 196) {
    int idx = (bid - 192) * 256 + tid;
    int k = idx >> 3, h = idx & 7;
    float as = 0.f, ad = 0.f;
    #pragma unroll
    for (int c = 0; c < 32; ++c) {
      float wv = W1[(size_t)k * 256 + h * 32 + c];
      as += wv * att_src1[h * 32 + c];
      ad += wv * att_dst1[h * 32 + c];
    }
    Wsrc1[idx] = as;
    Wdst1[idx] = ad;
  } else if (bid < 197) {
    int k = tid;
    float as = 0.f, ad = 0.f;
    #pragma unroll
    for (int c = 0; c < 64; ++c) {
      float wv = W2[(size_t)k * 64 + c];
      as += wv * att_src2[c];
      ad += wv * att_dst2[c];
    }
    w_s2[k] = as;
    w_d2[k] = ad;
  } else {
    int e = (bid - 197) * 256 + tid;
    if (e >= Etot) return;
    int d = (e < E0) ? ei[E0 + e] : (e - E0);
    atomicAdd(&counts[d], 1);
  }
}

// ------------- fused exclusive scan: decoupled lookback, 1 kernel -----------
// btot pre-zeroed. Block total >= 1024 > 0 acts as its own publish flag.
__global__ __launch_bounds__(256) void scan_fused(
    const int* __restrict__ counts, int* __restrict__ row_start,
    int* __restrict__ btot, int n) {
  __shared__ int wsum[4];
  __shared__ int s_prev;
  const int tid = threadIdx.x;
  const int lane = tid & 63;
  const int wid = tid >> 6;
  const int base = blockIdx.x * 1024 + tid * 4;
  int c[4], inc[4];
  #pragma unroll
  for (int j = 0; j < 4; ++j)
    c[j] = (base + j < n) ? counts[base + j] : 0;
  inc[0] = c[0];
  #pragma unroll
  for (int j = 1; j < 4; ++j) inc[j] = inc[j - 1] + c[j];
  int tsum = inc[3];
  int wincl = tsum;
  #pragma unroll
  for (int off = 1; off < 64; off <<= 1) {
    int v = __shfl_up(wincl, off, 64);
    if (lane >= off) wincl += v;
  }
  if (lane == 63) wsum[wid] = wincl;
  __syncthreads();
  int woff = 0;
  #pragma unroll
  for (int j = 0; j < 4; ++j)
    if (j < wid) woff += wsum[j];

  // publish this block's total (tid 255 holds woff + wincl = block total)
  if (tid == 255) atomicExch(&btot[blockIdx.x], woff + wincl);

  // lookback: wave-0 lane j spins on predecessor j (j < blockIdx.x <= 48)
  if (wid == 0) {
    int run = 0;
    if (lane < blockIdx.x) {
      int v;
      do {
        v = atomicAdd(&btot[lane], 0);
      } while (v == 0);
      run = v;
    }
    #pragma unroll
    for (int off = 32; off > 0; off >>= 1) run += __shfl_xor(run, off, 64);
    if (lane == 0) s_prev = run;
  }
  __syncthreads();

  int prefix = s_prev + woff + (wincl - tsum);
  #pragma unroll
  for (int j = 0; j < 4; ++j)
    if (base + j < n) row_start[base + j + 1] = prefix + inc[j];
  if (blockIdx.x == 0 && tid == 0) row_start[0] = 0;
}

// -------- kernel B: gemm1 + fill_csr + attproj1 (block-range dispatch) ------
__global__ __launch_bounds__(256) void kernelB(
    const float* __restrict__ x, const ushort_t* __restrict__ W1t,
    ushort_t* __restrict__ h1, int M,
    const int* __restrict__ ei, int E0, int Etot,
    const int* __restrict__ row_start, int* __restrict__ cursor,
    int* __restrict__ csr_src,
    const float* __restrict__ Wsrc, const float* __restrict__ Wdst,
    float* __restrict__ a_src, float* __restrict__ a_dst,
    int GB1, int FB) {
  __shared__ char smem[10240];
  const int bid = blockIdx.x;
  const int tid = threadIdx.x;

  if (bid < GB1) {
    ushort_t* As = (ushort_t*)smem;
    ushort_t* Bs = As + 64 * 40;
    const int lane = tid & 63;
    const int wave = tid >> 6;
    const int wr = wave >> 1, wc = wave & 1;
    const int row0 = (bid >> 2) * 64, col0 = (bid & 3) * 64;
    const int sr = tid >> 2;
    const int sk = (tid & 3) * 8;
    const int l15 = lane & 15;
    const int lk8 = (lane >> 4) * 8;
    const int K = 128;

    f32x4 acc[2][2];
    #pragma unroll
    for (int i = 0; i < 2; ++i)
      #pragma unroll
      for (int j = 0; j < 2; ++j) acc[i][j] = (f32x4){0.f, 0.f, 0.f, 0.f};

    for (int k0 = 0; k0 < K; k0 += 32) {
      const int gr = row0 + sr;
      float4 f0 = {0.f, 0.f, 0.f, 0.f}, f1 = {0.f, 0.f, 0.f, 0.f};
      if (gr < M) {
        f0 = *(const float4*)&x[(size_t)gr * K + k0 + sk];
        f1 = *(const float4*)&x[(size_t)gr * K + k0 + sk + 4];
      }
      uint4 av;
      av.x = pack2(f0.x, f0.y);
      av.y = pack2(f0.z, f0.w);
      av.z = pack2(f1.x, f1.y);
      av.w = pack2(f1.z, f1.w);
      *(uint4*)&As[sr * 40 + sk] = av;
      uint4 bv = *(const uint4*)&W1t[(size_t)(col0 + sr) * K + k0 + sk];
      *(uint4*)&Bs[sr * 40 + sk] = bv;
      __syncthreads();

      bf16x8 af[2], bfr[2];
      #pragma unroll
      for (int mi = 0; mi < 2; ++mi)
        af[mi] = *(const bf16x8*)&As[(wr * 32 + mi * 16 + l15) * 40 + lk8];
      #pragma unroll
      for (int ni = 0; ni < 2; ++ni)
        bfr[ni] = *(const bf16x8*)&Bs[(wc * 32 + ni * 16 + l15) * 40 + lk8];
      #pragma unroll
      for (int mi = 0; mi < 2; ++mi)
        #pragma unroll
        for (int ni = 0; ni < 2; ++ni)
          acc[mi][ni] = __builtin_amdgcn_mfma_f32_16x16x32_bf16(
              af[mi], bfr[ni], acc[mi][ni], 0, 0, 0);
      __syncthreads();
    }

    #pragma unroll
    for (int mi = 0; mi < 2; ++mi) {
      #pragma unroll
      for (int ni = 0; ni < 2; ++ni) {
        #pragma unroll
        for (int r = 0; r < 4; ++r) {
          int grow = row0 + wr * 32 + mi * 16 + (lane >> 4) * 4 + r;
          int gcol = col0 + wc * 32 + ni * 16 + l15;
          if (grow < M) h1[(size_t)grow * F1 + gcol] = f2bf(acc[mi][ni][r]);
        }
      }
    }
  } else if (bid < GB1 + FB) {
    int e = (bid - GB1) * 256 + tid;
    if (e >= Etot) return;
    int s, d;
    if (e < E0) { s = ei[e]; d = ei[E0 + e]; } else { s = d = e - E0; }
    int slot = row_start[d] + atomicAdd(&cursor[d], 1);
    csr_src[slot] = s;
  } else {
    float* ws = (float*)smem;
    float* wd = ws + 1024;
    #pragma unroll
    for (int i = 0; i < 4; ++i) {
      ws[tid + i * 256] = Wsrc[tid + i * 256];
      wd[tid + i * 256] = Wdst[tid + i * 256];
    }
    __syncthreads();
    const int node = (bid - GB1 - FB) * 32 + (tid >> 3);
    const int h = tid & 7;
    if (node >= M) return;
    float as = 0.f, ad = 0.f;
    const float* xr = &x[(size_t)node * 128];
    for (int k = 0; k < 128; ++k) {
      float xv = xr[k];
      as += xv * ws[k * 8 + h];
      ad += xv * wd[k * 8 + h];
    }
    a_src[node * 8 + h] = as;
    a_dst[node * 8 + h] = ad;
  }
}

// -------------------------- MFMA GEMM (layer 2) -----------------------------
__global__ __launch_bounds__(256) void gemm_bf16(
    const ushort_t* __restrict__ Ab, const ushort_t* __restrict__ Bt,
    ushort_t* __restrict__ Cb, int M, int N, int K) {
  __shared__ ushort_t As[64 * 40];
  __shared__ ushort_t Bs[64 * 40];
  const int tid = threadIdx.x;
  const int lane = tid & 63;
  const int wave = tid >> 6;
  const int wr = wave >> 1, wc = wave & 1;
  const int row0 = blockIdx.y * 64, col0 = blockIdx.x * 64;
  const int sr = tid >> 2;
  const int sk = (tid & 3) * 8;
  const int l15 = lane & 15;
  const int lk8 = (lane >> 4) * 8;

  f32x4 acc[2][2];
  #pragma unroll
  for (int i = 0; i < 2; ++i)
    #pragma unroll
    for (int j = 0; j < 2; ++j) acc[i][j] = (f32x4){0.f, 0.f, 0.f, 0.f};

  for (int k0 = 0; k0 < K; k0 += 32) {
    const int gr = row0 + sr;
    uint4 av = {0u, 0u, 0u, 0u};
    if (gr < M) av = *(const uint4*)&Ab[(size_t)gr * K + k0 + sk];
    *(uint4*)&As[sr * 40 + sk] = av;
    uint4 bv = *(const uint4*)&Bt[(size_t)(col0 + sr) * K + k0 + sk];
    *(uint4*)&Bs[sr * 40 + sk] = bv;
    __syncthreads();

    bf16x8 af[2], bfr[2];
    #pragma unroll
    for (int mi = 0; mi < 2; ++mi)
      af[mi] = *(const bf16x8*)&As[(wr * 32 + mi * 16 + l15) * 40 + lk8];
    #pragma unroll
    for (int ni = 0; ni < 2; ++ni)
      bfr[ni] = *(const bf16x8*)&Bs[(wc * 32 + ni * 16 + l15) * 40 + lk8];
    #pragma unroll
    for (int mi = 0; mi < 2; ++mi)
      #pragma unroll
      for (int ni = 0; ni < 2; ++ni)
        acc[mi][ni] = __builtin_amdgcn_mfma_f32_16x16x32_bf16(
            af[mi], bfr[ni], acc[mi][ni], 0, 0, 0);
    __syncthreads();
  }

  #pragma unroll
  for (int mi = 0; mi < 2; ++mi) {
    #pragma unroll
    for (int ni = 0; ni < 2; ++ni) {
      #pragma unroll
      for (int r = 0; r < 4; ++r) {
        int grow = row0 + wr * 32 + mi * 16 + (lane >> 4) * 4 + r;
        int gcol = col0 + wc * 32 + ni * 16 + l15;
        if (grow < M) Cb[(size_t)grow * N + gcol] = f2bf(acc[mi][ni][r]);
      }
    }
  }
}

// ---------- gather layer 1: single-pass + fused attproj2 epilogue -----------
__global__ __launch_bounds__(256) void gather1(
    const int* __restrict__ csr_src, const int* __restrict__ row_start,
    const float* __restrict__ a_src, const float* __restrict__ a_dst,
    const ushort_t* __restrict__ h1, const float* __restrict__ b,
    const float* __restrict__ ws2, const float* __restrict__ wd2,
    ushort_t* __restrict__ out, float* __restrict__ a_src2,
    float* __restrict__ a_dst2) {
  const int d = blockIdx.x;
  const int tid = threadIdx.x;
  const int rs = row_start[d];
  const int deg = row_start[d + 1] - rs;
  __shared__ float coef[64 * 8];
  __shared__ int s_lds[64];
  __shared__ float red8[32];
  __shared__ float rdeninv[8];
  __shared__ float part[256][4];

  const int h8 = tid & 7;
  const int slot = tid >> 3;
  const int wv = tid >> 6;
  const int lane = tid & 63;
  const int cg = tid & 63;
  const int hh = cg >> 3;
  const float adv = a_dst[d * 8 + h8];

  float dpart = 0.f;
  f32x4 acc = {0.f, 0.f, 0.f, 0.f};

  for (int t0 = 0; t0 < deg; t0 += 64) {
    const int nt = min(64, deg - t0);
    __syncthreads();
    #pragma unroll
    for (int half = 0; half < 2; ++half) {
      const int e = slot + half * 32;
      if (e < nt) {
        const int s = csr_src[rs + t0 + e];
        if (h8 == 0) s_lds[e] = s;
        const float ex = __expf(lrelu(a_src[s * 8 + h8] + adv));
        coef[e * 8 + h8] = ex;
        dpart += ex;
      }
    }
    __syncthreads();
    for (int i = wv; i < nt; i += 4) {
      const int s = s_lds[i];
      const float cf = coef[i * 8 + hh];
      ushort4 hv = *(const ushort4*)&h1[(size_t)s * F1 + cg * 4];
      acc[0] += cf * bf2f(hv.x);
      acc[1] += cf * bf2f(hv.y);
      acc[2] += cf * bf2f(hv.z);
      acc[3] += cf * bf2f(hv.w);
    }
  }

  dpart += __shfl_xor(dpart, 8, 64);
  dpart += __shfl_xor(dpart, 16, 64);
  dpart += __shfl_xor(dpart, 32, 64);
  part[tid][0] = acc[0];
  part[tid][1] = acc[1];
  part[tid][2] = acc[2];
  part[tid][3] = acc[3];
  if (lane < 8) red8[wv * 8 + lane] = dpart;
  __syncthreads();
  if (tid < 8)
    rdeninv[tid] = 1.f / (red8[tid] + red8[8 + tid] + red8[16 + tid] +
                          red8[24 + tid]);
  __syncthreads();
  if (tid < 64) {
    const int ch = tid * 4;
    const float rden = rdeninv[tid >> 3];
    ushort4 ob;
    float ps = 0.f, pd = 0.f;
    #pragma unroll
    for (int j = 0; j < 4; ++j) {
      float v = part[tid][j] + part[tid + 64][j] + part[tid + 128][j] +
                part[tid + 192][j];
      v = fmaxf(v * rden + b[ch + j], 0.f);
      ushort_t bv = f2bf(v);
      ((ushort_t*)&ob)[j] = bv;
      float r = bf2f(bv);
      ps += r * ws2[ch + j];
      pd += r * wd2[ch + j];
    }
    *(ushort4*)&out[(size_t)d * F1 + ch] = ob;
    #pragma unroll
    for (int off = 32; off > 0; off >>= 1) {
      ps += __shfl_xor(ps, off, 64);
      pd += __shfl_xor(pd, off, 64);
    }
    if (tid == 0) {
      a_src2[d] = ps;
      a_dst2[d] = pd;
    }
  }
}

// ------ gather layer 2 + log_softmax: 4-edge-parallel, UNIFORM trip count ---
__global__ __launch_bounds__(256) void gather2(
    const int* __restrict__ csr_src, const int* __restrict__ row_start,
    const float* __restrict__ a_src, const float* __restrict__ a_dst,
    const ushort_t* __restrict__ h2, const float* __restrict__ b,
    float* __restrict__ out, int n) {
  const int d = blockIdx.x * 4 + (threadIdx.x >> 6);
  const int lane = threadIdx.x & 63;
  if (d >= n) return;
  const int rs = row_start[d];
  const int deg = row_start[d + 1] - rs;
  const float adv = a_dst[d];

  const int sub = lane >> 4;
  const int q = lane & 15;
  float lsum = 0.f;
  f32x4 acc = {0.f, 0.f, 0.f, 0.f};
  for (int t0 = 0; t0 < deg; t0 += 64) {
    int myi = t0 + lane;
    int mys = 0;
    float myc = 0.f;
    if (myi < deg) {
      mys = csr_src[rs + myi];
      myc = __expf(lrelu(a_src[mys] + adv));
      lsum += myc;
    }
    const int nt = min(64, deg - t0);
    const int ntp = (nt + 3) & ~3;
    for (int e = sub; e < ntp; e += 4) {
      float cf = __shfl(myc, e, 64);
      int s = __shfl(mys, e, 64);
      ushort4 hv = *(const ushort4*)&h2[(size_t)s * F2 + q * 4];
      acc[0] += cf * bf2f(hv.x);
      acc[1] += cf * bf2f(hv.y);
      acc[2] += cf * bf2f(hv.z);
      acc[3] += cf * bf2f(hv.w);
    }
  }
  #pragma unroll
  for (int off = 32; off > 0; off >>= 1) lsum += __shfl_xor(lsum, off, 64);
  const float rden = 1.f / lsum;

  #pragma unroll
  for (int j = 0; j < 4; ++j) {
    acc[j] += __shfl_xor(acc[j], 16, 64);
    acc[j] += __shfl_xor(acc[j], 32, 64);
  }
  float vx = __shfl(acc[0], lane >> 2, 64);
  float vy = __shfl(acc[1], lane >> 2, 64);
  float vz = __shfl(acc[2], lane >> 2, 64);
  float vw = __shfl(acc[3], lane >> 2, 64);
  int c3 = lane & 3;
  float v = (c3 == 0) ? vx : (c3 == 1) ? vy : (c3 == 2) ? vz : vw;
  v = v * rden + b[lane];
  float m = v;
  #pragma unroll
  for (int off = 32; off > 0; off >>= 1) m = fmaxf(m, __shfl_xor(m, off, 64));
  float ex = __expf(v - m);
  float ss = ex;
  #pragma unroll
  for (int off = 32; off > 0; off >>= 1) ss += __shfl_xor(ss, off, 64);
  out[(size_t)d * F2 + lane] = v - m - __logf(ss);
}

// ------------------------------- launch -------------------------------------
extern "C" void kernel_launch(void* const* d_in, const int* in_sizes, int n_in,
                              void* d_out, int out_size, void* d_ws,
                              size_t ws_size, hipStream_t stream) {
  const float* x        = (const float*)d_in[0];
  const int*   ei       = (const int*)d_in[1];
  const float* W1       = (const float*)d_in[2];
  const float* att_src1 = (const float*)d_in[3];
  const float* att_dst1 = (const float*)d_in[4];
  const float* b1       = (const float*)d_in[5];
  const float* W2       = (const float*)d_in[6];
  const float* att_src2 = (const float*)d_in[7];
  const float* att_dst2 = (const float*)d_in[8];
  const float* b2       = (const float*)d_in[9];

  const int N = in_sizes[0] / 128;
  const int E0 = in_sizes[1] / 2;
  const int Etot = E0 + N;
  const int nb1024 = (N + 1023) / 1024;

  char* w = (char*)d_ws;
  size_t off = 0;
  auto alloc = [&](size_t bytes) {
    char* p = w + off;
    off += (bytes + 255) & ~(size_t)255;
    return p;
  };
  ushort_t* h1        = (ushort_t*)alloc((size_t)N * F1 * 2);
  ushort_t* h1out     = (ushort_t*)alloc((size_t)N * F1 * 2);
  ushort_t* h2b       = (ushort_t*)alloc((size_t)N * F2 * 2);
  int*      csr_src   = (int*)     alloc((size_t)Etot * 4);
  int*      row_start = (int*)     alloc((size_t)(N + 1) * 4);
  int*      cc        = (int*)     alloc(((size_t)2 * N + nb1024) * 4);
  int*      counts    = cc;
  int*      cursor    = cc + N;
  int*      btot      = cc + 2 * N;   // zeroed with cc (sentinel protocol)
  float*    a_src1    = (float*)   alloc((size_t)N * HEADS1 * 4);
  float*    a_dst1    = (float*)   alloc((size_t)N * HEADS1 * 4);
  float*    a_src2    = (float*)   alloc((size_t)N * 4);
  float*    a_dst2    = (float*)   alloc((size_t)N * 4);
  ushort_t* W1t       = (ushort_t*)alloc(128 * 256 * 2);
  ushort_t* W2t       = (ushort_t*)alloc(256 * 64 * 2);
  float*    Wsrc1     = (float*)   alloc(128 * 8 * 4);
  float*    Wdst1     = (float*)   alloc(128 * 8 * 4);
  float*    w_s2      = (float*)   alloc(256 * 4);
  float*    w_d2      = (float*)   alloc(256 * 4);

  hipMemsetAsync(cc, 0, ((size_t)2 * N + nb1024) * 4, stream);

  dim3 blk(256);
  const int eb = (Etot + 255) / 256;
  const int gy = (N + 63) / 64;
  const int GB1 = 4 * gy;
  const int attb = (N + 31) / 32;

  kernelA<<<197 + eb, blk, 0, stream>>>(W1, W2, att_src1, att_dst1, att_src2,
                                        att_dst2, W1t, W2t, Wsrc1, Wdst1,
                                        w_s2, w_d2, ei, E0, Etot, counts);
  scan_fused<<<nb1024, blk, 0, stream>>>(counts, row_start, btot, N);

  kernelB<<<GB1 + eb + attb, blk, 0, stream>>>(
      x, W1t, h1, N, ei, E0, Etot, row_start, cursor, csr_src, Wsrc1, Wdst1,
      a_src1, a_dst1, GB1, eb);

  gather1<<<N, blk, 0, stream>>>(csr_src, row_start, a_src1, a_dst1, h1, b1,
                                 w_s2, w_d2, h1out, a_src2, a_dst2);

  gemm_bf16<<<dim3(F2 / 64, gy), blk, 0, stream>>>(h1out, W2t, h2b, N, F2, F1);
  gather2<<<(N + 3) / 4, blk, 0, stream>>>(csr_src, row_start, a_src2, a_dst2,
                                           h2b, b2, (float*)d_out, N);
}

// Round 17
// 238.419 us; speedup vs baseline: 16.4616x; 1.0596x over previous
//
#include <hip/hip_runtime.h>
#include <hip/hip_bf16.h>
#include <cmath>

// ---------------------------------------------------------------------------
// GAT 2-layer forward. R17: gather1 rewritten wave-per-node (4 nodes/block,
// zero LDS, zero barriers, uniform-shfl discipline per R15). Everything else
// identical to R16.
// ---------------------------------------------------------------------------

#define HEADS1 8
#define F1 256
#define F2 64
#define NEG_SLOPE 0.2f

typedef unsigned int uint;
typedef unsigned short ushort_t;
typedef __attribute__((ext_vector_type(8))) short bf16x8;
typedef __attribute__((ext_vector_type(4))) float f32x4;

__device__ __forceinline__ float lrelu(float x) {
  return x >= 0.f ? x : NEG_SLOPE * x;
}
__device__ __forceinline__ ushort_t f2bf(float f) {
  uint u = __float_as_uint(f);
  return (ushort_t)((u + 0x7FFFu + ((u >> 16) & 1u)) >> 16);
}
__device__ __forceinline__ float bf2f(ushort_t u) {
  return __uint_as_float(((uint)u) << 16);
}
__device__ __forceinline__ uint pack2(float a, float b) {
  return (uint)f2bf(a) | ((uint)f2bf(b) << 16);
}

// --------------- kernel A: weight prep (197 blocks) + deg_count -------------
__global__ __launch_bounds__(256) void kernelA(
    const float* __restrict__ W1, const float* __restrict__ W2,
    const float* __restrict__ att_src1, const float* __restrict__ att_dst1,
    const float* __restrict__ att_src2, const float* __restrict__ att_dst2,
    ushort_t* __restrict__ W1t, ushort_t* __restrict__ W2t,
    float* __restrict__ Wsrc1, float* __restrict__ Wdst1,
    float* __restrict__ w_s2, float* __restrict__ w_d2,
    const int* __restrict__ ei, int E0, int Etot, int* __restrict__ counts) {
  const int bid = blockIdx.x;
  const int tid = threadIdx.x;
  if (bid < 128) {
    int idx = bid * 256 + tid;
    int r = idx >> 8, c = idx & 255;
    W1t[(size_t)c * 128 + r] = f2bf(W1[idx]);
  } else if (bid < 192) {
    int idx = (bid - 128) * 256 + tid;
    int r = idx >> 6, c = idx & 63;
    W2t[(size_t)c * 256 + r] = f2bf(W2[idx]);
  } else if (bid < 196) {
    int idx = (bid - 192) * 256 + tid;
    int k = idx >> 3, h = idx & 7;
    float as = 0.f, ad = 0.f;
    #pragma unroll
    for (int c = 0; c < 32; ++c) {
      float wv = W1[(size_t)k * 256 + h * 32 + c];
      as += wv * att_src1[h * 32 + c];
      ad += wv * att_dst1[h * 32 + c];
    }
    Wsrc1[idx] = as;
    Wdst1[idx] = ad;
  } else if (bid < 197) {
    int k = tid;
    float as = 0.f, ad = 0.f;
    #pragma unroll
    for (int c = 0; c < 64; ++c) {
      float wv = W2[(size_t)k * 64 + c];
      as += wv * att_src2[c];
      ad += wv * att_dst2[c];
    }
    w_s2[k] = as;
    w_d2[k] = ad;
  } else {
    int e = (bid - 197) * 256 + tid;
    if (e >= Etot) return;
    int d = (e < E0) ? ei[E0 + e] : (e - E0);
    atomicAdd(&counts[d], 1);
  }
}

// ------------- fused exclusive scan: decoupled lookback, 1 kernel -----------
__global__ __launch_bounds__(256) void scan_fused(
    const int* __restrict__ counts, int* __restrict__ row_start,
    int* __restrict__ btot, int n) {
  __shared__ int wsum[4];
  __shared__ int s_prev;
  const int tid = threadIdx.x;
  const int lane = tid & 63;
  const int wid = tid >> 6;
  const int base = blockIdx.x * 1024 + tid * 4;
  int c[4], inc[4];
  #pragma unroll
  for (int j = 0; j < 4; ++j)
    c[j] = (base + j < n) ? counts[base + j] : 0;
  inc[0] = c[0];
  #pragma unroll
  for (int j = 1; j < 4; ++j) inc[j] = inc[j - 1] + c[j];
  int tsum = inc[3];
  int wincl = tsum;
  #pragma unroll
  for (int off = 1; off < 64; off <<= 1) {
    int v = __shfl_up(wincl, off, 64);
    if (lane >= off) wincl += v;
  }
  if (lane == 63) wsum[wid] = wincl;
  __syncthreads();
  int woff = 0;
  #pragma unroll
  for (int j = 0; j < 4; ++j)
    if (j < wid) woff += wsum[j];

  if (tid == 255) atomicExch(&btot[blockIdx.x], woff + wincl);

  if (wid == 0) {
    int run = 0;
    if (lane < blockIdx.x) {
      int v;
      do {
        v = atomicAdd(&btot[lane], 0);
      } while (v == 0);
      run = v;
    }
    #pragma unroll
    for (int off = 32; off > 0; off >>= 1) run += __shfl_xor(run, off, 64);
    if (lane == 0) s_prev = run;
  }
  __syncthreads();

  int prefix = s_prev + woff + (wincl - tsum);
  #pragma unroll
  for (int j = 0; j < 4; ++j)
    if (base + j < n) row_start[base + j + 1] = prefix + inc[j];
  if (blockIdx.x == 0 && tid == 0) row_start[0] = 0;
}

// -------- kernel B: gemm1 + fill_csr + attproj1 (block-range dispatch) ------
__global__ __launch_bounds__(256) void kernelB(
    const float* __restrict__ x, const ushort_t* __restrict__ W1t,
    ushort_t* __restrict__ h1, int M,
    const int* __restrict__ ei, int E0, int Etot,
    const int* __restrict__ row_start, int* __restrict__ cursor,
    int* __restrict__ csr_src,
    const float* __restrict__ Wsrc, const float* __restrict__ Wdst,
    float* __restrict__ a_src, float* __restrict__ a_dst,
    int GB1, int FB) {
  __shared__ char smem[10240];
  const int bid = blockIdx.x;
  const int tid = threadIdx.x;

  if (bid < GB1) {
    ushort_t* As = (ushort_t*)smem;
    ushort_t* Bs = As + 64 * 40;
    const int lane = tid & 63;
    const int wave = tid >> 6;
    const int wr = wave >> 1, wc = wave & 1;
    const int row0 = (bid >> 2) * 64, col0 = (bid & 3) * 64;
    const int sr = tid >> 2;
    const int sk = (tid & 3) * 8;
    const int l15 = lane & 15;
    const int lk8 = (lane >> 4) * 8;
    const int K = 128;

    f32x4 acc[2][2];
    #pragma unroll
    for (int i = 0; i < 2; ++i)
      #pragma unroll
      for (int j = 0; j < 2; ++j) acc[i][j] = (f32x4){0.f, 0.f, 0.f, 0.f};

    for (int k0 = 0; k0 < K; k0 += 32) {
      const int gr = row0 + sr;
      float4 f0 = {0.f, 0.f, 0.f, 0.f}, f1 = {0.f, 0.f, 0.f, 0.f};
      if (gr < M) {
        f0 = *(const float4*)&x[(size_t)gr * K + k0 + sk];
        f1 = *(const float4*)&x[(size_t)gr * K + k0 + sk + 4];
      }
      uint4 av;
      av.x = pack2(f0.x, f0.y);
      av.y = pack2(f0.z, f0.w);
      av.z = pack2(f1.x, f1.y);
      av.w = pack2(f1.z, f1.w);
      *(uint4*)&As[sr * 40 + sk] = av;
      uint4 bv = *(const uint4*)&W1t[(size_t)(col0 + sr) * K + k0 + sk];
      *(uint4*)&Bs[sr * 40 + sk] = bv;
      __syncthreads();

      bf16x8 af[2], bfr[2];
      #pragma unroll
      for (int mi = 0; mi < 2; ++mi)
        af[mi] = *(const bf16x8*)&As[(wr * 32 + mi * 16 + l15) * 40 + lk8];
      #pragma unroll
      for (int ni = 0; ni < 2; ++ni)
        bfr[ni] = *(const bf16x8*)&Bs[(wc * 32 + ni * 16 + l15) * 40 + lk8];
      #pragma unroll
      for (int mi = 0; mi < 2; ++mi)
        #pragma unroll
        for (int ni = 0; ni < 2; ++ni)
          acc[mi][ni] = __builtin_amdgcn_mfma_f32_16x16x32_bf16(
              af[mi], bfr[ni], acc[mi][ni], 0, 0, 0);
      __syncthreads();
    }

    #pragma unroll
    for (int mi = 0; mi < 2; ++mi) {
      #pragma unroll
      for (int ni = 0; ni < 2; ++ni) {
        #pragma unroll
        for (int r = 0; r < 4; ++r) {
          int grow = row0 + wr * 32 + mi * 16 + (lane >> 4) * 4 + r;
          int gcol = col0 + wc * 32 + ni * 16 + l15;
          if (grow < M) h1[(size_t)grow * F1 + gcol] = f2bf(acc[mi][ni][r]);
        }
      }
    }
  } else if (bid < GB1 + FB) {
    int e = (bid - GB1) * 256 + tid;
    if (e >= Etot) return;
    int s, d;
    if (e < E0) { s = ei[e]; d = ei[E0 + e]; } else { s = d = e - E0; }
    int slot = row_start[d] + atomicAdd(&cursor[d], 1);
    csr_src[slot] = s;
  } else {
    float* ws = (float*)smem;
    float* wd = ws + 1024;
    #pragma unroll
    for (int i = 0; i < 4; ++i) {
      ws[tid + i * 256] = Wsrc[tid + i * 256];
      wd[tid + i * 256] = Wdst[tid + i * 256];
    }
    __syncthreads();
    const int node = (bid - GB1 - FB) * 32 + (tid >> 3);
    const int h = tid & 7;
    if (node >= M) return;
    float as = 0.f, ad = 0.f;
    const float* xr = &x[(size_t)node * 128];
    for (int k = 0; k < 128; ++k) {
      float xv = xr[k];
      as += xv * ws[k * 8 + h];
      ad += xv * wd[k * 8 + h];
    }
    a_src[node * 8 + h] = as;
    a_dst[node * 8 + h] = ad;
  }
}

// -------------------------- MFMA GEMM (layer 2) -----------------------------
__global__ __launch_bounds__(256) void gemm_bf16(
    const ushort_t* __restrict__ Ab, const ushort_t* __restrict__ Bt,
    ushort_t* __restrict__ Cb, int M, int N, int K) {
  __shared__ ushort_t As[64 * 40];
  __shared__ ushort_t Bs[64 * 40];
  const int tid = threadIdx.x;
  const int lane = tid & 63;
  const int wave = tid >> 6;
  const int wr = wave >> 1, wc = wave & 1;
  const int row0 = blockIdx.y * 64, col0 = blockIdx.x * 64;
  const int sr = tid >> 2;
  const int sk = (tid & 3) * 8;
  const int l15 = lane & 15;
  const int lk8 = (lane >> 4) * 8;

  f32x4 acc[2][2];
  #pragma unroll
  for (int i = 0; i < 2; ++i)
    #pragma unroll
    for (int j = 0; j < 2; ++j) acc[i][j] = (f32x4){0.f, 0.f, 0.f, 0.f};

  for (int k0 = 0; k0 < K; k0 += 32) {
    const int gr = row0 + sr;
    uint4 av = {0u, 0u, 0u, 0u};
    if (gr < M) av = *(const uint4*)&Ab[(size_t)gr * K + k0 + sk];
    *(uint4*)&As[sr * 40 + sk] = av;
    uint4 bv = *(const uint4*)&Bt[(size_t)(col0 + sr) * K + k0 + sk];
    *(uint4*)&Bs[sr * 40 + sk] = bv;
    __syncthreads();

    bf16x8 af[2], bfr[2];
    #pragma unroll
    for (int mi = 0; mi < 2; ++mi)
      af[mi] = *(const bf16x8*)&As[(wr * 32 + mi * 16 + l15) * 40 + lk8];
    #pragma unroll
    for (int ni = 0; ni < 2; ++ni)
      bfr[ni] = *(const bf16x8*)&Bs[(wc * 32 + ni * 16 + l15) * 40 + lk8];
    #pragma unroll
    for (int mi = 0; mi < 2; ++mi)
      #pragma unroll
      for (int ni = 0; ni < 2; ++ni)
        acc[mi][ni] = __builtin_amdgcn_mfma_f32_16x16x32_bf16(
            af[mi], bfr[ni], acc[mi][ni], 0, 0, 0);
    __syncthreads();
  }

  #pragma unroll
  for (int mi = 0; mi < 2; ++mi) {
    #pragma unroll
    for (int ni = 0; ni < 2; ++ni) {
      #pragma unroll
      for (int r = 0; r < 4; ++r) {
        int grow = row0 + wr * 32 + mi * 16 + (lane >> 4) * 4 + r;
        int gcol = col0 + wc * 32 + ni * 16 + l15;
        if (grow < M) Cb[(size_t)grow * N + gcol] = f2bf(acc[mi][ni][r]);
      }
    }
  }
}

// ------- gather layer 1: wave-per-node, zero LDS/barriers, uniform shfl -----
// 4 nodes/block. Producer (pe=lane>>3, ph=lane&7): raw exps per 8-edge tile;
// consumer: all 64 lanes ushort4-load the full 512B row per edge. Scale at
// end; fused attproj2 epilogue as wave reduce.
__global__ __launch_bounds__(256) void gather1(
    const int* __restrict__ csr_src, const int* __restrict__ row_start,
    const float* __restrict__ a_src, const float* __restrict__ a_dst,
    const ushort_t* __restrict__ h1, const float* __restrict__ b,
    const float* __restrict__ ws2, const float* __restrict__ wd2,
    ushort_t* __restrict__ out, float* __restrict__ a_src2,
    float* __restrict__ a_dst2, int n) {
  const int d = blockIdx.x * 4 + (threadIdx.x >> 6);
  const int lane = threadIdx.x & 63;
  if (d >= n) return;
  const int rs = row_start[d];
  const int deg = row_start[d + 1] - rs;
  const int pe = lane >> 3;      // producer edge slot 0..7
  const int ph = lane & 7;       // producer head
  const int hsel = lane >> 3;    // head of this lane's channels (ch=lane*4)
  const float adv = a_dst[d * 8 + ph];

  float dpart = 0.f;
  f32x4 acc = {0.f, 0.f, 0.f, 0.f};

  for (int t0 = 0; t0 < deg; t0 += 8) {
    const int nt = min(8, deg - t0);   // wave-uniform
    const int myi = t0 + pe;
    int mys = 0;
    float myc = 0.f;
    if (myi < deg) {
      mys = csr_src[rs + myi];
      myc = __expf(lrelu(a_src[mys * 8 + ph] + adv));
      dpart += myc;
    }
    for (int jj = 0; jj < nt; ++jj) {  // uniform loop -> shfl sources active
      float cf = __shfl(myc, jj * 8 + hsel, 64);
      int s = __shfl(mys, jj * 8, 64);
      ushort4 hv = *(const ushort4*)&h1[(size_t)s * F1 + lane * 4];
      acc[0] += cf * bf2f(hv.x);
      acc[1] += cf * bf2f(hv.y);
      acc[2] += cf * bf2f(hv.z);
      acc[3] += cf * bf2f(hv.w);
    }
  }

  // denom for head ph at every lane: reduce over pe (lane bits 3,4,5)
  dpart += __shfl_xor(dpart, 8, 64);
  dpart += __shfl_xor(dpart, 16, 64);
  dpart += __shfl_xor(dpart, 32, 64);
  // this lane's channels use head hsel -> fetch denom from lane hsel (l&7==hsel)
  const float rden = 1.f / __shfl(dpart, hsel, 64);

  const int ch = lane * 4;
  ushort4 ob;
  float ps = 0.f, pd = 0.f;
  #pragma unroll
  for (int j = 0; j < 4; ++j) {
    float v = fmaxf(acc[j] * rden + b[ch + j], 0.f);
    ushort_t bv = f2bf(v);
    ((ushort_t*)&ob)[j] = bv;
    float r = bf2f(bv);
    ps += r * ws2[ch + j];
    pd += r * wd2[ch + j];
  }
  *(ushort4*)&out[(size_t)d * F1 + ch] = ob;
  #pragma unroll
  for (int off = 32; off > 0; off >>= 1) {
    ps += __shfl_xor(ps, off, 64);
    pd += __shfl_xor(pd, off, 64);
  }
  if (lane == 0) {
    a_src2[d] = ps;
    a_dst2[d] = pd;
  }
}

// ------ gather layer 2 + log_softmax: 4-edge-parallel, UNIFORM trip count ---
__global__ __launch_bounds__(256) void gather2(
    const int* __restrict__ csr_src, const int* __restrict__ row_start,
    const float* __restrict__ a_src, const float* __restrict__ a_dst,
    const ushort_t* __restrict__ h2, const float* __restrict__ b,
    float* __restrict__ out, int n) {
  const int d = blockIdx.x * 4 + (threadIdx.x >> 6);
  const int lane = threadIdx.x & 63;
  if (d >= n) return;
  const int rs = row_start[d];
  const int deg = row_start[d + 1] - rs;
  const float adv = a_dst[d];

  const int sub = lane >> 4;
  const int q = lane & 15;
  float lsum = 0.f;
  f32x4 acc = {0.f, 0.f, 0.f, 0.f};
  for (int t0 = 0; t0 < deg; t0 += 64) {
    int myi = t0 + lane;
    int mys = 0;
    float myc = 0.f;
    if (myi < deg) {
      mys = csr_src[rs + myi];
      myc = __expf(lrelu(a_src[mys] + adv));
      lsum += myc;
    }
    const int nt = min(64, deg - t0);
    const int ntp = (nt + 3) & ~3;
    for (int e = sub; e < ntp; e += 4) {
      float cf = __shfl(myc, e, 64);
      int s = __shfl(mys, e, 64);
      ushort4 hv = *(const ushort4*)&h2[(size_t)s * F2 + q * 4];
      acc[0] += cf * bf2f(hv.x);
      acc[1] += cf * bf2f(hv.y);
      acc[2] += cf * bf2f(hv.z);
      acc[3] += cf * bf2f(hv.w);
    }
  }
  #pragma unroll
  for (int off = 32; off > 0; off >>= 1) lsum += __shfl_xor(lsum, off, 64);
  const float rden = 1.f / lsum;

  #pragma unroll
  for (int j = 0; j < 4; ++j) {
    acc[j] += __shfl_xor(acc[j], 16, 64);
    acc[j] += __shfl_xor(acc[j], 32, 64);
  }
  float vx = __shfl(acc[0], lane >> 2, 64);
  float vy = __shfl(acc[1], lane >> 2, 64);
  float vz = __shfl(acc[2], lane >> 2, 64);
  float vw = __shfl(acc[3], lane >> 2, 64);
  int c3 = lane & 3;
  float v = (c3 == 0) ? vx : (c3 == 1) ? vy : (c3 == 2) ? vz : vw;
  v = v * rden + b[lane];
  float m = v;
  #pragma unroll
  for (int off = 32; off > 0; off >>= 1) m = fmaxf(m, __shfl_xor(m, off, 64));
  float ex = __expf(v - m);
  float ss = ex;
  #pragma unroll
  for (int off = 32; off > 0; off >>= 1) ss += __shfl_xor(ss, off, 64);
  out[(size_t)d * F2 + lane] = v - m - __logf(ss);
}

// ------------------------------- launch -------------------------------------
extern "C" void kernel_launch(void* const* d_in, const int* in_sizes, int n_in,
                              void* d_out, int out_size, void* d_ws,
                              size_t ws_size, hipStream_t stream) {
  const float* x        = (const float*)d_in[0];
  const int*   ei       = (const int*)d_in[1];
  const float* W1       = (const float*)d_in[2];
  const float* att_src1 = (const float*)d_in[3];
  const float* att_dst1 = (const float*)d_in[4];
  const float* b1       = (const float*)d_in[5];
  const float* W2       = (const float*)d_in[6];
  const float* att_src2 = (const float*)d_in[7];
  const float* att_dst2 = (const float*)d_in[8];
  const float* b2       = (const float*)d_in[9];

  const int N = in_sizes[0] / 128;
  const int E0 = in_sizes[1] / 2;
  const int Etot = E0 + N;
  const int nb1024 = (N + 1023) / 1024;

  char* w = (char*)d_ws;
  size_t off = 0;
  auto alloc = [&](size_t bytes) {
    char* p = w + off;
    off += (bytes + 255) & ~(size_t)255;
    return p;
  };
  ushort_t* h1        = (ushort_t*)alloc((size_t)N * F1 * 2);
  ushort_t* h1out     = (ushort_t*)alloc((size_t)N * F1 * 2);
  ushort_t* h2b       = (ushort_t*)alloc((size_t)N * F2 * 2);
  int*      csr_src   = (int*)     alloc((size_t)Etot * 4);
  int*      row_start = (int*)     alloc((size_t)(N + 1) * 4);
  int*      cc        = (int*)     alloc(((size_t)2 * N + nb1024) * 4);
  int*      counts    = cc;
  int*      cursor    = cc + N;
  int*      btot      = cc + 2 * N;
  float*    a_src1    = (float*)   alloc((size_t)N * HEADS1 * 4);
  float*    a_dst1    = (float*)   alloc((size_t)N * HEADS1 * 4);
  float*    a_src2    = (float*)   alloc((size_t)N * 4);
  float*    a_dst2    = (float*)   alloc((size_t)N * 4);
  ushort_t* W1t       = (ushort_t*)alloc(128 * 256 * 2);
  ushort_t* W2t       = (ushort_t*)alloc(256 * 64 * 2);
  float*    Wsrc1     = (float*)   alloc(128 * 8 * 4);
  float*    Wdst1     = (float*)   alloc(128 * 8 * 4);
  float*    w_s2      = (float*)   alloc(256 * 4);
  float*    w_d2      = (float*)   alloc(256 * 4);

  hipMemsetAsync(cc, 0, ((size_t)2 * N + nb1024) * 4, stream);

  dim3 blk(256);
  const int eb = (Etot + 255) / 256;
  const int gy = (N + 63) / 64;
  const int GB1 = 4 * gy;
  const int attb = (N + 31) / 32;

  kernelA<<<197 + eb, blk, 0, stream>>>(W1, W2, att_src1, att_dst1, att_src2,
                                        att_dst2, W1t, W2t, Wsrc1, Wdst1,
                                        w_s2, w_d2, ei, E0, Etot, counts);
  scan_fused<<<nb1024, blk, 0, stream>>>(counts, row_start, btot, N);

  kernelB<<<GB1 + eb + attb, blk, 0, stream>>>(
      x, W1t, h1, N, ei, E0, Etot, row_start, cursor, csr_src, Wsrc1, Wdst1,
      a_src1, a_dst1, GB1, eb);

  gather1<<<(N + 3) / 4, blk, 0, stream>>>(csr_src, row_start, a_src1, a_dst1,
                                           h1, b1, w_s2, w_d2, h1out, a_src2,
                                           a_dst2, N);

  gemm_bf16<<<dim3(F2 / 64, gy), blk, 0, stream>>>(h1out, W2t, h2b, N, F2, F1);
  gather2<<<(N + 3) / 4, blk, 0, stream>>>(csr_src, row_start, a_src2, a_dst2,
                                           h2b, b2, (float*)d_out, N);
}

// Round 18
// 228.679 us; speedup vs baseline: 17.1627x; 1.0426x over previous
//
#include <hip/hip_runtime.h>
#include <hip/hip_bf16.h>
#include <hip/hip_fp8.h>
#include <cmath>

// ---------------------------------------------------------------------------
// GAT 2-layer forward. R18: h1 stored as OCP fp8-e4m3 (halves gather1's
// gather traffic; table 12.8MB doubles per-XCD L2 hit rate). Everything else
// identical to R17.
// ---------------------------------------------------------------------------

#define HEADS1 8
#define F1 256
#define F2 64
#define NEG_SLOPE 0.2f

typedef unsigned int uint;
typedef unsigned short ushort_t;
typedef unsigned char uchar_t;
typedef __attribute__((ext_vector_type(8))) short bf16x8;
typedef __attribute__((ext_vector_type(4))) float f32x4;

__device__ __forceinline__ float lrelu(float x) {
  return x >= 0.f ? x : NEG_SLOPE * x;
}
__device__ __forceinline__ ushort_t f2bf(float f) {
  uint u = __float_as_uint(f);
  return (ushort_t)((u + 0x7FFFu + ((u >> 16) & 1u)) >> 16);
}
__device__ __forceinline__ float bf2f(ushort_t u) {
  return __uint_as_float(((uint)u) << 16);
}
__device__ __forceinline__ uint pack2(float a, float b) {
  return (uint)f2bf(a) | ((uint)f2bf(b) << 16);
}
__device__ __forceinline__ uchar_t f2fp8(float f) {
  __hip_fp8_e4m3 t(f);
  return (uchar_t)t.__x;
}
__device__ __forceinline__ float fp82f(uchar_t u) {
  __hip_fp8_e4m3 t;
  t.__x = (__hip_fp8_storage_t)u;
  return (float)t;
}

// --------------- kernel A: weight prep (197 blocks) + deg_count -------------
__global__ __launch_bounds__(256) void kernelA(
    const float* __restrict__ W1, const float* __restrict__ W2,
    const float* __restrict__ att_src1, const float* __restrict__ att_dst1,
    const float* __restrict__ att_src2, const float* __restrict__ att_dst2,
    ushort_t* __restrict__ W1t, ushort_t* __restrict__ W2t,
    float* __restrict__ Wsrc1, float* __restrict__ Wdst1,
    float* __restrict__ w_s2, float* __restrict__ w_d2,
    const int* __restrict__ ei, int E0, int Etot, int* __restrict__ counts) {
  const int bid = blockIdx.x;
  const int tid = threadIdx.x;
  if (bid < 128) {
    int idx = bid * 256 + tid;
    int r = idx >> 8, c = idx & 255;
    W1t[(size_t)c * 128 + r] = f2bf(W1[idx]);
  } else if (bid < 192) {
    int idx = (bid - 128) * 256 + tid;
    int r = idx >> 6, c = idx & 63;
    W2t[(size_t)c * 256 + r] = f2bf(W2[idx]);
  } else if (bid < 196) {
    int idx = (bid - 192) * 256 + tid;
    int k = idx >> 3, h = idx & 7;
    float as = 0.f, ad = 0.f;
    #pragma unroll
    for (int c = 0; c < 32; ++c) {
      float wv = W1[(size_t)k * 256 + h * 32 + c];
      as += wv * att_src1[h * 32 + c];
      ad += wv * att_dst1[h * 32 + c];
    }
    Wsrc1[idx] = as;
    Wdst1[idx] = ad;
  } else if (bid < 197) {
    int k = tid;
    float as = 0.f, ad = 0.f;
    #pragma unroll
    for (int c = 0; c < 64; ++c) {
      float wv = W2[(size_t)k * 64 + c];
      as += wv * att_src2[c];
      ad += wv * att_dst2[c];
    }
    w_s2[k] = as;
    w_d2[k] = ad;
  } else {
    int e = (bid - 197) * 256 + tid;
    if (e >= Etot) return;
    int d = (e < E0) ? ei[E0 + e] : (e - E0);
    atomicAdd(&counts[d], 1);
  }
}

// ------------- fused exclusive scan: decoupled lookback, 1 kernel -----------
__global__ __launch_bounds__(256) void scan_fused(
    const int* __restrict__ counts, int* __restrict__ row_start,
    int* __restrict__ btot, int n) {
  __shared__ int wsum[4];
  __shared__ int s_prev;
  const int tid = threadIdx.x;
  const int lane = tid & 63;
  const int wid = tid >> 6;
  const int base = blockIdx.x * 1024 + tid * 4;
  int c[4], inc[4];
  #pragma unroll
  for (int j = 0; j < 4; ++j)
    c[j] = (base + j < n) ? counts[base + j] : 0;
  inc[0] = c[0];
  #pragma unroll
  for (int j = 1; j < 4; ++j) inc[j] = inc[j - 1] + c[j];
  int tsum = inc[3];
  int wincl = tsum;
  #pragma unroll
  for (int off = 1; off < 64; off <<= 1) {
    int v = __shfl_up(wincl, off, 64);
    if (lane >= off) wincl += v;
  }
  if (lane == 63) wsum[wid] = wincl;
  __syncthreads();
  int woff = 0;
  #pragma unroll
  for (int j = 0; j < 4; ++j)
    if (j < wid) woff += wsum[j];

  if (tid == 255) atomicExch(&btot[blockIdx.x], woff + wincl);

  if (wid == 0) {
    int run = 0;
    if (lane < blockIdx.x) {
      int v;
      do {
        v = atomicAdd(&btot[lane], 0);
      } while (v == 0);
      run = v;
    }
    #pragma unroll
    for (int off = 32; off > 0; off >>= 1) run += __shfl_xor(run, off, 64);
    if (lane == 0) s_prev = run;
  }
  __syncthreads();

  int prefix = s_prev + woff + (wincl - tsum);
  #pragma unroll
  for (int j = 0; j < 4; ++j)
    if (base + j < n) row_start[base + j + 1] = prefix + inc[j];
  if (blockIdx.x == 0 && tid == 0) row_start[0] = 0;
}

// -------- kernel B: gemm1 + fill_csr + attproj1 (block-range dispatch) ------
__global__ __launch_bounds__(256) void kernelB(
    const float* __restrict__ x, const ushort_t* __restrict__ W1t,
    uchar_t* __restrict__ h1, int M,
    const int* __restrict__ ei, int E0, int Etot,
    const int* __restrict__ row_start, int* __restrict__ cursor,
    int* __restrict__ csr_src,
    const float* __restrict__ Wsrc, const float* __restrict__ Wdst,
    float* __restrict__ a_src, float* __restrict__ a_dst,
    int GB1, int FB) {
  __shared__ char smem[10240];
  const int bid = blockIdx.x;
  const int tid = threadIdx.x;

  if (bid < GB1) {
    ushort_t* As = (ushort_t*)smem;
    ushort_t* Bs = As + 64 * 40;
    const int lane = tid & 63;
    const int wave = tid >> 6;
    const int wr = wave >> 1, wc = wave & 1;
    const int row0 = (bid >> 2) * 64, col0 = (bid & 3) * 64;
    const int sr = tid >> 2;
    const int sk = (tid & 3) * 8;
    const int l15 = lane & 15;
    const int lk8 = (lane >> 4) * 8;
    const int K = 128;

    f32x4 acc[2][2];
    #pragma unroll
    for (int i = 0; i < 2; ++i)
      #pragma unroll
      for (int j = 0; j < 2; ++j) acc[i][j] = (f32x4){0.f, 0.f, 0.f, 0.f};

    for (int k0 = 0; k0 < K; k0 += 32) {
      const int gr = row0 + sr;
      float4 f0 = {0.f, 0.f, 0.f, 0.f}, f1 = {0.f, 0.f, 0.f, 0.f};
      if (gr < M) {
        f0 = *(const float4*)&x[(size_t)gr * K + k0 + sk];
        f1 = *(const float4*)&x[(size_t)gr * K + k0 + sk + 4];
      }
      uint4 av;
      av.x = pack2(f0.x, f0.y);
      av.y = pack2(f0.z, f0.w);
      av.z = pack2(f1.x, f1.y);
      av.w = pack2(f1.z, f1.w);
      *(uint4*)&As[sr * 40 + sk] = av;
      uint4 bv = *(const uint4*)&W1t[(size_t)(col0 + sr) * K + k0 + sk];
      *(uint4*)&Bs[sr * 40 + sk] = bv;
      __syncthreads();

      bf16x8 af[2], bfr[2];
      #pragma unroll
      for (int mi = 0; mi < 2; ++mi)
        af[mi] = *(const bf16x8*)&As[(wr * 32 + mi * 16 + l15) * 40 + lk8];
      #pragma unroll
      for (int ni = 0; ni < 2; ++ni)
        bfr[ni] = *(const bf16x8*)&Bs[(wc * 32 + ni * 16 + l15) * 40 + lk8];
      #pragma unroll
      for (int mi = 0; mi < 2; ++mi)
        #pragma unroll
        for (int ni = 0; ni < 2; ++ni)
          acc[mi][ni] = __builtin_amdgcn_mfma_f32_16x16x32_bf16(
              af[mi], bfr[ni], acc[mi][ni], 0, 0, 0);
      __syncthreads();
    }

    #pragma unroll
    for (int mi = 0; mi < 2; ++mi) {
      #pragma unroll
      for (int ni = 0; ni < 2; ++ni) {
        #pragma unroll
        for (int r = 0; r < 4; ++r) {
          int grow = row0 + wr * 32 + mi * 16 + (lane >> 4) * 4 + r;
          int gcol = col0 + wc * 32 + ni * 16 + l15;
          if (grow < M) h1[(size_t)grow * F1 + gcol] = f2fp8(acc[mi][ni][r]);
        }
      }
    }
  } else if (bid < GB1 + FB) {
    int e = (bid - GB1) * 256 + tid;
    if (e >= Etot) return;
    int s, d;
    if (e < E0) { s = ei[e]; d = ei[E0 + e]; } else { s = d = e - E0; }
    int slot = row_start[d] + atomicAdd(&cursor[d], 1);
    csr_src[slot] = s;
  } else {
    float* ws = (float*)smem;
    float* wd = ws + 1024;
    #pragma unroll
    for (int i = 0; i < 4; ++i) {
      ws[tid + i * 256] = Wsrc[tid + i * 256];
      wd[tid + i * 256] = Wdst[tid + i * 256];
    }
    __syncthreads();
    const int node = (bid - GB1 - FB) * 32 + (tid >> 3);
    const int h = tid & 7;
    if (node >= M) return;
    float as = 0.f, ad = 0.f;
    const float* xr = &x[(size_t)node * 128];
    for (int k = 0; k < 128; ++k) {
      float xv = xr[k];
      as += xv * ws[k * 8 + h];
      ad += xv * wd[k * 8 + h];
    }
    a_src[node * 8 + h] = as;
    a_dst[node * 8 + h] = ad;
  }
}

// -------------------------- MFMA GEMM (layer 2) -----------------------------
__global__ __launch_bounds__(256) void gemm_bf16(
    const ushort_t* __restrict__ Ab, const ushort_t* __restrict__ Bt,
    ushort_t* __restrict__ Cb, int M, int N, int K) {
  __shared__ ushort_t As[64 * 40];
  __shared__ ushort_t Bs[64 * 40];
  const int tid = threadIdx.x;
  const int lane = tid & 63;
  const int wave = tid >> 6;
  const int wr = wave >> 1, wc = wave & 1;
  const int row0 = blockIdx.y * 64, col0 = blockIdx.x * 64;
  const int sr = tid >> 2;
  const int sk = (tid & 3) * 8;
  const int l15 = lane & 15;
  const int lk8 = (lane >> 4) * 8;

  f32x4 acc[2][2];
  #pragma unroll
  for (int i = 0; i < 2; ++i)
    #pragma unroll
    for (int j = 0; j < 2; ++j) acc[i][j] = (f32x4){0.f, 0.f, 0.f, 0.f};

  for (int k0 = 0; k0 < K; k0 += 32) {
    const int gr = row0 + sr;
    uint4 av = {0u, 0u, 0u, 0u};
    if (gr < M) av = *(const uint4*)&Ab[(size_t)gr * K + k0 + sk];
    *(uint4*)&As[sr * 40 + sk] = av;
    uint4 bv = *(const uint4*)&Bt[(size_t)(col0 + sr) * K + k0 + sk];
    *(uint4*)&Bs[sr * 40 + sk] = bv;
    __syncthreads();

    bf16x8 af[2], bfr[2];
    #pragma unroll
    for (int mi = 0; mi < 2; ++mi)
      af[mi] = *(const bf16x8*)&As[(wr * 32 + mi * 16 + l15) * 40 + lk8];
    #pragma unroll
    for (int ni = 0; ni < 2; ++ni)
      bfr[ni] = *(const bf16x8*)&Bs[(wc * 32 + ni * 16 + l15) * 40 + lk8];
    #pragma unroll
    for (int mi = 0; mi < 2; ++mi)
      #pragma unroll
      for (int ni = 0; ni < 2; ++ni)
        acc[mi][ni] = __builtin_amdgcn_mfma_f32_16x16x32_bf16(
            af[mi], bfr[ni], acc[mi][ni], 0, 0, 0);
    __syncthreads();
  }

  #pragma unroll
  for (int mi = 0; mi < 2; ++mi) {
    #pragma unroll
    for (int ni = 0; ni < 2; ++ni) {
      #pragma unroll
      for (int r = 0; r < 4; ++r) {
        int grow = row0 + wr * 32 + mi * 16 + (lane >> 4) * 4 + r;
        int gcol = col0 + wc * 32 + ni * 16 + l15;
        if (grow < M) Cb[(size_t)grow * N + gcol] = f2bf(acc[mi][ni][r]);
      }
    }
  }
}

// ------- gather layer 1: wave-per-node, fp8 h1 rows, uniform shfl -----------
__global__ __launch_bounds__(256) void gather1(
    const int* __restrict__ csr_src, const int* __restrict__ row_start,
    const float* __restrict__ a_src, const float* __restrict__ a_dst,
    const uchar_t* __restrict__ h1, const float* __restrict__ b,
    const float* __restrict__ ws2, const float* __restrict__ wd2,
    ushort_t* __restrict__ out, float* __restrict__ a_src2,
    float* __restrict__ a_dst2, int n) {
  const int d = blockIdx.x * 4 + (threadIdx.x >> 6);
  const int lane = threadIdx.x & 63;
  if (d >= n) return;
  const int rs = row_start[d];
  const int deg = row_start[d + 1] - rs;
  const int pe = lane >> 3;
  const int ph = lane & 7;
  const int hsel = lane >> 3;
  const float adv = a_dst[d * 8 + ph];

  float dpart = 0.f;
  f32x4 acc = {0.f, 0.f, 0.f, 0.f};

  for (int t0 = 0; t0 < deg; t0 += 8) {
    const int nt = min(8, deg - t0);
    const int myi = t0 + pe;
    int mys = 0;
    float myc = 0.f;
    if (myi < deg) {
      mys = csr_src[rs + myi];
      myc = __expf(lrelu(a_src[mys * 8 + ph] + adv));
      dpart += myc;
    }
    for (int jj = 0; jj < nt; ++jj) {
      float cf = __shfl(myc, jj * 8 + hsel, 64);
      int s = __shfl(mys, jj * 8, 64);
      uint hv = *(const uint*)&h1[(size_t)s * F1 + lane * 4];
      acc[0] += cf * fp82f((uchar_t)(hv & 0xff));
      acc[1] += cf * fp82f((uchar_t)((hv >> 8) & 0xff));
      acc[2] += cf * fp82f((uchar_t)((hv >> 16) & 0xff));
      acc[3] += cf * fp82f((uchar_t)(hv >> 24));
    }
  }

  dpart += __shfl_xor(dpart, 8, 64);
  dpart += __shfl_xor(dpart, 16, 64);
  dpart += __shfl_xor(dpart, 32, 64);
  const float rden = 1.f / __shfl(dpart, hsel, 64);

  const int ch = lane * 4;
  ushort4 ob;
  float ps = 0.f, pd = 0.f;
  #pragma unroll
  for (int j = 0; j < 4; ++j) {
    float v = fmaxf(acc[j] * rden + b[ch + j], 0.f);
    ushort_t bv = f2bf(v);
    ((ushort_t*)&ob)[j] = bv;
    float r = bf2f(bv);
    ps += r * ws2[ch + j];
    pd += r * wd2[ch + j];
  }
  *(ushort4*)&out[(size_t)d * F1 + ch] = ob;
  #pragma unroll
  for (int off = 32; off > 0; off >>= 1) {
    ps += __shfl_xor(ps, off, 64);
    pd += __shfl_xor(pd, off, 64);
  }
  if (lane == 0) {
    a_src2[d] = ps;
    a_dst2[d] = pd;
  }
}

// ------ gather layer 2 + log_softmax: 4-edge-parallel, UNIFORM trip count ---
__global__ __launch_bounds__(256) void gather2(
    const int* __restrict__ csr_src, const int* __restrict__ row_start,
    const float* __restrict__ a_src, const float* __restrict__ a_dst,
    const ushort_t* __restrict__ h2, const float* __restrict__ b,
    float* __restrict__ out, int n) {
  const int d = blockIdx.x * 4 + (threadIdx.x >> 6);
  const int lane = threadIdx.x & 63;
  if (d >= n) return;
  const int rs = row_start[d];
  const int deg = row_start[d + 1] - rs;
  const float adv = a_dst[d];

  const int sub = lane >> 4;
  const int q = lane & 15;
  float lsum = 0.f;
  f32x4 acc = {0.f, 0.f, 0.f, 0.f};
  for (int t0 = 0; t0 < deg; t0 += 64) {
    int myi = t0 + lane;
    int mys = 0;
    float myc = 0.f;
    if (myi < deg) {
      mys = csr_src[rs + myi];
      myc = __expf(lrelu(a_src[mys] + adv));
      lsum += myc;
    }
    const int nt = min(64, deg - t0);
    const int ntp = (nt + 3) & ~3;
    for (int e = sub; e < ntp; e += 4) {
      float cf = __shfl(myc, e, 64);
      int s = __shfl(mys, e, 64);
      ushort4 hv = *(const ushort4*)&h2[(size_t)s * F2 + q * 4];
      acc[0] += cf * bf2f(hv.x);
      acc[1] += cf * bf2f(hv.y);
      acc[2] += cf * bf2f(hv.z);
      acc[3] += cf * bf2f(hv.w);
    }
  }
  #pragma unroll
  for (int off = 32; off > 0; off >>= 1) lsum += __shfl_xor(lsum, off, 64);
  const float rden = 1.f / lsum;

  #pragma unroll
  for (int j = 0; j < 4; ++j) {
    acc[j] += __shfl_xor(acc[j], 16, 64);
    acc[j] += __shfl_xor(acc[j], 32, 64);
  }
  float vx = __shfl(acc[0], lane >> 2, 64);
  float vy = __shfl(acc[1], lane >> 2, 64);
  float vz = __shfl(acc[2], lane >> 2, 64);
  float vw = __shfl(acc[3], lane >> 2, 64);
  int c3 = lane & 3;
  float v = (c3 == 0) ? vx : (c3 == 1) ? vy : (c3 == 2) ? vz : vw;
  v = v * rden + b[lane];
  float m = v;
  #pragma unroll
  for (int off = 32; off > 0; off >>= 1) m = fmaxf(m, __shfl_xor(m, off, 64));
  float ex = __expf(v - m);
  float ss = ex;
  #pragma unroll
  for (int off = 32; off > 0; off >>= 1) ss += __shfl_xor(ss, off, 64);
  out[(size_t)d * F2 + lane] = v - m - __logf(ss);
}

// ------------------------------- launch -------------------------------------
extern "C" void kernel_launch(void* const* d_in, const int* in_sizes, int n_in,
                              void* d_out, int out_size, void* d_ws,
                              size_t ws_size, hipStream_t stream) {
  const float* x        = (const float*)d_in[0];
  const int*   ei       = (const int*)d_in[1];
  const float* W1       = (const float*)d_in[2];
  const float* att_src1 = (const float*)d_in[3];
  const float* att_dst1 = (const float*)d_in[4];
  const float* b1       = (const float*)d_in[5];
  const float* W2       = (const float*)d_in[6];
  const float* att_src2 = (const float*)d_in[7];
  const float* att_dst2 = (const float*)d_in[8];
  const float* b2       = (const float*)d_in[9];

  const int N = in_sizes[0] / 128;
  const int E0 = in_sizes[1] / 2;
  const int Etot = E0 + N;
  const int nb1024 = (N + 1023) / 1024;

  char* w = (char*)d_ws;
  size_t off = 0;
  auto alloc = [&](size_t bytes) {
    char* p = w + off;
    off += (bytes + 255) & ~(size_t)255;
    return p;
  };
  uchar_t*  h1        = (uchar_t*) alloc((size_t)N * F1 * 1);   // 12.8MB fp8
  ushort_t* h1out     = (ushort_t*)alloc((size_t)N * F1 * 2);
  ushort_t* h2b       = (ushort_t*)alloc((size_t)N * F2 * 2);
  int*      csr_src   = (int*)     alloc((size_t)Etot * 4);
  int*      row_start = (int*)     alloc((size_t)(N + 1) * 4);
  int*      cc        = (int*)     alloc(((size_t)2 * N + nb1024) * 4);
  int*      counts    = cc;
  int*      cursor    = cc + N;
  int*      btot      = cc + 2 * N;
  float*    a_src1    = (float*)   alloc((size_t)N * HEADS1 * 4);
  float*    a_dst1    = (float*)   alloc((size_t)N * HEADS1 * 4);
  float*    a_src2    = (float*)   alloc((size_t)N * 4);
  float*    a_dst2    = (float*)   alloc((size_t)N * 4);
  ushort_t* W1t       = (ushort_t*)alloc(128 * 256 * 2);
  ushort_t* W2t       = (ushort_t*)alloc(256 * 64 * 2);
  float*    Wsrc1     = (float*)   alloc(128 * 8 * 4);
  float*    Wdst1     = (float*)   alloc(128 * 8 * 4);
  float*    w_s2      = (float*)   alloc(256 * 4);
  float*    w_d2      = (float*)   alloc(256 * 4);

  hipMemsetAsync(cc, 0, ((size_t)2 * N + nb1024) * 4, stream);

  dim3 blk(256);
  const int eb = (Etot + 255) / 256;
  const int gy = (N + 63) / 64;
  const int GB1 = 4 * gy;
  const int attb = (N + 31) / 32;

  kernelA<<<197 + eb, blk, 0, stream>>>(W1, W2, att_src1, att_dst1, att_src2,
                                        att_dst2, W1t, W2t, Wsrc1, Wdst1,
                                        w_s2, w_d2, ei, E0, Etot, counts);
  scan_fused<<<nb1024, blk, 0, stream>>>(counts, row_start, btot, N);

  kernelB<<<GB1 + eb + attb, blk, 0, stream>>>(
      x, W1t, h1, N, ei, E0, Etot, row_start, cursor, csr_src, Wsrc1, Wdst1,
      a_src1, a_dst1, GB1, eb);

  gather1<<<(N + 3) / 4, blk, 0, stream>>>(csr_src, row_start, a_src1, a_dst1,
                                           h1, b1, w_s2, w_d2, h1out, a_src2,
                                           a_dst2, N);

  gemm_bf16<<<dim3(F2 / 64, gy), blk, 0, stream>>>(h1out, W2t, h2b, N, F2, F1);
  gather2<<<(N + 3) / 4, blk, 0, stream>>>(csr_src, row_start, a_src2, a_dst2,
                                           h2b, b2, (float*)d_out, N);
}